// Round 18
// baseline (1815.026 us; speedup 1.0000x reference)
//
#include <hip/hip_runtime.h>
#include <hip/hip_bf16.h>
#include <math.h>

// ---------------------------------------------------------------------------
// GraphEncoder round 18: kill per-step VALU in mfma_gemm.
// Round-17 was neutral and showed occupancy is NOT the limiter; VALUBusy 39%
// is the top pipe (address machinery: per-step source-select + 64-bit addr
// recompute in stage(), runtime-cur LDS indexing). Fixes:
//  (1) strength-reduced staging pointers (advance +32/step, one-time A2 switch)
//  (2) K-loop unrolled x2 (nsteps always even) -> compile-time LDS slot
//      indices + precomputed read offsets.
// Schedule (depth-2, counted vmcnt, barrier-after-MFMA) unchanged from r17.
// ---------------------------------------------------------------------------

constexpr int NN    = 100000;
constexpr int EE    = 400000;
constexpr int EP    = EE + NN;      // 500000 (incl self loops)
constexpr int BG    = 4096;
constexpr int FIN   = 300;
constexpr int HEADS = 4;
constexpr int HID   = 256;
constexpr int G4H   = 1024;
constexpr int NH1   = 512;
constexpr int NH2   = 768;
constexpr int MP    = 100352;       // 392*256, 392 % 8 == 0
constexpr int KP0   = 320;          // FIN padded to mult of 32
constexpr int SCB   = 392;          // scan blocks (392*256 = 100352 >= NN)

typedef __attribute__((ext_vector_type(4))) float f32x4;
typedef __attribute__((ext_vector_type(8))) short s16x8;

#define LOG2E 1.4426950408889634f

// fast HW transcendentals (v_exp_f32 = 2^x, v_rcp_f32)
__device__ inline float fexp(float x)  { return __builtin_amdgcn_exp2f(x * LOG2E); }
__device__ inline float frcp(float x)  { return __builtin_amdgcn_rcpf(x); }
__device__ inline float fsigm(float x) { return frcp(1.f + __builtin_amdgcn_exp2f(-LOG2E * x)); }
__device__ inline float ftanh(float x) { return 1.f - 2.f * frcp(1.f + __builtin_amdgcn_exp2f(2.f * LOG2E * x)); }

__device__ inline float b2f(short s) { return __uint_as_float(((unsigned)(unsigned short)s) << 16); }
__device__ inline short f2b(float f) {
    unsigned u = __float_as_uint(f);
    u += 0x7fff + ((u >> 16) & 1);          // round-to-nearest-even
    return (short)(u >> 16);
}
__device__ inline float wsum64(float v) {
#pragma unroll
    for (int o = 32; o > 0; o >>= 1) v += __shfl_xor(v, o);
    return v;
}

// ---------------- utility kernels -------------------------------------------
__global__ __launch_bounds__(256) void zero_f32(float* __restrict__ p, long long n)
{
    long long i = (long long)blockIdx.x * 256 + threadIdx.x;
    long long stride = (long long)gridDim.x * 256;
    for (; i < n; i += stride) p[i] = 0.f;
}

// f32 -> bf16 with row/col zero padding
__global__ __launch_bounds__(256) void conv_bf16(
    const float* __restrict__ src, short* __restrict__ dst,
    int rsrc, int rdst, int Ks, int Kd)
{
    long long n = (long long)rdst * Kd;
    long long stride = (long long)gridDim.x * 256;
    for (long long i = (long long)blockIdx.x * 256 + threadIdx.x; i < n; i += stride) {
        int r = (int)(i / Kd);
        int k = (int)(i - (long long)r * Kd);
        float v = (r < rsrc && k < Ks) ? src[(long long)r * Ks + k] : 0.f;
        dst[i] = f2b(v);
    }
}

// gate-interleaved pack of LSTM weight [1024][K]:
// new row p -> orig row gate*256+ch, gate=(p>>4)&3, ch=(p>>7)*32+((p>>6)&1)*16+(p&15)
__global__ __launch_bounds__(256) void conv_gates(
    const float* __restrict__ src, short* __restrict__ dst, int K)
{
    long long n = (long long)G4H * K;
    long long stride = (long long)gridDim.x * 256;
    for (long long i = (long long)blockIdx.x * 256 + threadIdx.x; i < n; i += stride) {
        int p = (int)(i / K);
        int k = (int)(i - (long long)p * K);
        int gate = (p >> 4) & 3;
        int ch   = (p >> 7) * 32 + ((p >> 6) & 1) * 16 + (p & 15);
        dst[i] = f2b(src[(size_t)(gate * 256 + ch) * K + k]);
    }
}

__global__ __launch_bounds__(256) void concat2_f32(
    const float* __restrict__ a, const float* __restrict__ b,
    float* __restrict__ dst, int na, int nb)
{
    int i = blockIdx.x * 256 + threadIdx.x;
    if (i < na) dst[i] = a[i];
    else if (i < na + nb) dst[i] = b[i - na];
}

// ---------------- CSR build -------------------------------------------------
__global__ __launch_bounds__(256) void edge_hist(const int* __restrict__ ei,
                                                 int* __restrict__ deg)
{
    int e = blockIdx.x * 256 + threadIdx.x;
    if (e >= EP) return;
    int d = (e < EE) ? ei[EE + e] : e - EE;
    atomicAdd(&deg[d], 1);
}

// pass 1: per-block chunk sums (coalesced)
__global__ __launch_bounds__(256) void scan_part(const int* __restrict__ deg,
                                                 int* __restrict__ bsum)
{
    int b = blockIdx.x, t = threadIdx.x;
    int i = b * 256 + t;
    int v = (i < NN) ? deg[i] : 0;
#pragma unroll
    for (int o = 32; o > 0; o >>= 1) v += __shfl_down(v, o);
    __shared__ int sh[4];
    if ((t & 63) == 0) sh[t >> 6] = v;
    __syncthreads();
    if (t == 0) bsum[b] = sh[0] + sh[1] + sh[2] + sh[3];
}

// pass 2: scan the 392 block sums (single small block)
__global__ __launch_bounds__(512) void scan_tops(const int* __restrict__ bsum,
                                                 int* __restrict__ bpre,
                                                 int* __restrict__ rowptr)
{
    __shared__ int sh[512];
    int t = threadIdx.x;
    int v = (t < SCB) ? bsum[t] : 0;
    sh[t] = v;
    __syncthreads();
    for (int off = 1; off < 512; off <<= 1) {
        int u = (t >= off) ? sh[t - off] : 0;
        __syncthreads();
        sh[t] += u;
        __syncthreads();
    }
    if (t < SCB) bpre[t] = sh[t] - v;          // exclusive prefix
    if (t == SCB - 1) rowptr[NN] = sh[t];      // total == EP
}

// pass 3: intra-block exclusive scan + write rowptr/cursor (coalesced)
__global__ __launch_bounds__(256) void scan_fill(const int* __restrict__ deg,
                                                 const int* __restrict__ bpre,
                                                 int* __restrict__ rowptr,
                                                 int* __restrict__ cursor)
{
    __shared__ int sh[256];
    int b = blockIdx.x, t = threadIdx.x;
    int i = b * 256 + t;
    int v = (i < NN) ? deg[i] : 0;
    sh[t] = v;
    __syncthreads();
    for (int off = 1; off < 256; off <<= 1) {
        int u = (t >= off) ? sh[t - off] : 0;
        __syncthreads();
        sh[t] += u;
        __syncthreads();
    }
    if (i < NN) {
        rowptr[i] = bpre[b] + sh[t] - v;       // exclusive
        cursor[i] = 0;
    }
}

__global__ __launch_bounds__(256) void edge_fill(const int* __restrict__ ei,
                                                 const int* __restrict__ rowptr,
                                                 int* __restrict__ cursor,
                                                 int* __restrict__ esrc)
{
    int e = blockIdx.x * 256 + threadIdx.x;
    if (e >= EP) return;
    int s, d;
    if (e < EE) { s = ei[e]; d = ei[EE + e]; }
    else        { s = d = e - EE; }
    int slot = rowptr[d] + atomicAdd(&cursor[d], 1);
    esrc[slot] = s;
}

// ---------------- MFMA GEMM with fused epilogues ----------------------------
// C[M x N] = A1[M x K1] @ B1[N x K1]^T (+ A2[M x K2] @ B2[N x K2]^T)
// BM=256 x BN=128 tile; 8 waves (512 thr) as 4x2 of 64x64.
// 1-D grid of (M/256)*(N/128) blocks; XCD swizzle. Requires (M/256)%8==0.
// 2-slot LDS, depth-2 prefetch, counted vmcnt; K-loop unrolled x2 (nsteps
// even at all call sites: KK in {256,320,512}); strength-reduced staging
// pointers (advance +32/step; one-time switch to A2/B2 at K1 crossover).
// mode 0: +bias -> f32 Cf      mode 1: +bias -> bf16 Cb
// mode 2: LSTM epilogue (gate-interleaved B; N=1024): reads c_in (or 0,
//         prefetched to regs pre-K-loop), writes c_out f32 + h_out bf16.
__global__ __launch_bounds__(512) void mfma_gemm(
    const short* __restrict__ A1, const short* __restrict__ B1, int K1,
    const short* __restrict__ A2, const short* __restrict__ B2, int K2,
    const float* __restrict__ bias,
    const float* __restrict__ bih, const float* __restrict__ bhh,
    const float* __restrict__ c_in, float* __restrict__ c_out,
    short* __restrict__ h_out,
    float* __restrict__ Cf, short* __restrict__ Cb, int N, int mode, int nct)
{
    __shared__ __align__(16) short sA[2][256 * 32];   // 16KB each
    __shared__ __align__(16) short sB[2][128 * 32];   // 8KB each
    const int tid  = threadIdx.x;
    const int w    = tid >> 6, lane = tid & 63;
    const int wr   = w >> 1,  wc   = w & 1;      // 4x2 waves of 64x64
    // XCD-aware decode (consecutive bids round-robin across 8 XCDs)
    const int bid  = blockIdx.x;
    const int xcd  = bid & 7;
    const int slot = bid >> 3;
    const int g    = slot / nct;
    const int tcol = slot - g * nct;
    const int row0 = (g * 8 + xcd) * 256;
    const int col0 = tcol * 128;

    f32x4 acc[4][4];
#pragma unroll
    for (int m = 0; m < 4; ++m)
#pragma unroll
        for (int n = 0; n < 4; ++n) acc[m][n] = (f32x4){0.f, 0.f, 0.f, 0.f};

    const int rs = lane >> 2;
    const int cs = lane & 3;
    const int KK = K1 + K2;
    const int nsteps = KK >> 5;                  // even at all call sites
    const int l16 = lane & 15;
    const int rloc = wr * 64 + ((lane >> 4) << 2);   // block-local base row

    // mode-2: prefetch c_in into regs; latency hides under the K-loop
    float co_pre[4][4] = {};
    const int ch = tcol * 32 + wc * 16 + l16;        // mode-2 channel
    if (mode == 2 && c_in) {
#pragma unroll
        for (int m = 0; m < 4; ++m)
#pragma unroll
            for (int r = 0; r < 4; ++r)
                co_pre[m][r] = c_in[(size_t)(row0 + rloc + m * 16 + r) * HID + ch];
    }

    // ---- staging state: strength-reduced per-thread pointers ----
    const int rowa0 = (w * 2 + 0) * 16 + rs;
    const int rowa1 = (w * 2 + 1) * 16 + rs;
    const int rowb  = w * 16 + rs;
    const int c8a0  = cs ^ ((rowa0 + (rowa0 >> 2)) & 3);
    const int c8a1  = cs ^ ((rowa1 + (rowa1 >> 2)) & 3);
    const int c8b   = cs ^ ((rowb  + (rowb  >> 2)) & 3);
    const short* pA0 = A1 + (size_t)(row0 + rowa0) * K1 + c8a0 * 8;
    const short* pA1 = A1 + (size_t)(row0 + rowa1) * K1 + c8a1 * 8;
    const short* pB  = B1 + (size_t)(col0 + rowb ) * K1 + c8b  * 8;
    short* laA0[2] = { &sA[0][(w * 2 + 0) * 512 + lane * 8], &sA[1][(w * 2 + 0) * 512 + lane * 8] };
    short* laA1[2] = { &sA[0][(w * 2 + 1) * 512 + lane * 8], &sA[1][(w * 2 + 1) * 512 + lane * 8] };
    short* lbB [2] = { &sB[0][w * 512 + lane * 8],           &sB[1][w * 512 + lane * 8] };
    int next_k = 0;

    auto stage = [&](int buf) {   // buf is a literal 0/1 at every call site
        __builtin_amdgcn_global_load_lds((const __attribute__((address_space(1))) void*)pA0,
                                         (__attribute__((address_space(3))) void*)laA0[buf], 16, 0, 0);
        __builtin_amdgcn_global_load_lds((const __attribute__((address_space(1))) void*)pA1,
                                         (__attribute__((address_space(3))) void*)laA1[buf], 16, 0, 0);
        __builtin_amdgcn_global_load_lds((const __attribute__((address_space(1))) void*)pB,
                                         (__attribute__((address_space(3))) void*)lbB[buf], 16, 0, 0);
        next_k += 32;
        if (K2 > 0 && next_k == K1) {            // one-time switch to source 2
            pA0 = A2 + (size_t)(row0 + rowa0) * K2 + c8a0 * 8;
            pA1 = A2 + (size_t)(row0 + rowa1) * K2 + c8a1 * 8;
            pB  = B2 + (size_t)(col0 + rowb ) * K2 + c8b  * 8;
        } else {
            pA0 += 32; pA1 += 32; pB += 32;
        }
    };

    // ---- precomputed LDS read offsets (short units) ----
    int offA[4], offB[4];
    {
        const int rl = lane & 15;
        const int cw = lane >> 4;
#pragma unroll
        for (int m = 0; m < 4; ++m) {
            int r  = wr * 64 + m * 16 + rl;
            int sl = cw ^ ((r + (r >> 2)) & 3);
            offA[m] = r * 32 + sl * 8;
            int c  = wc * 64 + m * 16 + rl;
            int sc = cw ^ ((c + (c >> 2)) & 3);
            offB[m] = c * 32 + sc * 8;
        }
    }

    stage(0);
    stage(1);                     // 6 loads in flight; KK >= 64 guaranteed

    for (int t = 0; t < nsteps; t += 2) {
        // ---------- substep A: step t, slot 0 ----------
        asm volatile("s_waitcnt vmcnt(3)" ::: "memory");   // t+1 < nsteps always
        __builtin_amdgcn_s_barrier();
        asm volatile("" ::: "memory");
        {
            s16x8 af[4], bg[4];
#pragma unroll
            for (int m = 0; m < 4; ++m) {
                af[m] = *(const s16x8*)(&sA[0][offA[m]]);
                bg[m] = *(const s16x8*)(&sB[0][offB[m]]);
            }
#pragma unroll
            for (int m = 0; m < 4; ++m)
#pragma unroll
                for (int n = 0; n < 4; ++n)
                    acc[m][n] = __builtin_amdgcn_mfma_f32_16x16x32_bf16(af[m], bg[n], acc[m][n], 0, 0, 0);
        }
        __builtin_amdgcn_s_barrier();          // all waves done reading slot 0
        asm volatile("" ::: "memory");
        if (t + 2 < nsteps) stage(0);          // re-stage slot 0 for step t+2

        // ---------- substep B: step t+1, slot 1 ----------
        if (t + 2 < nsteps) asm volatile("s_waitcnt vmcnt(3)" ::: "memory");
        else                asm volatile("s_waitcnt vmcnt(0)" ::: "memory");
        __builtin_amdgcn_s_barrier();
        asm volatile("" ::: "memory");
        {
            s16x8 af[4], bg[4];
#pragma unroll
            for (int m = 0; m < 4; ++m) {
                af[m] = *(const s16x8*)(&sA[1][offA[m]]);
                bg[m] = *(const s16x8*)(&sB[1][offB[m]]);
            }
#pragma unroll
            for (int m = 0; m < 4; ++m)
#pragma unroll
                for (int n = 0; n < 4; ++n)
                    acc[m][n] = __builtin_amdgcn_mfma_f32_16x16x32_bf16(af[m], bg[n], acc[m][n], 0, 0, 0);
        }
        __builtin_amdgcn_s_barrier();          // all waves done reading slot 1
        asm volatile("" ::: "memory");
        if (t + 3 < nsteps) stage(1);          // re-stage slot 1 for step t+3
    }

    // C/D layout: col=lane&15, row=(lane>>4)*4+reg
    const int rbase = row0 + rloc;
    if (mode == 2) {
        float bi[4];
#pragma unroll
        for (int gg2 = 0; gg2 < 4; ++gg2) bi[gg2] = bih[gg2 * 256 + ch] + bhh[gg2 * 256 + ch];
#pragma unroll
        for (int m = 0; m < 4; ++m) {
#pragma unroll
            for (int r = 0; r < 4; ++r) {
                int row = rbase + m * 16 + r;
                float gi = acc[m][0][r] + bi[0];
                float gf = acc[m][1][r] + bi[1];
                float gg = acc[m][2][r] + bi[2];
                float go = acc[m][3][r] + bi[3];
                size_t idx = (size_t)row * HID + ch;
                float c2 = fsigm(gf) * co_pre[m][r] + fsigm(gi) * ftanh(gg);
                float h2 = fsigm(go) * ftanh(c2);
                c_out[idx] = c2;
                h_out[idx] = f2b(h2);
            }
        }
    } else {
        const int cbase = col0 + wc * 64 + l16;
#pragma unroll
        for (int n = 0; n < 4; ++n) {
            int col = cbase + n * 16;
            float ba = bias ? bias[col] : 0.f;
#pragma unroll
            for (int m = 0; m < 4; ++m) {
#pragma unroll
                for (int r = 0; r < 4; ++r) {
                    int row = rbase + m * 16 + r;
                    float v = acc[m][n][r] + ba;
                    size_t idx = (size_t)row * N + col;
                    if (mode == 1) Cb[idx] = f2b(v);
                    else           Cf[idx] = v;
                }
            }
        }
    }
}

// ---------------- fused GATv2 (softmax + aggregate + bias + LN + ELU) -------
// one 64-lane wave per dst node; lane l = channel h*64+l per head h.
// xlr: [MP][512] bf16, cols 0..255 = lin_l(x), 256..511 = lin_r(x).
__global__ __launch_bounds__(256) void gat_fused(
    const short* __restrict__ xlr, const int* __restrict__ rowptr,
    const int* __restrict__ esrc, const float* __restrict__ att,
    const float* __restrict__ gb, const float* __restrict__ lg,
    const float* __restrict__ lb, short* __restrict__ outb)
{
    int i    = blockIdx.x * 4 + (threadIdx.x >> 6);
    int lane = threadIdx.x & 63;
    if (i >= NN) return;
    float xr[HEADS], at[HEADS];
#pragma unroll
    for (int h = 0; h < HEADS; ++h) {
        xr[h] = b2f(xlr[(size_t)i * 512 + 256 + h * 64 + lane]);
        at[h] = att[h * 64 + lane];
    }
    float mx[HEADS], sm[HEADS], ac[HEADS];
#pragma unroll
    for (int h = 0; h < HEADS; ++h) { mx[h] = -INFINITY; sm[h] = 0.f; ac[h] = 0.f; }

    int lo = rowptr[i], hi = rowptr[i + 1];
    for (int e = lo; e < hi; ++e) {
        int s = esrc[e];
        float xs[HEADS], p[HEADS];
#pragma unroll
        for (int h = 0; h < HEADS; ++h) {
            xs[h] = b2f(xlr[(size_t)s * 512 + h * 64 + lane]);
            float v = xs[h] + xr[h];
            v = (v >= 0.f) ? v : 0.2f * v;
            p[h] = v * at[h];
        }
#pragma unroll
        for (int h = 0; h < HEADS; ++h) p[h] = wsum64(p[h]);
#pragma unroll
        for (int h = 0; h < HEADS; ++h) {
            float mn = fmaxf(mx[h], p[h]);
            float sc = fexp(mx[h] - mn);     // first iter: exp(-inf)=0
            float a  = fexp(p[h] - mn);
            sm[h] = sm[h] * sc + a;
            ac[h] = ac[h] * sc + a * xs[h];
            mx[h] = mn;
        }
    }
    // y = ac/sm (+ gat bias), then LayerNorm(256) + ELU, write bf16
    float val[HEADS], s1 = 0.f, s2 = 0.f;
#pragma unroll
    for (int h = 0; h < HEADS; ++h) {
        float v = ac[h] * frcp(sm[h]) + gb[h * 64 + lane];
        val[h] = v; s1 += v; s2 += v * v;
    }
    s1 = wsum64(s1); s2 = wsum64(s2);
    float mean = s1 * (1.f / 256.f);
    float var  = s2 * (1.f / 256.f) - mean * mean;
    float inv  = rsqrtf(var + 1e-5f);
#pragma unroll
    for (int h = 0; h < HEADS; ++h) {
        float v = (val[h] - mean) * inv * lg[h * 64 + lane] + lb[h * 64 + lane];
        v = (v > 0.f) ? v : (fexp(v) - 1.f);
        outb[(size_t)i * HID + h * 64 + lane] = f2b(v);
    }
}

// ---------------- LayerNorm (+act) for the MLP head -------------------------
__global__ __launch_bounds__(256) void ln_act_kernel(
    const float* __restrict__ in, const float* __restrict__ gamma,
    const float* __restrict__ beta, float* __restrict__ outf,
    short* __restrict__ outb, int width, int act)
{
    int row = blockIdx.x;
    const float* ip = in + (size_t)row * width;
    float vals[3];
    float s = 0.f, ss = 0.f;
    int nw = width >> 8;
    for (int i = 0; i < nw; ++i) {
        int c = threadIdx.x + (i << 8);
        float v = ip[c];
        vals[i] = v; s += v; ss += v * v;
    }
#pragma unroll
    for (int off = 32; off > 0; off >>= 1) {
        s  += __shfl_down(s, off);
        ss += __shfl_down(ss, off);
    }
    __shared__ float sh[8];
    int wv = threadIdx.x >> 6, lane = threadIdx.x & 63;
    if (lane == 0) { sh[wv] = s; sh[4 + wv] = ss; }
    __syncthreads();
    if (threadIdx.x == 0) {
        sh[0] = sh[0] + sh[1] + sh[2] + sh[3];
        sh[4] = sh[4] + sh[5] + sh[6] + sh[7];
    }
    __syncthreads();
    float mean = sh[0] / width;
    float var  = sh[4] / width - mean * mean;
    float inv  = rsqrtf(var + 1e-5f);
    for (int i = 0; i < nw; ++i) {
        int c = threadIdx.x + (i << 8);
        float v = (vals[i] - mean) * inv * gamma[c] + beta[c];
        if (act == 1) v = fmaxf(v, 0.f);
        if (outb) outb[(size_t)row * width + c] = f2b(v);
        else      outf[(size_t)row * width + c] = v;
    }
}

// ---------------- sorted-batch mean pool ------------------------------------
__global__ __launch_bounds__(256) void pool_mean(
    const short* __restrict__ h, const int* __restrict__ batch,
    short* __restrict__ poolb)
{
    int b    = blockIdx.x * 4 + (threadIdx.x >> 6);
    int lane = threadIdx.x & 63;
    if (b >= BG) return;
    auto lbound = [&](int key) {
        int lo = 0, hi = NN;
        while (lo < hi) { int mid = (lo + hi) >> 1; if (batch[mid] < key) lo = mid + 1; else hi = mid; }
        return lo;
    };
    int lo = lbound(b), hi = lbound(b + 1);
    float acc[HEADS] = {0.f, 0.f, 0.f, 0.f};
    for (int r = lo; r < hi; ++r)
#pragma unroll
        for (int hh = 0; hh < HEADS; ++hh)
            acc[hh] += b2f(h[(size_t)r * HID + hh * 64 + lane]);
    float inv = 1.f / fmaxf((float)(hi - lo), 1.f);
#pragma unroll
    for (int hh = 0; hh < HEADS; ++hh)
        poolb[(size_t)b * HID + hh * 64 + lane] = f2b(acc[hh] * inv);
}

// ---------------------------------------------------------------------------
extern "C" void kernel_launch(void* const* d_in, const int* in_sizes, int n_in,
                              void* d_out, int out_size, void* d_ws, size_t ws_size,
                              hipStream_t stream)
{
    (void)in_sizes; (void)n_in; (void)out_size; (void)ws_size;
    const float* x      = (const float*)d_in[0];
    const int*   ei     = (const int*)d_in[1];
    const int*   batch  = (const int*)d_in[2];
    const float* lin0_w = (const float*)d_in[4];
    const float* lin0_b = (const float*)d_in[5];
    const float* r0_wih = (const float*)d_in[6];
    const float* r0_bih = (const float*)d_in[8];
    const float* r0_bhh = (const float*)d_in[9];
    const float* mh1_w  = (const float*)d_in[46];
    const float* mh1_b  = (const float*)d_in[47];
    const float* ln1_g  = (const float*)d_in[48];
    const float* ln1_b  = (const float*)d_in[49];
    const float* mh2_w  = (const float*)d_in[50];
    const float* mh2_b  = (const float*)d_in[51];
    const float* ln2_g  = (const float*)d_in[52];
    const float* ln2_b  = (const float*)d_in[53];
    float* out = (float*)d_out;

    // ---- workspace bump allocation ----
    char* wsb = (char*)d_ws;
    auto alloc = [&](size_t bytes) -> void* {
        void* p = (void*)wsb;
        wsb += (bytes + 255) & ~(size_t)255;
        return p;
    };
    const size_t NH = (size_t)MP * HID;
    float* cb   = (float*)alloc(NH * 4);          // LSTM cell state f32
    short* hA   = (short*)alloc(NH * 2);          // h ping
    short* hB   = (short*)alloc(NH * 2);          // h pong
    short* ybb  = (short*)alloc(NH * 2);          // LSTM-input / x0 bf16
    short* xlr  = (short*)alloc((size_t)MP * 512 * 2);  // [xl|xr] bf16
    int*   deg    = (int*)alloc((size_t)NN * 4);
    int*   rowptr = (int*)alloc((size_t)(NN + 1) * 4);
    int*   cursor = (int*)alloc((size_t)NN * 4);
    int*   esrc   = (int*)alloc((size_t)EP * 4);
    int*   bsum   = (int*)alloc((size_t)SCB * 4);
    int*   bpre   = (int*)alloc((size_t)SCB * 4);
    // weights bf16
    short* w_lin0 = (short*)alloc((size_t)256 * KP0 * 2);
    short* w_r0   = (short*)alloc((size_t)G4H * 256 * 2);
    short* w_lr[3]; short* w_ih[3]; short* w_hh[3]; float* blr[3];
    for (int l = 0; l < 3; ++l) {
        int Kp = (l == 0) ? KP0 : 256;
        w_lr[l] = (short*)alloc((size_t)512 * Kp * 2);
        w_ih[l] = (short*)alloc((size_t)G4H * 256 * 2);
        w_hh[l] = (short*)alloc((size_t)G4H * 256 * 2);
        blr[l]  = (float*)alloc(512 * 4);
    }
    short* w_m1 = (short*)alloc((size_t)NH1 * 256 * 2);
    short* w_m2 = (short*)alloc((size_t)NH2 * NH1 * 2);
    // xb (layer-0 padded input) with head temps aliased over it (head runs
    // only after xb is dead)
    short* xb = (short*)alloc((size_t)MP * KP0 * 2);   // 64 MB
    float* z1    = (float*)xb;                          // BG*NH1 f32 (8.4MB)
    short* z1b   = (short*)(z1 + (size_t)BG * NH1);     // BG*NH1 bf16
    short* poolb = z1b + (size_t)BG * NH1;              // BG*HID bf16

    auto conv = [&](const float* s, short* d, int rs, int rd, int Ks, int Kd) {
        conv_bf16<<<dim3(512), dim3(256), 0, stream>>>(s, d, rs, rd, Ks, Kd);
    };
    auto convg = [&](const float* s, short* d) {
        conv_gates<<<dim3(512), dim3(256), 0, stream>>>(s, d, 256);
    };
    // mode 0/1 GEMM; 1-D grid with XCD swizzle (requires (M/256)%8==0)
    auto G = [&](const short* A, const short* B, int K, const float* bias,
                 float* Cf, short* Cbb, int M, int N, int mode) {
        int nrp = M / 256, nct = N / 128;
        mfma_gemm<<<dim3(nrp * nct), dim3(512), 0, stream>>>(
            A, B, K, nullptr, nullptr, 0, bias,
            nullptr, nullptr, nullptr, nullptr, nullptr, Cf, Cbb, N, mode, nct);
    };
    // mode 2 LSTM GEMM
    auto GL = [&](const short* A1, const short* B1, int K1,
                  const short* A2, const short* B2, int K2,
                  const float* bih, const float* bhh,
                  const float* ci, float* co, short* ho) {
        mfma_gemm<<<dim3((MP / 256) * 8), dim3(512), 0, stream>>>(
            A1, B1, K1, A2, B2, K2, nullptr,
            bih, bhh, ci, co, ho, nullptr, nullptr, G4H, 2, 8);
    };

    // ---- conversions + CSR build ----
    conv(x, xb, NN, MP, FIN, KP0);
    conv(lin0_w, w_lin0, 256, 256, FIN, KP0);
    convg(r0_wih, w_r0);
    for (int l = 0; l < 3; ++l) {
        int base = 10 + 12 * l;
        int K  = (l == 0) ? FIN : 256;
        int Kp = (l == 0) ? KP0 : 256;
        conv((const float*)d_in[base + 0], w_lr[l], 256, 256, K, Kp);
        conv((const float*)d_in[base + 2], w_lr[l] + (size_t)256 * Kp, 256, 256, K, Kp);
        convg((const float*)d_in[base + 8], w_ih[l]);
        convg((const float*)d_in[base + 9], w_hh[l]);
        concat2_f32<<<dim3(2), dim3(256), 0, stream>>>(
            (const float*)d_in[base + 1], (const float*)d_in[base + 3], blr[l], 256, 256);
    }
    conv(mh1_w, w_m1, NH1, NH1, 256, 256);
    conv(mh2_w, w_m2, NH2, NH2, NH1, NH1);

    zero_f32<<<dim3(256), dim3(256), 0, stream>>>((float*)deg, NN);
    edge_hist<<<dim3((EP + 255) / 256), dim3(256), 0, stream>>>(ei, deg);
    scan_part<<<dim3(SCB), dim3(256), 0, stream>>>(deg, bsum);
    scan_tops<<<dim3(1), dim3(512), 0, stream>>>(bsum, bpre, rowptr);
    scan_fill<<<dim3(SCB), dim3(256), 0, stream>>>(deg, bpre, rowptr, cursor);
    edge_fill<<<dim3((EP + 255) / 256), dim3(256), 0, stream>>>(ei, rowptr, cursor, esrc);

    // ---- lin0 -> x0 (bf16); rnn0 LSTM from zero state (fused epilogue) ----
    G(xb, w_lin0, KP0, lin0_b, nullptr, ybb, MP, HID, 1);
    GL(ybb, w_r0, 256, nullptr, nullptr, 0, r0_bih, r0_bhh, nullptr, cb, hA);

    // ---- 3x (GATv2 -> LN+ELU -> LSTM) ----
    short* hprev = hA;
    short* hnext = hB;
    for (int l = 0; l < 3; ++l) {
        int base = 10 + 12 * l;
        const float* att = (const float*)d_in[base + 4];
        const float* gb  = (const float*)d_in[base + 5];
        const float* lg  = (const float*)d_in[base + 6];
        const float* lb  = (const float*)d_in[base + 7];
        const float* bih = (const float*)d_in[base + 10];
        const float* bhh = (const float*)d_in[base + 11];
        const short* Ain = (l == 0) ? xb : hprev;
        int K = (l == 0) ? KP0 : 256;

        G(Ain, w_lr[l], K, blr[l], nullptr, xlr, MP, 512, 1);
        gat_fused<<<dim3((NN + 3) / 4), dim3(256), 0, stream>>>(
            xlr, rowptr, esrc, att, gb, lg, lb, ybb);
        GL(ybb, w_ih[l], 256, hprev, w_hh[l], 256, bih, bhh, cb, cb, hnext);
        short* t = hprev; hprev = hnext; hnext = t;
    }

    // ---- mean pool (sorted batch) + MLP head ----
    pool_mean<<<dim3((BG + 3) / 4), dim3(256), 0, stream>>>(hprev, batch, poolb);
    G(poolb, w_m1, 256, mh1_b, z1, nullptr, BG, NH1, 0);
    ln_act_kernel<<<dim3(BG), dim3(256), 0, stream>>>(z1, ln1_g, ln1_b, nullptr, z1b, NH1, 1);
    G(z1b, w_m2, NH1, mh2_b, out, nullptr, BG, NH2, 0);
    ln_act_kernel<<<dim3(BG), dim3(256), 0, stream>>>(out, ln2_g, ln2_b, out, nullptr, NH2, 0);
}

// Round 19
// 1588.118 us; speedup vs baseline: 1.1429x; 1.1429x over previous
//
#include <hip/hip_runtime.h>
#include <hip/hip_bf16.h>
#include <math.h>

// ---------------------------------------------------------------------------
// GraphEncoder round 19 = revert to round-17 (best verified: 1593us).
// Round-18's VALU-trimming (persistent pointers + x2 unroll) cut VALUBusy
// 39->25% but raised VGPR 64->68, dropping occupancy 39->23% and regressing
// to 1815us. Lesson: at this tile config, the 64-VGPR occupancy boundary
// dominates instruction-count savings; r16/r17's 184us/dispatch is the
// structural plateau for the 2-slot counted-vmcnt schedule.
// Config: BM=256xBN=128, 8 waves, depth-2 prefetch, counted vmcnt (3/0),
// barrier-after-MFMA, XCD swizzle, hierarchical scan, fused GAT + LSTM
// epilogues, HW transcendentals.
// ---------------------------------------------------------------------------

constexpr int NN    = 100000;
constexpr int EE    = 400000;
constexpr int EP    = EE + NN;      // 500000 (incl self loops)
constexpr int BG    = 4096;
constexpr int FIN   = 300;
constexpr int HEADS = 4;
constexpr int HID   = 256;
constexpr int G4H   = 1024;
constexpr int NH1   = 512;
constexpr int NH2   = 768;
constexpr int MP    = 100352;       // 392*256, 392 % 8 == 0
constexpr int KP0   = 320;          // FIN padded to mult of 32
constexpr int SCB   = 392;          // scan blocks (392*256 = 100352 >= NN)

typedef __attribute__((ext_vector_type(4))) float f32x4;
typedef __attribute__((ext_vector_type(8))) short s16x8;

#define LOG2E 1.4426950408889634f

// fast HW transcendentals (v_exp_f32 = 2^x, v_rcp_f32)
__device__ inline float fexp(float x)  { return __builtin_amdgcn_exp2f(x * LOG2E); }
__device__ inline float frcp(float x)  { return __builtin_amdgcn_rcpf(x); }
__device__ inline float fsigm(float x) { return frcp(1.f + __builtin_amdgcn_exp2f(-LOG2E * x)); }
__device__ inline float ftanh(float x) { return 1.f - 2.f * frcp(1.f + __builtin_amdgcn_exp2f(2.f * LOG2E * x)); }

__device__ inline float b2f(short s) { return __uint_as_float(((unsigned)(unsigned short)s) << 16); }
__device__ inline short f2b(float f) {
    unsigned u = __float_as_uint(f);
    u += 0x7fff + ((u >> 16) & 1);          // round-to-nearest-even
    return (short)(u >> 16);
}
__device__ inline float wsum64(float v) {
#pragma unroll
    for (int o = 32; o > 0; o >>= 1) v += __shfl_xor(v, o);
    return v;
}

// ---------------- utility kernels -------------------------------------------
__global__ __launch_bounds__(256) void zero_f32(float* __restrict__ p, long long n)
{
    long long i = (long long)blockIdx.x * 256 + threadIdx.x;
    long long stride = (long long)gridDim.x * 256;
    for (; i < n; i += stride) p[i] = 0.f;
}

// f32 -> bf16 with row/col zero padding
__global__ __launch_bounds__(256) void conv_bf16(
    const float* __restrict__ src, short* __restrict__ dst,
    int rsrc, int rdst, int Ks, int Kd)
{
    long long n = (long long)rdst * Kd;
    long long stride = (long long)gridDim.x * 256;
    for (long long i = (long long)blockIdx.x * 256 + threadIdx.x; i < n; i += stride) {
        int r = (int)(i / Kd);
        int k = (int)(i - (long long)r * Kd);
        float v = (r < rsrc && k < Ks) ? src[(long long)r * Ks + k] : 0.f;
        dst[i] = f2b(v);
    }
}

// gate-interleaved pack of LSTM weight [1024][K]:
// new row p -> orig row gate*256+ch, gate=(p>>4)&3, ch=(p>>7)*32+((p>>6)&1)*16+(p&15)
__global__ __launch_bounds__(256) void conv_gates(
    const float* __restrict__ src, short* __restrict__ dst, int K)
{
    long long n = (long long)G4H * K;
    long long stride = (long long)gridDim.x * 256;
    for (long long i = (long long)blockIdx.x * 256 + threadIdx.x; i < n; i += stride) {
        int p = (int)(i / K);
        int k = (int)(i - (long long)p * K);
        int gate = (p >> 4) & 3;
        int ch   = (p >> 7) * 32 + ((p >> 6) & 1) * 16 + (p & 15);
        dst[i] = f2b(src[(size_t)(gate * 256 + ch) * K + k]);
    }
}

__global__ __launch_bounds__(256) void concat2_f32(
    const float* __restrict__ a, const float* __restrict__ b,
    float* __restrict__ dst, int na, int nb)
{
    int i = blockIdx.x * 256 + threadIdx.x;
    if (i < na) dst[i] = a[i];
    else if (i < na + nb) dst[i] = b[i - na];
}

// ---------------- CSR build -------------------------------------------------
__global__ __launch_bounds__(256) void edge_hist(const int* __restrict__ ei,
                                                 int* __restrict__ deg)
{
    int e = blockIdx.x * 256 + threadIdx.x;
    if (e >= EP) return;
    int d = (e < EE) ? ei[EE + e] : e - EE;
    atomicAdd(&deg[d], 1);
}

// pass 1: per-block chunk sums (coalesced)
__global__ __launch_bounds__(256) void scan_part(const int* __restrict__ deg,
                                                 int* __restrict__ bsum)
{
    int b = blockIdx.x, t = threadIdx.x;
    int i = b * 256 + t;
    int v = (i < NN) ? deg[i] : 0;
#pragma unroll
    for (int o = 32; o > 0; o >>= 1) v += __shfl_down(v, o);
    __shared__ int sh[4];
    if ((t & 63) == 0) sh[t >> 6] = v;
    __syncthreads();
    if (t == 0) bsum[b] = sh[0] + sh[1] + sh[2] + sh[3];
}

// pass 2: scan the 392 block sums (single small block)
__global__ __launch_bounds__(512) void scan_tops(const int* __restrict__ bsum,
                                                 int* __restrict__ bpre,
                                                 int* __restrict__ rowptr)
{
    __shared__ int sh[512];
    int t = threadIdx.x;
    int v = (t < SCB) ? bsum[t] : 0;
    sh[t] = v;
    __syncthreads();
    for (int off = 1; off < 512; off <<= 1) {
        int u = (t >= off) ? sh[t - off] : 0;
        __syncthreads();
        sh[t] += u;
        __syncthreads();
    }
    if (t < SCB) bpre[t] = sh[t] - v;          // exclusive prefix
    if (t == SCB - 1) rowptr[NN] = sh[t];      // total == EP
}

// pass 3: intra-block exclusive scan + write rowptr/cursor (coalesced)
__global__ __launch_bounds__(256) void scan_fill(const int* __restrict__ deg,
                                                 const int* __restrict__ bpre,
                                                 int* __restrict__ rowptr,
                                                 int* __restrict__ cursor)
{
    __shared__ int sh[256];
    int b = blockIdx.x, t = threadIdx.x;
    int i = b * 256 + t;
    int v = (i < NN) ? deg[i] : 0;
    sh[t] = v;
    __syncthreads();
    for (int off = 1; off < 256; off <<= 1) {
        int u = (t >= off) ? sh[t - off] : 0;
        __syncthreads();
        sh[t] += u;
        __syncthreads();
    }
    if (i < NN) {
        rowptr[i] = bpre[b] + sh[t] - v;       // exclusive
        cursor[i] = 0;
    }
}

__global__ __launch_bounds__(256) void edge_fill(const int* __restrict__ ei,
                                                 const int* __restrict__ rowptr,
                                                 int* __restrict__ cursor,
                                                 int* __restrict__ esrc)
{
    int e = blockIdx.x * 256 + threadIdx.x;
    if (e >= EP) return;
    int s, d;
    if (e < EE) { s = ei[e]; d = ei[EE + e]; }
    else        { s = d = e - EE; }
    int slot = rowptr[d] + atomicAdd(&cursor[d], 1);
    esrc[slot] = s;
}

// ---------------- MFMA GEMM with fused epilogues ----------------------------
// C[M x N] = A1[M x K1] @ B1[N x K1]^T (+ A2[M x K2] @ B2[N x K2]^T)
// BM=256 x BN=128 tile; 8 waves (512 thr) as 4x2 of 64x64.
// 1-D grid of (M/256)*(N/128) blocks; XCD swizzle: xcd=bid&7, slot=bid>>3,
// g=slot/nct, ct=slot%nct, row_panel=g*8+xcd. Requires (M/256)%8==0.
// 2-slot LDS (48KB), depth-2 prefetch, counted vmcnt (3/0).
// Requires KK >= 64 (all call sites have KK >= 256).
// mode 0: +bias -> f32 Cf      mode 1: +bias -> bf16 Cb
// mode 2: LSTM epilogue (gate-interleaved B; N=1024): reads c_in (or 0,
//         prefetched to regs pre-K-loop), writes c_out f32 + h_out bf16.
__global__ __launch_bounds__(512) void mfma_gemm(
    const short* __restrict__ A1, const short* __restrict__ B1, int K1,
    const short* __restrict__ A2, const short* __restrict__ B2, int K2,
    const float* __restrict__ bias,
    const float* __restrict__ bih, const float* __restrict__ bhh,
    const float* __restrict__ c_in, float* __restrict__ c_out,
    short* __restrict__ h_out,
    float* __restrict__ Cf, short* __restrict__ Cb, int N, int mode, int nct)
{
    __shared__ __align__(16) short sA[2][256 * 32];   // 16KB each
    __shared__ __align__(16) short sB[2][128 * 32];   // 8KB each
    const int tid  = threadIdx.x;
    const int w    = tid >> 6, lane = tid & 63;
    const int wr   = w >> 1,  wc   = w & 1;      // 4x2 waves of 64x64
    // XCD-aware decode (consecutive bids round-robin across 8 XCDs)
    const int bid  = blockIdx.x;
    const int xcd  = bid & 7;
    const int slot = bid >> 3;
    const int g    = slot / nct;
    const int tcol = slot - g * nct;
    const int row0 = (g * 8 + xcd) * 256;
    const int col0 = tcol * 128;

    f32x4 acc[4][4];
#pragma unroll
    for (int m = 0; m < 4; ++m)
#pragma unroll
        for (int n = 0; n < 4; ++n) acc[m][n] = (f32x4){0.f, 0.f, 0.f, 0.f};

    const int rs = lane >> 2;
    const int cs = lane & 3;
    const int KK = K1 + K2;
    const int nsteps = KK >> 5;
    const int l16 = lane & 15;
    const int rloc = wr * 64 + ((lane >> 4) << 2);   // block-local base row

    // mode-2: prefetch c_in into regs; latency hides under the K-loop
    float co_pre[4][4] = {};
    const int ch = tcol * 32 + wc * 16 + l16;        // mode-2 channel
    if (mode == 2 && c_in) {
#pragma unroll
        for (int m = 0; m < 4; ++m)
#pragma unroll
            for (int r = 0; r < 4; ++r)
                co_pre[m][r] = c_in[(size_t)(row0 + rloc + m * 16 + r) * HID + ch];
    }

    // 3 global_load_lds per wave per stage call (2x A-seg, 1x B-seg)
    auto stage = [&](int buf, int k0) {
        const short* Ak; const short* Bk; int kk, ld;
        if (k0 < K1) { Ak = A1; Bk = B1; kk = k0;      ld = K1; }
        else         { Ak = A2; Bk = B2; kk = k0 - K1; ld = K2; }
#pragma unroll
        for (int i = 0; i < 2; ++i) {
            int seg = w * 2 + i;                     // 16 A-segs of 16 rows
            int row = seg * 16 + rs;
            int c8  = cs ^ ((row + (row >> 2)) & 3);
            const short* ga = Ak + (size_t)(row0 + row) * ld + kk + c8 * 8;
            short* la = &sA[buf][seg * 512 + lane * 8];
            __builtin_amdgcn_global_load_lds((const __attribute__((address_space(1))) void*)ga,
                                             (__attribute__((address_space(3))) void*)la, 16, 0, 0);
        }
        {
            int row = w * 16 + rs;                   // 8 B-segs of 16 rows
            int c8  = cs ^ ((row + (row >> 2)) & 3);
            const short* gb = Bk + (size_t)(col0 + row) * ld + kk + c8 * 8;
            short* lb = &sB[buf][w * 512 + lane * 8];
            __builtin_amdgcn_global_load_lds((const __attribute__((address_space(1))) void*)gb,
                                             (__attribute__((address_space(3))) void*)lb, 16, 0, 0);
        }
    };

    stage(0, 0);
    stage(1, 32);                  // 6 loads in flight; KK >= 64 guaranteed
    int cur = 0;
    for (int t = 0; t < nsteps; ++t) {
        // wait for group t (oldest); keep the newer group in flight
        if (t + 1 < nsteps) asm volatile("s_waitcnt vmcnt(3)" ::: "memory");
        else                asm volatile("s_waitcnt vmcnt(0)" ::: "memory");
        __builtin_amdgcn_s_barrier();          // all waves: buf[cur] ready
        asm volatile("" ::: "memory");

        s16x8 af[4], bg[4];
        {
            const int rl = lane & 15;
            const int cw = lane >> 4;
#pragma unroll
            for (int m = 0; m < 4; ++m) {
                int r  = wr * 64 + m * 16 + rl;
                int sl = cw ^ ((r + (r >> 2)) & 3);
                af[m] = *(const s16x8*)(&sA[cur][r * 32 + sl * 8]);
                int c  = wc * 64 + m * 16 + rl;
                int sc = cw ^ ((c + (c >> 2)) & 3);
                bg[m] = *(const s16x8*)(&sB[cur][c * 32 + sc * 8]);
            }
        }
        // MFMAs consume all af/bg (compiler interleaves reads+MFMA with
        // fine-grained lgkmcnt); after them this wave's LDS reads are done.
#pragma unroll
        for (int m = 0; m < 4; ++m)
#pragma unroll
            for (int n = 0; n < 4; ++n)
                acc[m][n] = __builtin_amdgcn_mfma_f32_16x16x32_bf16(af[m], bg[n], acc[m][n], 0, 0, 0);

        __builtin_amdgcn_s_barrier();          // all waves done READING buf[cur]
        asm volatile("" ::: "memory");
        if (t + 2 < nsteps) stage(cur, (t + 2) * 32);   // re-stage 2 ahead
        cur ^= 1;
    }

    // C/D layout: col=lane&15, row=(lane>>4)*4+reg
    const int rbase = row0 + rloc;
    if (mode == 2) {
        float bi[4];
#pragma unroll
        for (int gg2 = 0; gg2 < 4; ++gg2) bi[gg2] = bih[gg2 * 256 + ch] + bhh[gg2 * 256 + ch];
#pragma unroll
        for (int m = 0; m < 4; ++m) {
#pragma unroll
            for (int r = 0; r < 4; ++r) {
                int row = rbase + m * 16 + r;
                float gi = acc[m][0][r] + bi[0];
                float gf = acc[m][1][r] + bi[1];
                float gg = acc[m][2][r] + bi[2];
                float go = acc[m][3][r] + bi[3];
                size_t idx = (size_t)row * HID + ch;
                float c2 = fsigm(gf) * co_pre[m][r] + fsigm(gi) * ftanh(gg);
                float h2 = fsigm(go) * ftanh(c2);
                c_out[idx] = c2;
                h_out[idx] = f2b(h2);
            }
        }
    } else {
        const int cbase = col0 + wc * 64 + l16;
#pragma unroll
        for (int n = 0; n < 4; ++n) {
            int col = cbase + n * 16;
            float ba = bias ? bias[col] : 0.f;
#pragma unroll
            for (int m = 0; m < 4; ++m) {
#pragma unroll
                for (int r = 0; r < 4; ++r) {
                    int row = rbase + m * 16 + r;
                    float v = acc[m][n][r] + ba;
                    size_t idx = (size_t)row * N + col;
                    if (mode == 1) Cb[idx] = f2b(v);
                    else           Cf[idx] = v;
                }
            }
        }
    }
}

// ---------------- fused GATv2 (softmax + aggregate + bias + LN + ELU) -------
// one 64-lane wave per dst node; lane l = channel h*64+l per head h.
// xlr: [MP][512] bf16, cols 0..255 = lin_l(x), 256..511 = lin_r(x).
__global__ __launch_bounds__(256) void gat_fused(
    const short* __restrict__ xlr, const int* __restrict__ rowptr,
    const int* __restrict__ esrc, const float* __restrict__ att,
    const float* __restrict__ gb, const float* __restrict__ lg,
    const float* __restrict__ lb, short* __restrict__ outb)
{
    int i    = blockIdx.x * 4 + (threadIdx.x >> 6);
    int lane = threadIdx.x & 63;
    if (i >= NN) return;
    float xr[HEADS], at[HEADS];
#pragma unroll
    for (int h = 0; h < HEADS; ++h) {
        xr[h] = b2f(xlr[(size_t)i * 512 + 256 + h * 64 + lane]);
        at[h] = att[h * 64 + lane];
    }
    float mx[HEADS], sm[HEADS], ac[HEADS];
#pragma unroll
    for (int h = 0; h < HEADS; ++h) { mx[h] = -INFINITY; sm[h] = 0.f; ac[h] = 0.f; }

    int lo = rowptr[i], hi = rowptr[i + 1];
    for (int e = lo; e < hi; ++e) {
        int s = esrc[e];
        float xs[HEADS], p[HEADS];
#pragma unroll
        for (int h = 0; h < HEADS; ++h) {
            xs[h] = b2f(xlr[(size_t)s * 512 + h * 64 + lane]);
            float v = xs[h] + xr[h];
            v = (v >= 0.f) ? v : 0.2f * v;
            p[h] = v * at[h];
        }
#pragma unroll
        for (int h = 0; h < HEADS; ++h) p[h] = wsum64(p[h]);
#pragma unroll
        for (int h = 0; h < HEADS; ++h) {
            float mn = fmaxf(mx[h], p[h]);
            float sc = fexp(mx[h] - mn);     // first iter: exp(-inf)=0
            float a  = fexp(p[h] - mn);
            sm[h] = sm[h] * sc + a;
            ac[h] = ac[h] * sc + a * xs[h];
            mx[h] = mn;
        }
    }
    // y = ac/sm (+ gat bias), then LayerNorm(256) + ELU, write bf16
    float val[HEADS], s1 = 0.f, s2 = 0.f;
#pragma unroll
    for (int h = 0; h < HEADS; ++h) {
        float v = ac[h] * frcp(sm[h]) + gb[h * 64 + lane];
        val[h] = v; s1 += v; s2 += v * v;
    }
    s1 = wsum64(s1); s2 = wsum64(s2);
    float mean = s1 * (1.f / 256.f);
    float var  = s2 * (1.f / 256.f) - mean * mean;
    float inv  = rsqrtf(var + 1e-5f);
#pragma unroll
    for (int h = 0; h < HEADS; ++h) {
        float v = (val[h] - mean) * inv * lg[h * 64 + lane] + lb[h * 64 + lane];
        v = (v > 0.f) ? v : (fexp(v) - 1.f);
        outb[(size_t)i * HID + h * 64 + lane] = f2b(v);
    }
}

// ---------------- LayerNorm (+act) for the MLP head -------------------------
__global__ __launch_bounds__(256) void ln_act_kernel(
    const float* __restrict__ in, const float* __restrict__ gamma,
    const float* __restrict__ beta, float* __restrict__ outf,
    short* __restrict__ outb, int width, int act)
{
    int row = blockIdx.x;
    const float* ip = in + (size_t)row * width;
    float vals[3];
    float s = 0.f, ss = 0.f;
    int nw = width >> 8;
    for (int i = 0; i < nw; ++i) {
        int c = threadIdx.x + (i << 8);
        float v = ip[c];
        vals[i] = v; s += v; ss += v * v;
    }
#pragma unroll
    for (int off = 32; off > 0; off >>= 1) {
        s  += __shfl_down(s, off);
        ss += __shfl_down(ss, off);
    }
    __shared__ float sh[8];
    int wv = threadIdx.x >> 6, lane = threadIdx.x & 63;
    if (lane == 0) { sh[wv] = s; sh[4 + wv] = ss; }
    __syncthreads();
    if (threadIdx.x == 0) {
        sh[0] = sh[0] + sh[1] + sh[2] + sh[3];
        sh[4] = sh[4] + sh[5] + sh[6] + sh[7];
    }
    __syncthreads();
    float mean = sh[0] / width;
    float var  = sh[4] / width - mean * mean;
    float inv  = rsqrtf(var + 1e-5f);
    for (int i = 0; i < nw; ++i) {
        int c = threadIdx.x + (i << 8);
        float v = (vals[i] - mean) * inv * gamma[c] + beta[c];
        if (act == 1) v = fmaxf(v, 0.f);
        if (outb) outb[(size_t)row * width + c] = f2b(v);
        else      outf[(size_t)row * width + c] = v;
    }
}

// ---------------- sorted-batch mean pool ------------------------------------
__global__ __launch_bounds__(256) void pool_mean(
    const short* __restrict__ h, const int* __restrict__ batch,
    short* __restrict__ poolb)
{
    int b    = blockIdx.x * 4 + (threadIdx.x >> 6);
    int lane = threadIdx.x & 63;
    if (b >= BG) return;
    auto lbound = [&](int key) {
        int lo = 0, hi = NN;
        while (lo < hi) { int mid = (lo + hi) >> 1; if (batch[mid] < key) lo = mid + 1; else hi = mid; }
        return lo;
    };
    int lo = lbound(b), hi = lbound(b + 1);
    float acc[HEADS] = {0.f, 0.f, 0.f, 0.f};
    for (int r = lo; r < hi; ++r)
#pragma unroll
        for (int hh = 0; hh < HEADS; ++hh)
            acc[hh] += b2f(h[(size_t)r * HID + hh * 64 + lane]);
    float inv = 1.f / fmaxf((float)(hi - lo), 1.f);
#pragma unroll
    for (int hh = 0; hh < HEADS; ++hh)
        poolb[(size_t)b * HID + hh * 64 + lane] = f2b(acc[hh] * inv);
}

// ---------------------------------------------------------------------------
extern "C" void kernel_launch(void* const* d_in, const int* in_sizes, int n_in,
                              void* d_out, int out_size, void* d_ws, size_t ws_size,
                              hipStream_t stream)
{
    (void)in_sizes; (void)n_in; (void)out_size; (void)ws_size;
    const float* x      = (const float*)d_in[0];
    const int*   ei     = (const int*)d_in[1];
    const int*   batch  = (const int*)d_in[2];
    const float* lin0_w = (const float*)d_in[4];
    const float* lin0_b = (const float*)d_in[5];
    const float* r0_wih = (const float*)d_in[6];
    const float* r0_bih = (const float*)d_in[8];
    const float* r0_bhh = (const float*)d_in[9];
    const float* mh1_w  = (const float*)d_in[46];
    const float* mh1_b  = (const float*)d_in[47];
    const float* ln1_g  = (const float*)d_in[48];
    const float* ln1_b  = (const float*)d_in[49];
    const float* mh2_w  = (const float*)d_in[50];
    const float* mh2_b  = (const float*)d_in[51];
    const float* ln2_g  = (const float*)d_in[52];
    const float* ln2_b  = (const float*)d_in[53];
    float* out = (float*)d_out;

    // ---- workspace bump allocation ----
    char* wsb = (char*)d_ws;
    auto alloc = [&](size_t bytes) -> void* {
        void* p = (void*)wsb;
        wsb += (bytes + 255) & ~(size_t)255;
        return p;
    };
    const size_t NH = (size_t)MP * HID;
    float* cb   = (float*)alloc(NH * 4);          // LSTM cell state f32
    short* hA   = (short*)alloc(NH * 2);          // h ping
    short* hB   = (short*)alloc(NH * 2);          // h pong
    short* ybb  = (short*)alloc(NH * 2);          // LSTM-input / x0 bf16
    short* xlr  = (short*)alloc((size_t)MP * 512 * 2);  // [xl|xr] bf16
    int*   deg    = (int*)alloc((size_t)NN * 4);
    int*   rowptr = (int*)alloc((size_t)(NN + 1) * 4);
    int*   cursor = (int*)alloc((size_t)NN * 4);
    int*   esrc   = (int*)alloc((size_t)EP * 4);
    int*   bsum   = (int*)alloc((size_t)SCB * 4);
    int*   bpre   = (int*)alloc((size_t)SCB * 4);
    // weights bf16
    short* w_lin0 = (short*)alloc((size_t)256 * KP0 * 2);
    short* w_r0   = (short*)alloc((size_t)G4H * 256 * 2);
    short* w_lr[3]; short* w_ih[3]; short* w_hh[3]; float* blr[3];
    for (int l = 0; l < 3; ++l) {
        int Kp = (l == 0) ? KP0 : 256;
        w_lr[l] = (short*)alloc((size_t)512 * Kp * 2);
        w_ih[l] = (short*)alloc((size_t)G4H * 256 * 2);
        w_hh[l] = (short*)alloc((size_t)G4H * 256 * 2);
        blr[l]  = (float*)alloc(512 * 4);
    }
    short* w_m1 = (short*)alloc((size_t)NH1 * 256 * 2);
    short* w_m2 = (short*)alloc((size_t)NH2 * NH1 * 2);
    // xb (layer-0 padded input) with head temps aliased over it (head runs
    // only after xb is dead)
    short* xb = (short*)alloc((size_t)MP * KP0 * 2);   // 64 MB
    float* z1    = (float*)xb;                          // BG*NH1 f32 (8.4MB)
    short* z1b   = (short*)(z1 + (size_t)BG * NH1);     // BG*NH1 bf16
    short* poolb = z1b + (size_t)BG * NH1;              // BG*HID bf16

    auto conv = [&](const float* s, short* d, int rs, int rd, int Ks, int Kd) {
        conv_bf16<<<dim3(512), dim3(256), 0, stream>>>(s, d, rs, rd, Ks, Kd);
    };
    auto convg = [&](const float* s, short* d) {
        conv_gates<<<dim3(512), dim3(256), 0, stream>>>(s, d, 256);
    };
    // mode 0/1 GEMM; 1-D grid with XCD swizzle (requires (M/256)%8==0)
    auto G = [&](const short* A, const short* B, int K, const float* bias,
                 float* Cf, short* Cbb, int M, int N, int mode) {
        int nrp = M / 256, nct = N / 128;
        mfma_gemm<<<dim3(nrp * nct), dim3(512), 0, stream>>>(
            A, B, K, nullptr, nullptr, 0, bias,
            nullptr, nullptr, nullptr, nullptr, nullptr, Cf, Cbb, N, mode, nct);
    };
    // mode 2 LSTM GEMM
    auto GL = [&](const short* A1, const short* B1, int K1,
                  const short* A2, const short* B2, int K2,
                  const float* bih, const float* bhh,
                  const float* ci, float* co, short* ho) {
        mfma_gemm<<<dim3((MP / 256) * 8), dim3(512), 0, stream>>>(
            A1, B1, K1, A2, B2, K2, nullptr,
            bih, bhh, ci, co, ho, nullptr, nullptr, G4H, 2, 8);
    };

    // ---- conversions + CSR build ----
    conv(x, xb, NN, MP, FIN, KP0);
    conv(lin0_w, w_lin0, 256, 256, FIN, KP0);
    convg(r0_wih, w_r0);
    for (int l = 0; l < 3; ++l) {
        int base = 10 + 12 * l;
        int K  = (l == 0) ? FIN : 256;
        int Kp = (l == 0) ? KP0 : 256;
        conv((const float*)d_in[base + 0], w_lr[l], 256, 256, K, Kp);
        conv((const float*)d_in[base + 2], w_lr[l] + (size_t)256 * Kp, 256, 256, K, Kp);
        convg((const float*)d_in[base + 8], w_ih[l]);
        convg((const float*)d_in[base + 9], w_hh[l]);
        concat2_f32<<<dim3(2), dim3(256), 0, stream>>>(
            (const float*)d_in[base + 1], (const float*)d_in[base + 3], blr[l], 256, 256);
    }
    conv(mh1_w, w_m1, NH1, NH1, 256, 256);
    conv(mh2_w, w_m2, NH2, NH2, NH1, NH1);

    zero_f32<<<dim3(256), dim3(256), 0, stream>>>((float*)deg, NN);
    edge_hist<<<dim3((EP + 255) / 256), dim3(256), 0, stream>>>(ei, deg);
    scan_part<<<dim3(SCB), dim3(256), 0, stream>>>(deg, bsum);
    scan_tops<<<dim3(1), dim3(512), 0, stream>>>(bsum, bpre, rowptr);
    scan_fill<<<dim3(SCB), dim3(256), 0, stream>>>(deg, bpre, rowptr, cursor);
    edge_fill<<<dim3((EP + 255) / 256), dim3(256), 0, stream>>>(ei, rowptr, cursor, esrc);

    // ---- lin0 -> x0 (bf16); rnn0 LSTM from zero state (fused epilogue) ----
    G(xb, w_lin0, KP0, lin0_b, nullptr, ybb, MP, HID, 1);
    GL(ybb, w_r0, 256, nullptr, nullptr, 0, r0_bih, r0_bhh, nullptr, cb, hA);

    // ---- 3x (GATv2 -> LN+ELU -> LSTM) ----
    short* hprev = hA;
    short* hnext = hB;
    for (int l = 0; l < 3; ++l) {
        int base = 10 + 12 * l;
        const float* att = (const float*)d_in[base + 4];
        const float* gb  = (const float*)d_in[base + 5];
        const float* lg  = (const float*)d_in[base + 6];
        const float* lb  = (const float*)d_in[base + 7];
        const float* bih = (const float*)d_in[base + 10];
        const float* bhh = (const float*)d_in[base + 11];
        const short* Ain = (l == 0) ? xb : hprev;
        int K = (l == 0) ? KP0 : 256;

        G(Ain, w_lr[l], K, blr[l], nullptr, xlr, MP, 512, 1);
        gat_fused<<<dim3((NN + 3) / 4), dim3(256), 0, stream>>>(
            xlr, rowptr, esrc, att, gb, lg, lb, ybb);
        GL(ybb, w_ih[l], 256, hprev, w_hh[l], 256, bih, bhh, cb, cb, hnext);
        short* t = hprev; hprev = hnext; hnext = t;
    }

    // ---- mean pool (sorted batch) + MLP head ----
    pool_mean<<<dim3((BG + 3) / 4), dim3(256), 0, stream>>>(hprev, batch, poolb);
    G(poolb, w_m1, 256, mh1_b, z1, nullptr, BG, NH1, 0);
    ln_act_kernel<<<dim3(BG), dim3(256), 0, stream>>>(z1, ln1_g, ln1_b, nullptr, z1b, NH1, 1);
    G(z1b, w_m2, NH1, mh2_b, out, nullptr, BG, NH2, 0);
    ln_act_kernel<<<dim3(BG), dim3(256), 0, stream>>>(out, ln2_g, ln2_b, out, nullptr, NH2, 0);
}

// Round 20
// 1570.805 us; speedup vs baseline: 1.1555x; 1.0110x over previous
//
#include <hip/hip_runtime.h>
#include <hip/hip_bf16.h>
#include <math.h>

// ---------------------------------------------------------------------------
// GraphEncoder round 20: r19 (best: 1588us) + batched setup dispatches.
// The ~17 tiny weight-conversion kernels (each 82-512KB, launch-bound
// ~3-6us) merge into ONE conv_pack (descriptor table, 2-D grid); the 3
// concat2 into ONE concat_pack. ~41 -> ~25 dispatches. All hot kernels
// (mfma_gemm depth-2 counted-vmcnt, gat_fused, scans) identical to r19.
// ---------------------------------------------------------------------------

constexpr int NN    = 100000;
constexpr int EE    = 400000;
constexpr int EP    = EE + NN;      // 500000 (incl self loops)
constexpr int BG    = 4096;
constexpr int FIN   = 300;
constexpr int HEADS = 4;
constexpr int HID   = 256;
constexpr int G4H   = 1024;
constexpr int NH1   = 512;
constexpr int NH2   = 768;
constexpr int MP    = 100352;       // 392*256, 392 % 8 == 0
constexpr int KP0   = 320;          // FIN padded to mult of 32
constexpr int SCB   = 392;          // scan blocks (392*256 = 100352 >= NN)

typedef __attribute__((ext_vector_type(4))) float f32x4;
typedef __attribute__((ext_vector_type(8))) short s16x8;

#define LOG2E 1.4426950408889634f

// fast HW transcendentals (v_exp_f32 = 2^x, v_rcp_f32)
__device__ inline float fexp(float x)  { return __builtin_amdgcn_exp2f(x * LOG2E); }
__device__ inline float frcp(float x)  { return __builtin_amdgcn_rcpf(x); }
__device__ inline float fsigm(float x) { return frcp(1.f + __builtin_amdgcn_exp2f(-LOG2E * x)); }
__device__ inline float ftanh(float x) { return 1.f - 2.f * frcp(1.f + __builtin_amdgcn_exp2f(2.f * LOG2E * x)); }

__device__ inline float b2f(short s) { return __uint_as_float(((unsigned)(unsigned short)s) << 16); }
__device__ inline short f2b(float f) {
    unsigned u = __float_as_uint(f);
    u += 0x7fff + ((u >> 16) & 1);          // round-to-nearest-even
    return (short)(u >> 16);
}
__device__ inline float wsum64(float v) {
#pragma unroll
    for (int o = 32; o > 0; o >>= 1) v += __shfl_xor(v, o);
    return v;
}

// ---------------- utility kernels -------------------------------------------
__global__ __launch_bounds__(256) void zero_f32(float* __restrict__ p, long long n)
{
    long long i = (long long)blockIdx.x * 256 + threadIdx.x;
    long long stride = (long long)gridDim.x * 256;
    for (; i < n; i += stride) p[i] = 0.f;
}

// f32 -> bf16 with row/col zero padding (used only for the big x conversion)
__global__ __launch_bounds__(256) void conv_bf16(
    const float* __restrict__ src, short* __restrict__ dst,
    int rsrc, int rdst, int Ks, int Kd)
{
    long long n = (long long)rdst * Kd;
    long long stride = (long long)gridDim.x * 256;
    for (long long i = (long long)blockIdx.x * 256 + threadIdx.x; i < n; i += stride) {
        int r = (int)(i / Kd);
        int k = (int)(i - (long long)r * Kd);
        float v = (r < rsrc && k < Ks) ? src[(long long)r * Ks + k] : 0.f;
        dst[i] = f2b(v);
    }
}

// ---- batched weight conversions: one dispatch for all small tensors --------
// gate==0: pad-convert [rsrc x Ks] -> [n/Kd x Kd] bf16
// gate==1: gate-interleaved LSTM pack (Ks = K), n = 1024*K
struct CDesc { const float* src; short* dst; int n, Ks, Kd, rsrc, gate; };
struct CPack { CDesc d[16]; };

__global__ __launch_bounds__(256) void conv_pack(CPack p, int nd)
{
    int di = blockIdx.y;
    if (di >= nd) return;
    CDesc c = p.d[di];
    int stride = gridDim.x * 256;
    for (int i = blockIdx.x * 256 + threadIdx.x; i < c.n; i += stride) {
        float v;
        if (c.gate) {
            int K  = c.Ks;
            int pp = i / K, k = i - pp * K;
            int gate = (pp >> 4) & 3;
            int ch   = (pp >> 7) * 32 + ((pp >> 6) & 1) * 16 + (pp & 15);
            v = c.src[(size_t)(gate * 256 + ch) * K + k];
        } else {
            int r = i / c.Kd, k = i - r * c.Kd;
            v = (r < c.rsrc && k < c.Ks) ? c.src[(size_t)r * c.Ks + k] : 0.f;
        }
        c.dst[i] = f2b(v);
    }
}

// ---- batched bias concat (3 layers x [bl|br] -> blr f32[512]) --------------
struct BPack { const float* a[3]; const float* b[3]; float* dst[3]; };
__global__ __launch_bounds__(256) void concat_pack(BPack p)
{
    int l = blockIdx.x >> 1;
    int half = blockIdx.x & 1;
    const float* s = half ? p.b[l] : p.a[l];
    p.dst[l][half * 256 + threadIdx.x] = s[threadIdx.x];
}

// ---------------- CSR build -------------------------------------------------
__global__ __launch_bounds__(256) void edge_hist(const int* __restrict__ ei,
                                                 int* __restrict__ deg)
{
    int e = blockIdx.x * 256 + threadIdx.x;
    if (e >= EP) return;
    int d = (e < EE) ? ei[EE + e] : e - EE;
    atomicAdd(&deg[d], 1);
}

// pass 1: per-block chunk sums (coalesced)
__global__ __launch_bounds__(256) void scan_part(const int* __restrict__ deg,
                                                 int* __restrict__ bsum)
{
    int b = blockIdx.x, t = threadIdx.x;
    int i = b * 256 + t;
    int v = (i < NN) ? deg[i] : 0;
#pragma unroll
    for (int o = 32; o > 0; o >>= 1) v += __shfl_down(v, o);
    __shared__ int sh[4];
    if ((t & 63) == 0) sh[t >> 6] = v;
    __syncthreads();
    if (t == 0) bsum[b] = sh[0] + sh[1] + sh[2] + sh[3];
}

// pass 2: scan the 392 block sums (single small block)
__global__ __launch_bounds__(512) void scan_tops(const int* __restrict__ bsum,
                                                 int* __restrict__ bpre,
                                                 int* __restrict__ rowptr)
{
    __shared__ int sh[512];
    int t = threadIdx.x;
    int v = (t < SCB) ? bsum[t] : 0;
    sh[t] = v;
    __syncthreads();
    for (int off = 1; off < 512; off <<= 1) {
        int u = (t >= off) ? sh[t - off] : 0;
        __syncthreads();
        sh[t] += u;
        __syncthreads();
    }
    if (t < SCB) bpre[t] = sh[t] - v;          // exclusive prefix
    if (t == SCB - 1) rowptr[NN] = sh[t];      // total == EP
}

// pass 3: intra-block exclusive scan + write rowptr/cursor (coalesced)
__global__ __launch_bounds__(256) void scan_fill(const int* __restrict__ deg,
                                                 const int* __restrict__ bpre,
                                                 int* __restrict__ rowptr,
                                                 int* __restrict__ cursor)
{
    __shared__ int sh[256];
    int b = blockIdx.x, t = threadIdx.x;
    int i = b * 256 + t;
    int v = (i < NN) ? deg[i] : 0;
    sh[t] = v;
    __syncthreads();
    for (int off = 1; off < 256; off <<= 1) {
        int u = (t >= off) ? sh[t - off] : 0;
        __syncthreads();
        sh[t] += u;
        __syncthreads();
    }
    if (i < NN) {
        rowptr[i] = bpre[b] + sh[t] - v;       // exclusive
        cursor[i] = 0;
    }
}

__global__ __launch_bounds__(256) void edge_fill(const int* __restrict__ ei,
                                                 const int* __restrict__ rowptr,
                                                 int* __restrict__ cursor,
                                                 int* __restrict__ esrc)
{
    int e = blockIdx.x * 256 + threadIdx.x;
    if (e >= EP) return;
    int s, d;
    if (e < EE) { s = ei[e]; d = ei[EE + e]; }
    else        { s = d = e - EE; }
    int slot = rowptr[d] + atomicAdd(&cursor[d], 1);
    esrc[slot] = s;
}

// ---------------- MFMA GEMM with fused epilogues ----------------------------
// C[M x N] = A1[M x K1] @ B1[N x K1]^T (+ A2[M x K2] @ B2[N x K2]^T)
// BM=256 x BN=128 tile; 8 waves (512 thr) as 4x2 of 64x64.
// 1-D grid of (M/256)*(N/128) blocks; XCD swizzle: xcd=bid&7, slot=bid>>3,
// g=slot/nct, ct=slot%nct, row_panel=g*8+xcd. Requires (M/256)%8==0.
// 2-slot LDS (48KB), depth-2 prefetch, counted vmcnt (3/0).
// mode 0: +bias -> f32 Cf      mode 1: +bias -> bf16 Cb
// mode 2: LSTM epilogue (gate-interleaved B; N=1024): reads c_in (or 0,
//         prefetched to regs pre-K-loop), writes c_out f32 + h_out bf16.
__global__ __launch_bounds__(512) void mfma_gemm(
    const short* __restrict__ A1, const short* __restrict__ B1, int K1,
    const short* __restrict__ A2, const short* __restrict__ B2, int K2,
    const float* __restrict__ bias,
    const float* __restrict__ bih, const float* __restrict__ bhh,
    const float* __restrict__ c_in, float* __restrict__ c_out,
    short* __restrict__ h_out,
    float* __restrict__ Cf, short* __restrict__ Cb, int N, int mode, int nct)
{
    __shared__ __align__(16) short sA[2][256 * 32];   // 16KB each
    __shared__ __align__(16) short sB[2][128 * 32];   // 8KB each
    const int tid  = threadIdx.x;
    const int w    = tid >> 6, lane = tid & 63;
    const int wr   = w >> 1,  wc   = w & 1;      // 4x2 waves of 64x64
    // XCD-aware decode (consecutive bids round-robin across 8 XCDs)
    const int bid  = blockIdx.x;
    const int xcd  = bid & 7;
    const int slot = bid >> 3;
    const int g    = slot / nct;
    const int tcol = slot - g * nct;
    const int row0 = (g * 8 + xcd) * 256;
    const int col0 = tcol * 128;

    f32x4 acc[4][4];
#pragma unroll
    for (int m = 0; m < 4; ++m)
#pragma unroll
        for (int n = 0; n < 4; ++n) acc[m][n] = (f32x4){0.f, 0.f, 0.f, 0.f};

    const int rs = lane >> 2;
    const int cs = lane & 3;
    const int KK = K1 + K2;
    const int nsteps = KK >> 5;
    const int l16 = lane & 15;
    const int rloc = wr * 64 + ((lane >> 4) << 2);   // block-local base row

    // mode-2: prefetch c_in into regs; latency hides under the K-loop
    float co_pre[4][4] = {};
    const int ch = tcol * 32 + wc * 16 + l16;        // mode-2 channel
    if (mode == 2 && c_in) {
#pragma unroll
        for (int m = 0; m < 4; ++m)
#pragma unroll
            for (int r = 0; r < 4; ++r)
                co_pre[m][r] = c_in[(size_t)(row0 + rloc + m * 16 + r) * HID + ch];
    }

    // 3 global_load_lds per wave per stage call (2x A-seg, 1x B-seg)
    auto stage = [&](int buf, int k0) {
        const short* Ak; const short* Bk; int kk, ld;
        if (k0 < K1) { Ak = A1; Bk = B1; kk = k0;      ld = K1; }
        else         { Ak = A2; Bk = B2; kk = k0 - K1; ld = K2; }
#pragma unroll
        for (int i = 0; i < 2; ++i) {
            int seg = w * 2 + i;                     // 16 A-segs of 16 rows
            int row = seg * 16 + rs;
            int c8  = cs ^ ((row + (row >> 2)) & 3);
            const short* ga = Ak + (size_t)(row0 + row) * ld + kk + c8 * 8;
            short* la = &sA[buf][seg * 512 + lane * 8];
            __builtin_amdgcn_global_load_lds((const __attribute__((address_space(1))) void*)ga,
                                             (__attribute__((address_space(3))) void*)la, 16, 0, 0);
        }
        {
            int row = w * 16 + rs;                   // 8 B-segs of 16 rows
            int c8  = cs ^ ((row + (row >> 2)) & 3);
            const short* gb = Bk + (size_t)(col0 + row) * ld + kk + c8 * 8;
            short* lb = &sB[buf][w * 512 + lane * 8];
            __builtin_amdgcn_global_load_lds((const __attribute__((address_space(1))) void*)gb,
                                             (__attribute__((address_space(3))) void*)lb, 16, 0, 0);
        }
    };

    stage(0, 0);
    stage(1, 32);                  // 6 loads in flight; KK >= 64 guaranteed
    int cur = 0;
    for (int t = 0; t < nsteps; ++t) {
        // wait for group t (oldest); keep the newer group in flight
        if (t + 1 < nsteps) asm volatile("s_waitcnt vmcnt(3)" ::: "memory");
        else                asm volatile("s_waitcnt vmcnt(0)" ::: "memory");
        __builtin_amdgcn_s_barrier();          // all waves: buf[cur] ready
        asm volatile("" ::: "memory");

        s16x8 af[4], bg[4];
        {
            const int rl = lane & 15;
            const int cw = lane >> 4;
#pragma unroll
            for (int m = 0; m < 4; ++m) {
                int r  = wr * 64 + m * 16 + rl;
                int sl = cw ^ ((r + (r >> 2)) & 3);
                af[m] = *(const s16x8*)(&sA[cur][r * 32 + sl * 8]);
                int c  = wc * 64 + m * 16 + rl;
                int sc = cw ^ ((c + (c >> 2)) & 3);
                bg[m] = *(const s16x8*)(&sB[cur][c * 32 + sc * 8]);
            }
        }
        // MFMAs consume all af/bg (compiler interleaves reads+MFMA with
        // fine-grained lgkmcnt); after them this wave's LDS reads are done.
#pragma unroll
        for (int m = 0; m < 4; ++m)
#pragma unroll
            for (int n = 0; n < 4; ++n)
                acc[m][n] = __builtin_amdgcn_mfma_f32_16x16x32_bf16(af[m], bg[n], acc[m][n], 0, 0, 0);

        __builtin_amdgcn_s_barrier();          // all waves done READING buf[cur]
        asm volatile("" ::: "memory");
        if (t + 2 < nsteps) stage(cur, (t + 2) * 32);   // re-stage 2 ahead
        cur ^= 1;
    }

    // C/D layout: col=lane&15, row=(lane>>4)*4+reg
    const int rbase = row0 + rloc;
    if (mode == 2) {
        float bi[4];
#pragma unroll
        for (int gg2 = 0; gg2 < 4; ++gg2) bi[gg2] = bih[gg2 * 256 + ch] + bhh[gg2 * 256 + ch];
#pragma unroll
        for (int m = 0; m < 4; ++m) {
#pragma unroll
            for (int r = 0; r < 4; ++r) {
                int row = rbase + m * 16 + r;
                float gi = acc[m][0][r] + bi[0];
                float gf = acc[m][1][r] + bi[1];
                float gg = acc[m][2][r] + bi[2];
                float go = acc[m][3][r] + bi[3];
                size_t idx = (size_t)row * HID + ch;
                float c2 = fsigm(gf) * co_pre[m][r] + fsigm(gi) * ftanh(gg);
                float h2 = fsigm(go) * ftanh(c2);
                c_out[idx] = c2;
                h_out[idx] = f2b(h2);
            }
        }
    } else {
        const int cbase = col0 + wc * 64 + l16;
#pragma unroll
        for (int n = 0; n < 4; ++n) {
            int col = cbase + n * 16;
            float ba = bias ? bias[col] : 0.f;
#pragma unroll
            for (int m = 0; m < 4; ++m) {
#pragma unroll
                for (int r = 0; r < 4; ++r) {
                    int row = rbase + m * 16 + r;
                    float v = acc[m][n][r] + ba;
                    size_t idx = (size_t)row * N + col;
                    if (mode == 1) Cb[idx] = f2b(v);
                    else           Cf[idx] = v;
                }
            }
        }
    }
}

// ---------------- fused GATv2 (softmax + aggregate + bias + LN + ELU) -------
// one 64-lane wave per dst node; lane l = channel h*64+l per head h.
// xlr: [MP][512] bf16, cols 0..255 = lin_l(x), 256..511 = lin_r(x).
__global__ __launch_bounds__(256) void gat_fused(
    const short* __restrict__ xlr, const int* __restrict__ rowptr,
    const int* __restrict__ esrc, const float* __restrict__ att,
    const float* __restrict__ gb, const float* __restrict__ lg,
    const float* __restrict__ lb, short* __restrict__ outb)
{
    int i    = blockIdx.x * 4 + (threadIdx.x >> 6);
    int lane = threadIdx.x & 63;
    if (i >= NN) return;
    float xr[HEADS], at[HEADS];
#pragma unroll
    for (int h = 0; h < HEADS; ++h) {
        xr[h] = b2f(xlr[(size_t)i * 512 + 256 + h * 64 + lane]);
        at[h] = att[h * 64 + lane];
    }
    float mx[HEADS], sm[HEADS], ac[HEADS];
#pragma unroll
    for (int h = 0; h < HEADS; ++h) { mx[h] = -INFINITY; sm[h] = 0.f; ac[h] = 0.f; }

    int lo = rowptr[i], hi = rowptr[i + 1];
    for (int e = lo; e < hi; ++e) {
        int s = esrc[e];
        float xs[HEADS], p[HEADS];
#pragma unroll
        for (int h = 0; h < HEADS; ++h) {
            xs[h] = b2f(xlr[(size_t)s * 512 + h * 64 + lane]);
            float v = xs[h] + xr[h];
            v = (v >= 0.f) ? v : 0.2f * v;
            p[h] = v * at[h];
        }
#pragma unroll
        for (int h = 0; h < HEADS; ++h) p[h] = wsum64(p[h]);
#pragma unroll
        for (int h = 0; h < HEADS; ++h) {
            float mn = fmaxf(mx[h], p[h]);
            float sc = fexp(mx[h] - mn);     // first iter: exp(-inf)=0
            float a  = fexp(p[h] - mn);
            sm[h] = sm[h] * sc + a;
            ac[h] = ac[h] * sc + a * xs[h];
            mx[h] = mn;
        }
    }
    // y = ac/sm (+ gat bias), then LayerNorm(256) + ELU, write bf16
    float val[HEADS], s1 = 0.f, s2 = 0.f;
#pragma unroll
    for (int h = 0; h < HEADS; ++h) {
        float v = ac[h] * frcp(sm[h]) + gb[h * 64 + lane];
        val[h] = v; s1 += v; s2 += v * v;
    }
    s1 = wsum64(s1); s2 = wsum64(s2);
    float mean = s1 * (1.f / 256.f);
    float var  = s2 * (1.f / 256.f) - mean * mean;
    float inv  = rsqrtf(var + 1e-5f);
#pragma unroll
    for (int h = 0; h < HEADS; ++h) {
        float v = (val[h] - mean) * inv * lg[h * 64 + lane] + lb[h * 64 + lane];
        v = (v > 0.f) ? v : (fexp(v) - 1.f);
        outb[(size_t)i * HID + h * 64 + lane] = f2b(v);
    }
}

// ---------------- LayerNorm (+act) for the MLP head -------------------------
__global__ __launch_bounds__(256) void ln_act_kernel(
    const float* __restrict__ in, const float* __restrict__ gamma,
    const float* __restrict__ beta, float* __restrict__ outf,
    short* __restrict__ outb, int width, int act)
{
    int row = blockIdx.x;
    const float* ip = in + (size_t)row * width;
    float vals[3];
    float s = 0.f, ss = 0.f;
    int nw = width >> 8;
    for (int i = 0; i < nw; ++i) {
        int c = threadIdx.x + (i << 8);
        float v = ip[c];
        vals[i] = v; s += v; ss += v * v;
    }
#pragma unroll
    for (int off = 32; off > 0; off >>= 1) {
        s  += __shfl_down(s, off);
        ss += __shfl_down(ss, off);
    }
    __shared__ float sh[8];
    int wv = threadIdx.x >> 6, lane = threadIdx.x & 63;
    if (lane == 0) { sh[wv] = s; sh[4 + wv] = ss; }
    __syncthreads();
    if (threadIdx.x == 0) {
        sh[0] = sh[0] + sh[1] + sh[2] + sh[3];
        sh[4] = sh[4] + sh[5] + sh[6] + sh[7];
    }
    __syncthreads();
    float mean = sh[0] / width;
    float var  = sh[4] / width - mean * mean;
    float inv  = rsqrtf(var + 1e-5f);
    for (int i = 0; i < nw; ++i) {
        int c = threadIdx.x + (i << 8);
        float v = (vals[i] - mean) * inv * gamma[c] + beta[c];
        if (act == 1) v = fmaxf(v, 0.f);
        if (outb) outb[(size_t)row * width + c] = f2b(v);
        else      outf[(size_t)row * width + c] = v;
    }
}

// ---------------- sorted-batch mean pool ------------------------------------
__global__ __launch_bounds__(256) void pool_mean(
    const short* __restrict__ h, const int* __restrict__ batch,
    short* __restrict__ poolb)
{
    int b    = blockIdx.x * 4 + (threadIdx.x >> 6);
    int lane = threadIdx.x & 63;
    if (b >= BG) return;
    auto lbound = [&](int key) {
        int lo = 0, hi = NN;
        while (lo < hi) { int mid = (lo + hi) >> 1; if (batch[mid] < key) lo = mid + 1; else hi = mid; }
        return lo;
    };
    int lo = lbound(b), hi = lbound(b + 1);
    float acc[HEADS] = {0.f, 0.f, 0.f, 0.f};
    for (int r = lo; r < hi; ++r)
#pragma unroll
        for (int hh = 0; hh < HEADS; ++hh)
            acc[hh] += b2f(h[(size_t)r * HID + hh * 64 + lane]);
    float inv = 1.f / fmaxf((float)(hi - lo), 1.f);
#pragma unroll
    for (int hh = 0; hh < HEADS; ++hh)
        poolb[(size_t)b * HID + hh * 64 + lane] = f2b(acc[hh] * inv);
}

// ---------------------------------------------------------------------------
extern "C" void kernel_launch(void* const* d_in, const int* in_sizes, int n_in,
                              void* d_out, int out_size, void* d_ws, size_t ws_size,
                              hipStream_t stream)
{
    (void)in_sizes; (void)n_in; (void)out_size; (void)ws_size;
    const float* x      = (const float*)d_in[0];
    const int*   ei     = (const int*)d_in[1];
    const int*   batch  = (const int*)d_in[2];
    const float* lin0_w = (const float*)d_in[4];
    const float* lin0_b = (const float*)d_in[5];
    const float* r0_wih = (const float*)d_in[6];
    const float* r0_bih = (const float*)d_in[8];
    const float* r0_bhh = (const float*)d_in[9];
    const float* mh1_w  = (const float*)d_in[46];
    const float* mh1_b  = (const float*)d_in[47];
    const float* ln1_g  = (const float*)d_in[48];
    const float* ln1_b  = (const float*)d_in[49];
    const float* mh2_w  = (const float*)d_in[50];
    const float* mh2_b  = (const float*)d_in[51];
    const float* ln2_g  = (const float*)d_in[52];
    const float* ln2_b  = (const float*)d_in[53];
    float* out = (float*)d_out;

    // ---- workspace bump allocation ----
    char* wsb = (char*)d_ws;
    auto alloc = [&](size_t bytes) -> void* {
        void* p = (void*)wsb;
        wsb += (bytes + 255) & ~(size_t)255;
        return p;
    };
    const size_t NH = (size_t)MP * HID;
    float* cb   = (float*)alloc(NH * 4);          // LSTM cell state f32
    short* hA   = (short*)alloc(NH * 2);          // h ping
    short* hB   = (short*)alloc(NH * 2);          // h pong
    short* ybb  = (short*)alloc(NH * 2);          // LSTM-input / x0 bf16
    short* xlr  = (short*)alloc((size_t)MP * 512 * 2);  // [xl|xr] bf16
    int*   deg    = (int*)alloc((size_t)NN * 4);
    int*   rowptr = (int*)alloc((size_t)(NN + 1) * 4);
    int*   cursor = (int*)alloc((size_t)NN * 4);
    int*   esrc   = (int*)alloc((size_t)EP * 4);
    int*   bsum   = (int*)alloc((size_t)SCB * 4);
    int*   bpre   = (int*)alloc((size_t)SCB * 4);
    // weights bf16
    short* w_lin0 = (short*)alloc((size_t)256 * KP0 * 2);
    short* w_r0   = (short*)alloc((size_t)G4H * 256 * 2);
    short* w_lr[3]; short* w_ih[3]; short* w_hh[3]; float* blr[3];
    for (int l = 0; l < 3; ++l) {
        int Kp = (l == 0) ? KP0 : 256;
        w_lr[l] = (short*)alloc((size_t)512 * Kp * 2);
        w_ih[l] = (short*)alloc((size_t)G4H * 256 * 2);
        w_hh[l] = (short*)alloc((size_t)G4H * 256 * 2);
        blr[l]  = (float*)alloc(512 * 4);
    }
    short* w_m1 = (short*)alloc((size_t)NH1 * 256 * 2);
    short* w_m2 = (short*)alloc((size_t)NH2 * NH1 * 2);
    // xb (layer-0 padded input) with head temps aliased over it (head runs
    // only after xb is dead)
    short* xb = (short*)alloc((size_t)MP * KP0 * 2);   // 64 MB
    float* z1    = (float*)xb;                          // BG*NH1 f32 (8.4MB)
    short* z1b   = (short*)(z1 + (size_t)BG * NH1);     // BG*NH1 bf16
    short* poolb = z1b + (size_t)BG * NH1;              // BG*HID bf16

    // mode 0/1 GEMM; 1-D grid with XCD swizzle (requires (M/256)%8==0)
    auto G = [&](const short* A, const short* B, int K, const float* bias,
                 float* Cf, short* Cbb, int M, int N, int mode) {
        int nrp = M / 256, nct = N / 128;
        mfma_gemm<<<dim3(nrp * nct), dim3(512), 0, stream>>>(
            A, B, K, nullptr, nullptr, 0, bias,
            nullptr, nullptr, nullptr, nullptr, nullptr, Cf, Cbb, N, mode, nct);
    };
    // mode 2 LSTM GEMM
    auto GL = [&](const short* A1, const short* B1, int K1,
                  const short* A2, const short* B2, int K2,
                  const float* bih, const float* bhh,
                  const float* ci, float* co, short* ho) {
        mfma_gemm<<<dim3((MP / 256) * 8), dim3(512), 0, stream>>>(
            A1, B1, K1, A2, B2, K2, nullptr,
            bih, bhh, ci, co, ho, nullptr, nullptr, G4H, 2, 8);
    };

    // ---- batched conversions (1 dispatch) + x conversion + concat ----
    conv_bf16<<<dim3(512), dim3(256), 0, stream>>>(x, xb, NN, MP, FIN, KP0);

    CPack cp; int nd = 0;
    auto addc = [&](const float* s, short* d, int rsrc, int rdst, int Ks, int Kd) {
        cp.d[nd++] = CDesc{ s, d, rdst * Kd, Ks, Kd, rsrc, 0 };
    };
    auto addg = [&](const float* s, short* d) {
        cp.d[nd++] = CDesc{ s, d, G4H * 256, 256, 256, G4H, 1 };
    };
    addc(lin0_w, w_lin0, 256, 256, FIN, KP0);
    addg(r0_wih, w_r0);
    for (int l = 0; l < 3; ++l) {
        int base = 10 + 12 * l;
        int K  = (l == 0) ? FIN : 256;
        int Kp = (l == 0) ? KP0 : 256;
        addc((const float*)d_in[base + 0], w_lr[l], 256, 256, K, Kp);
        addc((const float*)d_in[base + 2], w_lr[l] + (size_t)256 * Kp, 256, 256, K, Kp);
        addg((const float*)d_in[base + 8], w_ih[l]);
        addg((const float*)d_in[base + 9], w_hh[l]);
    }
    addc(mh1_w, w_m1, NH1, NH1, 256, 256);
    addc(mh2_w, w_m2, NH2, NH2, NH1, NH1);
    conv_pack<<<dim3(32, nd), dim3(256), 0, stream>>>(cp, nd);

    BPack bp;
    for (int l = 0; l < 3; ++l) {
        int base = 10 + 12 * l;
        bp.a[l] = (const float*)d_in[base + 1];
        bp.b[l] = (const float*)d_in[base + 3];
        bp.dst[l] = blr[l];
    }
    concat_pack<<<dim3(6), dim3(256), 0, stream>>>(bp);

    // ---- CSR build ----
    zero_f32<<<dim3(256), dim3(256), 0, stream>>>((float*)deg, NN);
    edge_hist<<<dim3((EP + 255) / 256), dim3(256), 0, stream>>>(ei, deg);
    scan_part<<<dim3(SCB), dim3(256), 0, stream>>>(deg, bsum);
    scan_tops<<<dim3(1), dim3(512), 0, stream>>>(bsum, bpre, rowptr);
    scan_fill<<<dim3(SCB), dim3(256), 0, stream>>>(deg, bpre, rowptr, cursor);
    edge_fill<<<dim3((EP + 255) / 256), dim3(256), 0, stream>>>(ei, rowptr, cursor, esrc);

    // ---- lin0 -> x0 (bf16); rnn0 LSTM from zero state (fused epilogue) ----
    G(xb, w_lin0, KP0, lin0_b, nullptr, ybb, MP, HID, 1);
    GL(ybb, w_r0, 256, nullptr, nullptr, 0, r0_bih, r0_bhh, nullptr, cb, hA);

    // ---- 3x (GATv2 -> LN+ELU -> LSTM) ----
    short* hprev = hA;
    short* hnext = hB;
    for (int l = 0; l < 3; ++l) {
        int base = 10 + 12 * l;
        const float* att = (const float*)d_in[base + 4];
        const float* gb  = (const float*)d_in[base + 5];
        const float* lg  = (const float*)d_in[base + 6];
        const float* lb  = (const float*)d_in[base + 7];
        const float* bih = (const float*)d_in[base + 10];
        const float* bhh = (const float*)d_in[base + 11];
        const short* Ain = (l == 0) ? xb : hprev;
        int K = (l == 0) ? KP0 : 256;

        G(Ain, w_lr[l], K, blr[l], nullptr, xlr, MP, 512, 1);
        gat_fused<<<dim3((NN + 3) / 4), dim3(256), 0, stream>>>(
            xlr, rowptr, esrc, att, gb, lg, lb, ybb);
        GL(ybb, w_ih[l], 256, hprev, w_hh[l], 256, bih, bhh, cb, cb, hnext);
        short* t = hprev; hprev = hnext; hnext = t;
    }

    // ---- mean pool (sorted batch) + MLP head ----
    pool_mean<<<dim3((BG + 3) / 4), dim3(256), 0, stream>>>(hprev, batch, poolb);
    G(poolb, w_m1, 256, mh1_b, z1, nullptr, BG, NH1, 0);
    ln_act_kernel<<<dim3(BG), dim3(256), 0, stream>>>(z1, ln1_g, ln1_b, nullptr, z1b, NH1, 1);
    G(z1b, w_m2, NH1, mh2_b, out, nullptr, BG, NH2, 0);
    ln_act_kernel<<<dim3(BG), dim3(256), 0, stream>>>(out, ln2_g, ln2_b, out, nullptr, NH2, 0);
}

// Round 21
// 1425.890 us; speedup vs baseline: 1.2729x; 1.1016x over previous
//
#include <hip/hip_runtime.h>
#include <hip/hip_bf16.h>
#include <math.h>

// ---------------------------------------------------------------------------
// GraphEncoder round 21: r20 (best: 1571us) + gat_fused restructured to
// quarter-wave-per-head. Old: each lane handled channel l of all 4 heads ->
// per edge 4x 2B gathers + 24 shfl_xor (6 per head). New: lane = head*16 +
// lanelet, 4 channels/lane -> per edge ONE 8B short4 gather + 4-FMA local
// dot + 4 shfl_xor (16-lane head reduce). Same math per head; 6x fewer
// cross-lane ops, far shorter per-edge serial chain.
// All other kernels identical to r20 (GEMM plateau triple-verified).
// ---------------------------------------------------------------------------

constexpr int NN    = 100000;
constexpr int EE    = 400000;
constexpr int EP    = EE + NN;      // 500000 (incl self loops)
constexpr int BG    = 4096;
constexpr int FIN   = 300;
constexpr int HEADS = 4;
constexpr int HID   = 256;
constexpr int G4H   = 1024;
constexpr int NH1   = 512;
constexpr int NH2   = 768;
constexpr int MP    = 100352;       // 392*256, 392 % 8 == 0
constexpr int KP0   = 320;          // FIN padded to mult of 32
constexpr int SCB   = 392;          // scan blocks (392*256 = 100352 >= NN)

typedef __attribute__((ext_vector_type(4))) float f32x4;
typedef __attribute__((ext_vector_type(8))) short s16x8;
typedef __attribute__((ext_vector_type(4))) short s16x4;

#define LOG2E 1.4426950408889634f

// fast HW transcendentals (v_exp_f32 = 2^x, v_rcp_f32)
__device__ inline float fexp(float x)  { return __builtin_amdgcn_exp2f(x * LOG2E); }
__device__ inline float frcp(float x)  { return __builtin_amdgcn_rcpf(x); }
__device__ inline float fsigm(float x) { return frcp(1.f + __builtin_amdgcn_exp2f(-LOG2E * x)); }
__device__ inline float ftanh(float x) { return 1.f - 2.f * frcp(1.f + __builtin_amdgcn_exp2f(2.f * LOG2E * x)); }

__device__ inline float b2f(short s) { return __uint_as_float(((unsigned)(unsigned short)s) << 16); }
__device__ inline short f2b(float f) {
    unsigned u = __float_as_uint(f);
    u += 0x7fff + ((u >> 16) & 1);          // round-to-nearest-even
    return (short)(u >> 16);
}
__device__ inline float wsum64(float v) {
#pragma unroll
    for (int o = 32; o > 0; o >>= 1) v += __shfl_xor(v, o);
    return v;
}

// ---------------- utility kernels -------------------------------------------
__global__ __launch_bounds__(256) void zero_f32(float* __restrict__ p, long long n)
{
    long long i = (long long)blockIdx.x * 256 + threadIdx.x;
    long long stride = (long long)gridDim.x * 256;
    for (; i < n; i += stride) p[i] = 0.f;
}

// f32 -> bf16 with row/col zero padding (used only for the big x conversion)
__global__ __launch_bounds__(256) void conv_bf16(
    const float* __restrict__ src, short* __restrict__ dst,
    int rsrc, int rdst, int Ks, int Kd)
{
    long long n = (long long)rdst * Kd;
    long long stride = (long long)gridDim.x * 256;
    for (long long i = (long long)blockIdx.x * 256 + threadIdx.x; i < n; i += stride) {
        int r = (int)(i / Kd);
        int k = (int)(i - (long long)r * Kd);
        float v = (r < rsrc && k < Ks) ? src[(long long)r * Ks + k] : 0.f;
        dst[i] = f2b(v);
    }
}

// ---- batched weight conversions: one dispatch for all small tensors --------
// gate==0: pad-convert [rsrc x Ks] -> [n/Kd x Kd] bf16
// gate==1: gate-interleaved LSTM pack (Ks = K), n = 1024*K
struct CDesc { const float* src; short* dst; int n, Ks, Kd, rsrc, gate; };
struct CPack { CDesc d[16]; };

__global__ __launch_bounds__(256) void conv_pack(CPack p, int nd)
{
    int di = blockIdx.y;
    if (di >= nd) return;
    CDesc c = p.d[di];
    int stride = gridDim.x * 256;
    for (int i = blockIdx.x * 256 + threadIdx.x; i < c.n; i += stride) {
        float v;
        if (c.gate) {
            int K  = c.Ks;
            int pp = i / K, k = i - pp * K;
            int gate = (pp >> 4) & 3;
            int ch   = (pp >> 7) * 32 + ((pp >> 6) & 1) * 16 + (pp & 15);
            v = c.src[(size_t)(gate * 256 + ch) * K + k];
        } else {
            int r = i / c.Kd, k = i - r * c.Kd;
            v = (r < c.rsrc && k < c.Ks) ? c.src[(size_t)r * c.Ks + k] : 0.f;
        }
        c.dst[i] = f2b(v);
    }
}

// ---- batched bias concat (3 layers x [bl|br] -> blr f32[512]) --------------
struct BPack { const float* a[3]; const float* b[3]; float* dst[3]; };
__global__ __launch_bounds__(256) void concat_pack(BPack p)
{
    int l = blockIdx.x >> 1;
    int half = blockIdx.x & 1;
    const float* s = half ? p.b[l] : p.a[l];
    p.dst[l][half * 256 + threadIdx.x] = s[threadIdx.x];
}

// ---------------- CSR build -------------------------------------------------
__global__ __launch_bounds__(256) void edge_hist(const int* __restrict__ ei,
                                                 int* __restrict__ deg)
{
    int e = blockIdx.x * 256 + threadIdx.x;
    if (e >= EP) return;
    int d = (e < EE) ? ei[EE + e] : e - EE;
    atomicAdd(&deg[d], 1);
}

// pass 1: per-block chunk sums (coalesced)
__global__ __launch_bounds__(256) void scan_part(const int* __restrict__ deg,
                                                 int* __restrict__ bsum)
{
    int b = blockIdx.x, t = threadIdx.x;
    int i = b * 256 + t;
    int v = (i < NN) ? deg[i] : 0;
#pragma unroll
    for (int o = 32; o > 0; o >>= 1) v += __shfl_down(v, o);
    __shared__ int sh[4];
    if ((t & 63) == 0) sh[t >> 6] = v;
    __syncthreads();
    if (t == 0) bsum[b] = sh[0] + sh[1] + sh[2] + sh[3];
}

// pass 2: scan the 392 block sums (single small block)
__global__ __launch_bounds__(512) void scan_tops(const int* __restrict__ bsum,
                                                 int* __restrict__ bpre,
                                                 int* __restrict__ rowptr)
{
    __shared__ int sh[512];
    int t = threadIdx.x;
    int v = (t < SCB) ? bsum[t] : 0;
    sh[t] = v;
    __syncthreads();
    for (int off = 1; off < 512; off <<= 1) {
        int u = (t >= off) ? sh[t - off] : 0;
        __syncthreads();
        sh[t] += u;
        __syncthreads();
    }
    if (t < SCB) bpre[t] = sh[t] - v;          // exclusive prefix
    if (t == SCB - 1) rowptr[NN] = sh[t];      // total == EP
}

// pass 3: intra-block exclusive scan + write rowptr/cursor (coalesced)
__global__ __launch_bounds__(256) void scan_fill(const int* __restrict__ deg,
                                                 const int* __restrict__ bpre,
                                                 int* __restrict__ rowptr,
                                                 int* __restrict__ cursor)
{
    __shared__ int sh[256];
    int b = blockIdx.x, t = threadIdx.x;
    int i = b * 256 + t;
    int v = (i < NN) ? deg[i] : 0;
    sh[t] = v;
    __syncthreads();
    for (int off = 1; off < 256; off <<= 1) {
        int u = (t >= off) ? sh[t - off] : 0;
        __syncthreads();
        sh[t] += u;
        __syncthreads();
    }
    if (i < NN) {
        rowptr[i] = bpre[b] + sh[t] - v;       // exclusive
        cursor[i] = 0;
    }
}

__global__ __launch_bounds__(256) void edge_fill(const int* __restrict__ ei,
                                                 const int* __restrict__ rowptr,
                                                 int* __restrict__ cursor,
                                                 int* __restrict__ esrc)
{
    int e = blockIdx.x * 256 + threadIdx.x;
    if (e >= EP) return;
    int s, d;
    if (e < EE) { s = ei[e]; d = ei[EE + e]; }
    else        { s = d = e - EE; }
    int slot = rowptr[d] + atomicAdd(&cursor[d], 1);
    esrc[slot] = s;
}

// ---------------- MFMA GEMM with fused epilogues ----------------------------
// (identical to rounds 17/19/20 - triple-verified 184us plateau config)
__global__ __launch_bounds__(512) void mfma_gemm(
    const short* __restrict__ A1, const short* __restrict__ B1, int K1,
    const short* __restrict__ A2, const short* __restrict__ B2, int K2,
    const float* __restrict__ bias,
    const float* __restrict__ bih, const float* __restrict__ bhh,
    const float* __restrict__ c_in, float* __restrict__ c_out,
    short* __restrict__ h_out,
    float* __restrict__ Cf, short* __restrict__ Cb, int N, int mode, int nct)
{
    __shared__ __align__(16) short sA[2][256 * 32];   // 16KB each
    __shared__ __align__(16) short sB[2][128 * 32];   // 8KB each
    const int tid  = threadIdx.x;
    const int w    = tid >> 6, lane = tid & 63;
    const int wr   = w >> 1,  wc   = w & 1;      // 4x2 waves of 64x64
    // XCD-aware decode (consecutive bids round-robin across 8 XCDs)
    const int bid  = blockIdx.x;
    const int xcd  = bid & 7;
    const int slot = bid >> 3;
    const int g    = slot / nct;
    const int tcol = slot - g * nct;
    const int row0 = (g * 8 + xcd) * 256;
    const int col0 = tcol * 128;

    f32x4 acc[4][4];
#pragma unroll
    for (int m = 0; m < 4; ++m)
#pragma unroll
        for (int n = 0; n < 4; ++n) acc[m][n] = (f32x4){0.f, 0.f, 0.f, 0.f};

    const int rs = lane >> 2;
    const int cs = lane & 3;
    const int KK = K1 + K2;
    const int nsteps = KK >> 5;
    const int l16 = lane & 15;
    const int rloc = wr * 64 + ((lane >> 4) << 2);   // block-local base row

    // mode-2: prefetch c_in into regs; latency hides under the K-loop
    float co_pre[4][4] = {};
    const int ch = tcol * 32 + wc * 16 + l16;        // mode-2 channel
    if (mode == 2 && c_in) {
#pragma unroll
        for (int m = 0; m < 4; ++m)
#pragma unroll
            for (int r = 0; r < 4; ++r)
                co_pre[m][r] = c_in[(size_t)(row0 + rloc + m * 16 + r) * HID + ch];
    }

    // 3 global_load_lds per wave per stage call (2x A-seg, 1x B-seg)
    auto stage = [&](int buf, int k0) {
        const short* Ak; const short* Bk; int kk, ld;
        if (k0 < K1) { Ak = A1; Bk = B1; kk = k0;      ld = K1; }
        else         { Ak = A2; Bk = B2; kk = k0 - K1; ld = K2; }
#pragma unroll
        for (int i = 0; i < 2; ++i) {
            int seg = w * 2 + i;                     // 16 A-segs of 16 rows
            int row = seg * 16 + rs;
            int c8  = cs ^ ((row + (row >> 2)) & 3);
            const short* ga = Ak + (size_t)(row0 + row) * ld + kk + c8 * 8;
            short* la = &sA[buf][seg * 512 + lane * 8];
            __builtin_amdgcn_global_load_lds((const __attribute__((address_space(1))) void*)ga,
                                             (__attribute__((address_space(3))) void*)la, 16, 0, 0);
        }
        {
            int row = w * 16 + rs;                   // 8 B-segs of 16 rows
            int c8  = cs ^ ((row + (row >> 2)) & 3);
            const short* gb = Bk + (size_t)(col0 + row) * ld + kk + c8 * 8;
            short* lb = &sB[buf][w * 512 + lane * 8];
            __builtin_amdgcn_global_load_lds((const __attribute__((address_space(1))) void*)gb,
                                             (__attribute__((address_space(3))) void*)lb, 16, 0, 0);
        }
    };

    stage(0, 0);
    stage(1, 32);                  // 6 loads in flight; KK >= 64 guaranteed
    int cur = 0;
    for (int t = 0; t < nsteps; ++t) {
        // wait for group t (oldest); keep the newer group in flight
        if (t + 1 < nsteps) asm volatile("s_waitcnt vmcnt(3)" ::: "memory");
        else                asm volatile("s_waitcnt vmcnt(0)" ::: "memory");
        __builtin_amdgcn_s_barrier();          // all waves: buf[cur] ready
        asm volatile("" ::: "memory");

        s16x8 af[4], bg[4];
        {
            const int rl = lane & 15;
            const int cw = lane >> 4;
#pragma unroll
            for (int m = 0; m < 4; ++m) {
                int r  = wr * 64 + m * 16 + rl;
                int sl = cw ^ ((r + (r >> 2)) & 3);
                af[m] = *(const s16x8*)(&sA[cur][r * 32 + sl * 8]);
                int c  = wc * 64 + m * 16 + rl;
                int sc = cw ^ ((c + (c >> 2)) & 3);
                bg[m] = *(const s16x8*)(&sB[cur][c * 32 + sc * 8]);
            }
        }
        // MFMAs consume all af/bg (compiler interleaves reads+MFMA with
        // fine-grained lgkmcnt); after them this wave's LDS reads are done.
#pragma unroll
        for (int m = 0; m < 4; ++m)
#pragma unroll
            for (int n = 0; n < 4; ++n)
                acc[m][n] = __builtin_amdgcn_mfma_f32_16x16x32_bf16(af[m], bg[n], acc[m][n], 0, 0, 0);

        __builtin_amdgcn_s_barrier();          // all waves done READING buf[cur]
        asm volatile("" ::: "memory");
        if (t + 2 < nsteps) stage(cur, (t + 2) * 32);   // re-stage 2 ahead
        cur ^= 1;
    }

    // C/D layout: col=lane&15, row=(lane>>4)*4+reg
    const int rbase = row0 + rloc;
    if (mode == 2) {
        float bi[4];
#pragma unroll
        for (int gg2 = 0; gg2 < 4; ++gg2) bi[gg2] = bih[gg2 * 256 + ch] + bhh[gg2 * 256 + ch];
#pragma unroll
        for (int m = 0; m < 4; ++m) {
#pragma unroll
            for (int r = 0; r < 4; ++r) {
                int row = rbase + m * 16 + r;
                float gi = acc[m][0][r] + bi[0];
                float gf = acc[m][1][r] + bi[1];
                float gg = acc[m][2][r] + bi[2];
                float go = acc[m][3][r] + bi[3];
                size_t idx = (size_t)row * HID + ch;
                float c2 = fsigm(gf) * co_pre[m][r] + fsigm(gi) * ftanh(gg);
                float h2 = fsigm(go) * ftanh(c2);
                c_out[idx] = c2;
                h_out[idx] = f2b(h2);
            }
        }
    } else {
        const int cbase = col0 + wc * 64 + l16;
#pragma unroll
        for (int n = 0; n < 4; ++n) {
            int col = cbase + n * 16;
            float ba = bias ? bias[col] : 0.f;
#pragma unroll
            for (int m = 0; m < 4; ++m) {
#pragma unroll
                for (int r = 0; r < 4; ++r) {
                    int row = rbase + m * 16 + r;
                    float v = acc[m][n][r] + ba;
                    size_t idx = (size_t)row * N + col;
                    if (mode == 1) Cb[idx] = f2b(v);
                    else           Cf[idx] = v;
                }
            }
        }
    }
}

// ---------------- fused GATv2 (softmax + aggregate + bias + LN + ELU) -------
// one 64-lane wave per dst node; QUARTER-WAVE PER HEAD: lane = head*16 +
// lanelet, each lane owns 4 channels (cb = head*64 + lanelet*4).
// Per edge: one 8B short4 gather + 4-FMA local dot + 4 shfl_xor (16-lane
// reduce within the head's quarter). Online softmax state per quarter.
// xlr: [MP][512] bf16, cols 0..255 = lin_l(x), 256..511 = lin_r(x).
__global__ __launch_bounds__(256) void gat_fused(
    const short* __restrict__ xlr, const int* __restrict__ rowptr,
    const int* __restrict__ esrc, const float* __restrict__ att,
    const float* __restrict__ gb, const float* __restrict__ lg,
    const float* __restrict__ lb, short* __restrict__ outb)
{
    int i    = blockIdx.x * 4 + (threadIdx.x >> 6);
    int lane = threadIdx.x & 63;
    if (i >= NN) return;
    const int cb = (lane >> 4) * 64 + (lane & 15) * 4;   // channel base

    float xr4[4], at4[4];
    {
        s16x4 v = *(const s16x4*)(&xlr[(size_t)i * 512 + 256 + cb]);
#pragma unroll
        for (int j = 0; j < 4; ++j) { xr4[j] = b2f(v[j]); at4[j] = att[cb + j]; }
    }
    float mx = -INFINITY, sm = 0.f;
    float ac[4] = {0.f, 0.f, 0.f, 0.f};

    int lo = rowptr[i], hi = rowptr[i + 1];
    for (int e = lo; e < hi; ++e) {
        int s = esrc[e];
        s16x4 xv = *(const s16x4*)(&xlr[(size_t)s * 512 + cb]);
        float xs[4], pl = 0.f;
#pragma unroll
        for (int j = 0; j < 4; ++j) {
            xs[j] = b2f(xv[j]);
            float v = xs[j] + xr4[j];
            v = (v >= 0.f) ? v : 0.2f * v;
            pl += v * at4[j];
        }
#pragma unroll
        for (int o = 1; o < 16; o <<= 1) pl += __shfl_xor(pl, o);   // head logit
        float mn = fmaxf(mx, pl);
        float sc = fexp(mx - mn);            // first iter: exp(-inf)=0
        float a  = fexp(pl - mn);
        sm = sm * sc + a;
#pragma unroll
        for (int j = 0; j < 4; ++j) ac[j] = ac[j] * sc + a * xs[j];
        mx = mn;
    }
    // y = ac/sm (+ gat bias), then LayerNorm(256) + ELU, write bf16
    float val[4], s1 = 0.f, s2 = 0.f;
    float ism = frcp(sm);
#pragma unroll
    for (int j = 0; j < 4; ++j) {
        float v = ac[j] * ism + gb[cb + j];
        val[j] = v; s1 += v; s2 += v * v;
    }
    s1 = wsum64(s1); s2 = wsum64(s2);
    float mean = s1 * (1.f / 256.f);
    float var  = s2 * (1.f / 256.f) - mean * mean;
    float inv  = rsqrtf(var + 1e-5f);
    s16x4 ov;
#pragma unroll
    for (int j = 0; j < 4; ++j) {
        float v = (val[j] - mean) * inv * lg[cb + j] + lb[cb + j];
        v = (v > 0.f) ? v : (fexp(v) - 1.f);
        ov[j] = f2b(v);
    }
    *(s16x4*)(&outb[(size_t)i * HID + cb]) = ov;
}

// ---------------- LayerNorm (+act) for the MLP head -------------------------
__global__ __launch_bounds__(256) void ln_act_kernel(
    const float* __restrict__ in, const float* __restrict__ gamma,
    const float* __restrict__ beta, float* __restrict__ outf,
    short* __restrict__ outb, int width, int act)
{
    int row = blockIdx.x;
    const float* ip = in + (size_t)row * width;
    float vals[3];
    float s = 0.f, ss = 0.f;
    int nw = width >> 8;
    for (int i = 0; i < nw; ++i) {
        int c = threadIdx.x + (i << 8);
        float v = ip[c];
        vals[i] = v; s += v; ss += v * v;
    }
#pragma unroll
    for (int off = 32; off > 0; off >>= 1) {
        s  += __shfl_down(s, off);
        ss += __shfl_down(ss, off);
    }
    __shared__ float sh[8];
    int wv = threadIdx.x >> 6, lane = threadIdx.x & 63;
    if (lane == 0) { sh[wv] = s; sh[4 + wv] = ss; }
    __syncthreads();
    if (threadIdx.x == 0) {
        sh[0] = sh[0] + sh[1] + sh[2] + sh[3];
        sh[4] = sh[4] + sh[5] + sh[6] + sh[7];
    }
    __syncthreads();
    float mean = sh[0] / width;
    float var  = sh[4] / width - mean * mean;
    float inv  = rsqrtf(var + 1e-5f);
    for (int i = 0; i < nw; ++i) {
        int c = threadIdx.x + (i << 8);
        float v = (vals[i] - mean) * inv * gamma[c] + beta[c];
        if (act == 1) v = fmaxf(v, 0.f);
        if (outb) outb[(size_t)row * width + c] = f2b(v);
        else      outf[(size_t)row * width + c] = v;
    }
}

// ---------------- sorted-batch mean pool ------------------------------------
__global__ __launch_bounds__(256) void pool_mean(
    const short* __restrict__ h, const int* __restrict__ batch,
    short* __restrict__ poolb)
{
    int b    = blockIdx.x * 4 + (threadIdx.x >> 6);
    int lane = threadIdx.x & 63;
    if (b >= BG) return;
    auto lbound = [&](int key) {
        int lo = 0, hi = NN;
        while (lo < hi) { int mid = (lo + hi) >> 1; if (batch[mid] < key) lo = mid + 1; else hi = mid; }
        return lo;
    };
    int lo = lbound(b), hi = lbound(b + 1);
    float acc[HEADS] = {0.f, 0.f, 0.f, 0.f};
    for (int r = lo; r < hi; ++r)
#pragma unroll
        for (int hh = 0; hh < HEADS; ++hh)
            acc[hh] += b2f(h[(size_t)r * HID + hh * 64 + lane]);
    float inv = 1.f / fmaxf((float)(hi - lo), 1.f);
#pragma unroll
    for (int hh = 0; hh < HEADS; ++hh)
        poolb[(size_t)b * HID + hh * 64 + lane] = f2b(acc[hh] * inv);
}

// ---------------------------------------------------------------------------
extern "C" void kernel_launch(void* const* d_in, const int* in_sizes, int n_in,
                              void* d_out, int out_size, void* d_ws, size_t ws_size,
                              hipStream_t stream)
{
    (void)in_sizes; (void)n_in; (void)out_size; (void)ws_size;
    const float* x      = (const float*)d_in[0];
    const int*   ei     = (const int*)d_in[1];
    const int*   batch  = (const int*)d_in[2];
    const float* lin0_w = (const float*)d_in[4];
    const float* lin0_b = (const float*)d_in[5];
    const float* r0_wih = (const float*)d_in[6];
    const float* r0_bih = (const float*)d_in[8];
    const float* r0_bhh = (const float*)d_in[9];
    const float* mh1_w  = (const float*)d_in[46];
    const float* mh1_b  = (const float*)d_in[47];
    const float* ln1_g  = (const float*)d_in[48];
    const float* ln1_b  = (const float*)d_in[49];
    const float* mh2_w  = (const float*)d_in[50];
    const float* mh2_b  = (const float*)d_in[51];
    const float* ln2_g  = (const float*)d_in[52];
    const float* ln2_b  = (const float*)d_in[53];
    float* out = (float*)d_out;

    // ---- workspace bump allocation ----
    char* wsb = (char*)d_ws;
    auto alloc = [&](size_t bytes) -> void* {
        void* p = (void*)wsb;
        wsb += (bytes + 255) & ~(size_t)255;
        return p;
    };
    const size_t NH = (size_t)MP * HID;
    float* cb   = (float*)alloc(NH * 4);          // LSTM cell state f32
    short* hA   = (short*)alloc(NH * 2);          // h ping
    short* hB   = (short*)alloc(NH * 2);          // h pong
    short* ybb  = (short*)alloc(NH * 2);          // LSTM-input / x0 bf16
    short* xlr  = (short*)alloc((size_t)MP * 512 * 2);  // [xl|xr] bf16
    int*   deg    = (int*)alloc((size_t)NN * 4);
    int*   rowptr = (int*)alloc((size_t)(NN + 1) * 4);
    int*   cursor = (int*)alloc((size_t)NN * 4);
    int*   esrc   = (int*)alloc((size_t)EP * 4);
    int*   bsum   = (int*)alloc((size_t)SCB * 4);
    int*   bpre   = (int*)alloc((size_t)SCB * 4);
    // weights bf16
    short* w_lin0 = (short*)alloc((size_t)256 * KP0 * 2);
    short* w_r0   = (short*)alloc((size_t)G4H * 256 * 2);
    short* w_lr[3]; short* w_ih[3]; short* w_hh[3]; float* blr[3];
    for (int l = 0; l < 3; ++l) {
        int Kp = (l == 0) ? KP0 : 256;
        w_lr[l] = (short*)alloc((size_t)512 * Kp * 2);
        w_ih[l] = (short*)alloc((size_t)G4H * 256 * 2);
        w_hh[l] = (short*)alloc((size_t)G4H * 256 * 2);
        blr[l]  = (float*)alloc(512 * 4);
    }
    short* w_m1 = (short*)alloc((size_t)NH1 * 256 * 2);
    short* w_m2 = (short*)alloc((size_t)NH2 * NH1 * 2);
    // xb (layer-0 padded input) with head temps aliased over it (head runs
    // only after xb is dead)
    short* xb = (short*)alloc((size_t)MP * KP0 * 2);   // 64 MB
    float* z1    = (float*)xb;                          // BG*NH1 f32 (8.4MB)
    short* z1b   = (short*)(z1 + (size_t)BG * NH1);     // BG*NH1 bf16
    short* poolb = z1b + (size_t)BG * NH1;              // BG*HID bf16

    // mode 0/1 GEMM; 1-D grid with XCD swizzle (requires (M/256)%8==0)
    auto G = [&](const short* A, const short* B, int K, const float* bias,
                 float* Cf, short* Cbb, int M, int N, int mode) {
        int nrp = M / 256, nct = N / 128;
        mfma_gemm<<<dim3(nrp * nct), dim3(512), 0, stream>>>(
            A, B, K, nullptr, nullptr, 0, bias,
            nullptr, nullptr, nullptr, nullptr, nullptr, Cf, Cbb, N, mode, nct);
    };
    // mode 2 LSTM GEMM
    auto GL = [&](const short* A1, const short* B1, int K1,
                  const short* A2, const short* B2, int K2,
                  const float* bih, const float* bhh,
                  const float* ci, float* co, short* ho) {
        mfma_gemm<<<dim3((MP / 256) * 8), dim3(512), 0, stream>>>(
            A1, B1, K1, A2, B2, K2, nullptr,
            bih, bhh, ci, co, ho, nullptr, nullptr, G4H, 2, 8);
    };

    // ---- batched conversions (1 dispatch) + x conversion + concat ----
    conv_bf16<<<dim3(512), dim3(256), 0, stream>>>(x, xb, NN, MP, FIN, KP0);

    CPack cp; int nd = 0;
    auto addc = [&](const float* s, short* d, int rsrc, int rdst, int Ks, int Kd) {
        cp.d[nd++] = CDesc{ s, d, rdst * Kd, Ks, Kd, rsrc, 0 };
    };
    auto addg = [&](const float* s, short* d) {
        cp.d[nd++] = CDesc{ s, d, G4H * 256, 256, 256, G4H, 1 };
    };
    addc(lin0_w, w_lin0, 256, 256, FIN, KP0);
    addg(r0_wih, w_r0);
    for (int l = 0; l < 3; ++l) {
        int base = 10 + 12 * l;
        int K  = (l == 0) ? FIN : 256;
        int Kp = (l == 0) ? KP0 : 256;
        addc((const float*)d_in[base + 0], w_lr[l], 256, 256, K, Kp);
        addc((const float*)d_in[base + 2], w_lr[l] + (size_t)256 * Kp, 256, 256, K, Kp);
        addg((const float*)d_in[base + 8], w_ih[l]);
        addg((const float*)d_in[base + 9], w_hh[l]);
    }
    addc(mh1_w, w_m1, NH1, NH1, 256, 256);
    addc(mh2_w, w_m2, NH2, NH2, NH1, NH1);
    conv_pack<<<dim3(32, nd), dim3(256), 0, stream>>>(cp, nd);

    BPack bp;
    for (int l = 0; l < 3; ++l) {
        int base = 10 + 12 * l;
        bp.a[l] = (const float*)d_in[base + 1];
        bp.b[l] = (const float*)d_in[base + 3];
        bp.dst[l] = blr[l];
    }
    concat_pack<<<dim3(6), dim3(256), 0, stream>>>(bp);

    // ---- CSR build ----
    zero_f32<<<dim3(256), dim3(256), 0, stream>>>((float*)deg, NN);
    edge_hist<<<dim3((EP + 255) / 256), dim3(256), 0, stream>>>(ei, deg);
    scan_part<<<dim3(SCB), dim3(256), 0, stream>>>(deg, bsum);
    scan_tops<<<dim3(1), dim3(512), 0, stream>>>(bsum, bpre, rowptr);
    scan_fill<<<dim3(SCB), dim3(256), 0, stream>>>(deg, bpre, rowptr, cursor);
    edge_fill<<<dim3((EP + 255) / 256), dim3(256), 0, stream>>>(ei, rowptr, cursor, esrc);

    // ---- lin0 -> x0 (bf16); rnn0 LSTM from zero state (fused epilogue) ----
    G(xb, w_lin0, KP0, lin0_b, nullptr, ybb, MP, HID, 1);
    GL(ybb, w_r0, 256, nullptr, nullptr, 0, r0_bih, r0_bhh, nullptr, cb, hA);

    // ---- 3x (GATv2 -> LN+ELU -> LSTM) ----
    short* hprev = hA;
    short* hnext = hB;
    for (int l = 0; l < 3; ++l) {
        int base = 10 + 12 * l;
        const float* att = (const float*)d_in[base + 4];
        const float* gb  = (const float*)d_in[base + 5];
        const float* lg  = (const float*)d_in[base + 6];
        const float* lb  = (const float*)d_in[base + 7];
        const float* bih = (const float*)d_in[base + 10];
        const float* bhh = (const float*)d_in[base + 11];
        const short* Ain = (l == 0) ? xb : hprev;
        int K = (l == 0) ? KP0 : 256;

        G(Ain, w_lr[l], K, blr[l], nullptr, xlr, MP, 512, 1);
        gat_fused<<<dim3((NN + 3) / 4), dim3(256), 0, stream>>>(
            xlr, rowptr, esrc, att, gb, lg, lb, ybb);
        GL(ybb, w_ih[l], 256, hprev, w_hh[l], 256, bih, bhh, cb, cb, hnext);
        short* t = hprev; hprev = hnext; hnext = t;
    }

    // ---- mean pool (sorted batch) + MLP head ----
    pool_mean<<<dim3((BG + 3) / 4), dim3(256), 0, stream>>>(hprev, batch, poolb);
    G(poolb, w_m1, 256, mh1_b, z1, nullptr, BG, NH1, 0);
    ln_act_kernel<<<dim3(BG), dim3(256), 0, stream>>>(z1, ln1_g, ln1_b, nullptr, z1b, NH1, 1);
    G(z1b, w_m2, NH1, mh2_b, out, nullptr, BG, NH2, 0);
    ln_act_kernel<<<dim3(BG), dim3(256), 0, stream>>>(out, ln2_g, ln2_b, out, nullptr, NH2, 0);
}

// Round 22
// 1419.045 us; speedup vs baseline: 1.2790x; 1.0048x over previous
//
#include <hip/hip_runtime.h>
#include <hip/hip_bf16.h>
#include <math.h>

// ---------------------------------------------------------------------------
// GraphEncoder round 22: r21 (best: 1426us) + algebraic lin0->rnn0 fold.
// x0 = x@lin0_w^T + lin0_b feeds ONLY rnn0, so
//   gates = x @ (r0_wih @ lin0_w)^T + (r0_wih@lin0_b + r0_bih + r0_bhh).
// Two tiny device kernels (fold_w: W' [1024x320] f32-accum -> bf16 gate-
// interleaved; fold_b: b' [1024] orig layout) replace the lin0 GEMM and the
// ybb round-trip for rnn0. rnn0 GL now reads xb directly (K=320).
// All other kernels identical to r21 (GEMM plateau quadruple-verified;
// quarter-wave gat_fused).
// ---------------------------------------------------------------------------

constexpr int NN    = 100000;
constexpr int EE    = 400000;
constexpr int EP    = EE + NN;      // 500000 (incl self loops)
constexpr int BG    = 4096;
constexpr int FIN   = 300;
constexpr int HEADS = 4;
constexpr int HID   = 256;
constexpr int G4H   = 1024;
constexpr int NH1   = 512;
constexpr int NH2   = 768;
constexpr int MP    = 100352;       // 392*256, 392 % 8 == 0
constexpr int KP0   = 320;          // FIN padded to mult of 32
constexpr int SCB   = 392;          // scan blocks (392*256 = 100352 >= NN)

typedef __attribute__((ext_vector_type(4))) float f32x4;
typedef __attribute__((ext_vector_type(8))) short s16x8;
typedef __attribute__((ext_vector_type(4))) short s16x4;

#define LOG2E 1.4426950408889634f

// fast HW transcendentals (v_exp_f32 = 2^x, v_rcp_f32)
__device__ inline float fexp(float x)  { return __builtin_amdgcn_exp2f(x * LOG2E); }
__device__ inline float frcp(float x)  { return __builtin_amdgcn_rcpf(x); }
__device__ inline float fsigm(float x) { return frcp(1.f + __builtin_amdgcn_exp2f(-LOG2E * x)); }
__device__ inline float ftanh(float x) { return 1.f - 2.f * frcp(1.f + __builtin_amdgcn_exp2f(2.f * LOG2E * x)); }

__device__ inline float b2f(short s) { return __uint_as_float(((unsigned)(unsigned short)s) << 16); }
__device__ inline short f2b(float f) {
    unsigned u = __float_as_uint(f);
    u += 0x7fff + ((u >> 16) & 1);          // round-to-nearest-even
    return (short)(u >> 16);
}
__device__ inline float wsum64(float v) {
#pragma unroll
    for (int o = 32; o > 0; o >>= 1) v += __shfl_xor(v, o);
    return v;
}

// ---------------- utility kernels -------------------------------------------
__global__ __launch_bounds__(256) void zero_f32(float* __restrict__ p, long long n)
{
    long long i = (long long)blockIdx.x * 256 + threadIdx.x;
    long long stride = (long long)gridDim.x * 256;
    for (; i < n; i += stride) p[i] = 0.f;
}

// f32 -> bf16 with row/col zero padding (used only for the big x conversion)
__global__ __launch_bounds__(256) void conv_bf16(
    const float* __restrict__ src, short* __restrict__ dst,
    int rsrc, int rdst, int Ks, int Kd)
{
    long long n = (long long)rdst * Kd;
    long long stride = (long long)gridDim.x * 256;
    for (long long i = (long long)blockIdx.x * 256 + threadIdx.x; i < n; i += stride) {
        int r = (int)(i / Kd);
        int k = (int)(i - (long long)r * Kd);
        float v = (r < rsrc && k < Ks) ? src[(long long)r * Ks + k] : 0.f;
        dst[i] = f2b(v);
    }
}

// ---- batched weight conversions: one dispatch for all small tensors --------
// gate==0: pad-convert [rsrc x Ks] -> [n/Kd x Kd] bf16
// gate==1: gate-interleaved LSTM pack (Ks = K), n = 1024*K
struct CDesc { const float* src; short* dst; int n, Ks, Kd, rsrc, gate; };
struct CPack { CDesc d[16]; };

__global__ __launch_bounds__(256) void conv_pack(CPack p, int nd)
{
    int di = blockIdx.y;
    if (di >= nd) return;
    CDesc c = p.d[di];
    int stride = gridDim.x * 256;
    for (int i = blockIdx.x * 256 + threadIdx.x; i < c.n; i += stride) {
        float v;
        if (c.gate) {
            int K  = c.Ks;
            int pp = i / K, k = i - pp * K;
            int gate = (pp >> 4) & 3;
            int ch   = (pp >> 7) * 32 + ((pp >> 6) & 1) * 16 + (pp & 15);
            v = c.src[(size_t)(gate * 256 + ch) * K + k];
        } else {
            int r = i / c.Kd, k = i - r * c.Kd;
            v = (r < c.rsrc && k < c.Ks) ? c.src[(size_t)r * c.Ks + k] : 0.f;
        }
        c.dst[i] = f2b(v);
    }
}

// ---- lin0->rnn0 fold: W'[packed p][k] = sum_h r0_wih[orig][h]*lin0_w[h][k] --
// one block per packed row p (gate-interleaved dest); 320 threads = cols.
__global__ __launch_bounds__(320) void fold_w(
    const float* __restrict__ wih, const float* __restrict__ lw,
    short* __restrict__ dst)
{
    __shared__ float row[256];
    int p = blockIdx.x;
    int gate = (p >> 4) & 3;
    int ch   = (p >> 7) * 32 + ((p >> 6) & 1) * 16 + (p & 15);
    int orig = gate * 256 + ch;
    for (int h = threadIdx.x; h < 256; h += 320)
        row[h] = wih[(size_t)orig * 256 + h];
    __syncthreads();
    int j = threadIdx.x;                 // 0..319
    float s = 0.f;
    if (j < FIN) {
        for (int h = 0; h < 256; ++h) s += row[h] * lw[(size_t)h * FIN + j];
    }
    dst[(size_t)p * KP0 + j] = f2b(s);
}

// b'[orig t] = r0_bih[t] + r0_bhh[t] + sum_h r0_wih[t][h]*lin0_b[h]
__global__ __launch_bounds__(256) void fold_b(
    const float* __restrict__ wih, const float* __restrict__ lb,
    const float* __restrict__ bih, const float* __restrict__ bhh,
    float* __restrict__ dst)
{
    int t = blockIdx.x * 256 + threadIdx.x;
    if (t >= G4H) return;
    float s = bih[t] + bhh[t];
    for (int h = 0; h < 256; ++h) s += wih[(size_t)t * 256 + h] * lb[h];
    dst[t] = s;
}

// ---- batched bias concat (3 layers x [bl|br] -> blr f32[512]) --------------
struct BPack { const float* a[3]; const float* b[3]; float* dst[3]; };
__global__ __launch_bounds__(256) void concat_pack(BPack p)
{
    int l = blockIdx.x >> 1;
    int half = blockIdx.x & 1;
    const float* s = half ? p.b[l] : p.a[l];
    p.dst[l][half * 256 + threadIdx.x] = s[threadIdx.x];
}

// ---------------- CSR build -------------------------------------------------
__global__ __launch_bounds__(256) void edge_hist(const int* __restrict__ ei,
                                                 int* __restrict__ deg)
{
    int e = blockIdx.x * 256 + threadIdx.x;
    if (e >= EP) return;
    int d = (e < EE) ? ei[EE + e] : e - EE;
    atomicAdd(&deg[d], 1);
}

// pass 1: per-block chunk sums (coalesced)
__global__ __launch_bounds__(256) void scan_part(const int* __restrict__ deg,
                                                 int* __restrict__ bsum)
{
    int b = blockIdx.x, t = threadIdx.x;
    int i = b * 256 + t;
    int v = (i < NN) ? deg[i] : 0;
#pragma unroll
    for (int o = 32; o > 0; o >>= 1) v += __shfl_down(v, o);
    __shared__ int sh[4];
    if ((t & 63) == 0) sh[t >> 6] = v;
    __syncthreads();
    if (t == 0) bsum[b] = sh[0] + sh[1] + sh[2] + sh[3];
}

// pass 2: scan the 392 block sums (single small block)
__global__ __launch_bounds__(512) void scan_tops(const int* __restrict__ bsum,
                                                 int* __restrict__ bpre,
                                                 int* __restrict__ rowptr)
{
    __shared__ int sh[512];
    int t = threadIdx.x;
    int v = (t < SCB) ? bsum[t] : 0;
    sh[t] = v;
    __syncthreads();
    for (int off = 1; off < 512; off <<= 1) {
        int u = (t >= off) ? sh[t - off] : 0;
        __syncthreads();
        sh[t] += u;
        __syncthreads();
    }
    if (t < SCB) bpre[t] = sh[t] - v;          // exclusive prefix
    if (t == SCB - 1) rowptr[NN] = sh[t];      // total == EP
}

// pass 3: intra-block exclusive scan + write rowptr/cursor (coalesced)
__global__ __launch_bounds__(256) void scan_fill(const int* __restrict__ deg,
                                                 const int* __restrict__ bpre,
                                                 int* __restrict__ rowptr,
                                                 int* __restrict__ cursor)
{
    __shared__ int sh[256];
    int b = blockIdx.x, t = threadIdx.x;
    int i = b * 256 + t;
    int v = (i < NN) ? deg[i] : 0;
    sh[t] = v;
    __syncthreads();
    for (int off = 1; off < 256; off <<= 1) {
        int u = (t >= off) ? sh[t - off] : 0;
        __syncthreads();
        sh[t] += u;
        __syncthreads();
    }
    if (i < NN) {
        rowptr[i] = bpre[b] + sh[t] - v;       // exclusive
        cursor[i] = 0;
    }
}

__global__ __launch_bounds__(256) void edge_fill(const int* __restrict__ ei,
                                                 const int* __restrict__ rowptr,
                                                 int* __restrict__ cursor,
                                                 int* __restrict__ esrc)
{
    int e = blockIdx.x * 256 + threadIdx.x;
    if (e >= EP) return;
    int s, d;
    if (e < EE) { s = ei[e]; d = ei[EE + e]; }
    else        { s = d = e - EE; }
    int slot = rowptr[d] + atomicAdd(&cursor[d], 1);
    esrc[slot] = s;
}

// ---------------- MFMA GEMM with fused epilogues ----------------------------
// (identical schedule to r17/r19/r20/r21; mode-2 now allows bhh == nullptr)
__global__ __launch_bounds__(512) void mfma_gemm(
    const short* __restrict__ A1, const short* __restrict__ B1, int K1,
    const short* __restrict__ A2, const short* __restrict__ B2, int K2,
    const float* __restrict__ bias,
    const float* __restrict__ bih, const float* __restrict__ bhh,
    const float* __restrict__ c_in, float* __restrict__ c_out,
    short* __restrict__ h_out,
    float* __restrict__ Cf, short* __restrict__ Cb, int N, int mode, int nct)
{
    __shared__ __align__(16) short sA[2][256 * 32];   // 16KB each
    __shared__ __align__(16) short sB[2][128 * 32];   // 8KB each
    const int tid  = threadIdx.x;
    const int w    = tid >> 6, lane = tid & 63;
    const int wr   = w >> 1,  wc   = w & 1;      // 4x2 waves of 64x64
    // XCD-aware decode (consecutive bids round-robin across 8 XCDs)
    const int bid  = blockIdx.x;
    const int xcd  = bid & 7;
    const int slot = bid >> 3;
    const int g    = slot / nct;
    const int tcol = slot - g * nct;
    const int row0 = (g * 8 + xcd) * 256;
    const int col0 = tcol * 128;

    f32x4 acc[4][4];
#pragma unroll
    for (int m = 0; m < 4; ++m)
#pragma unroll
        for (int n = 0; n < 4; ++n) acc[m][n] = (f32x4){0.f, 0.f, 0.f, 0.f};

    const int rs = lane >> 2;
    const int cs = lane & 3;
    const int KK = K1 + K2;
    const int nsteps = KK >> 5;
    const int l16 = lane & 15;
    const int rloc = wr * 64 + ((lane >> 4) << 2);   // block-local base row

    // mode-2: prefetch c_in into regs; latency hides under the K-loop
    float co_pre[4][4] = {};
    const int ch = tcol * 32 + wc * 16 + l16;        // mode-2 channel
    if (mode == 2 && c_in) {
#pragma unroll
        for (int m = 0; m < 4; ++m)
#pragma unroll
            for (int r = 0; r < 4; ++r)
                co_pre[m][r] = c_in[(size_t)(row0 + rloc + m * 16 + r) * HID + ch];
    }

    // 3 global_load_lds per wave per stage call (2x A-seg, 1x B-seg)
    auto stage = [&](int buf, int k0) {
        const short* Ak; const short* Bk; int kk, ld;
        if (k0 < K1) { Ak = A1; Bk = B1; kk = k0;      ld = K1; }
        else         { Ak = A2; Bk = B2; kk = k0 - K1; ld = K2; }
#pragma unroll
        for (int i = 0; i < 2; ++i) {
            int seg = w * 2 + i;                     // 16 A-segs of 16 rows
            int row = seg * 16 + rs;
            int c8  = cs ^ ((row + (row >> 2)) & 3);
            const short* ga = Ak + (size_t)(row0 + row) * ld + kk + c8 * 8;
            short* la = &sA[buf][seg * 512 + lane * 8];
            __builtin_amdgcn_global_load_lds((const __attribute__((address_space(1))) void*)ga,
                                             (__attribute__((address_space(3))) void*)la, 16, 0, 0);
        }
        {
            int row = w * 16 + rs;                   // 8 B-segs of 16 rows
            int c8  = cs ^ ((row + (row >> 2)) & 3);
            const short* gb = Bk + (size_t)(col0 + row) * ld + kk + c8 * 8;
            short* lb = &sB[buf][w * 512 + lane * 8];
            __builtin_amdgcn_global_load_lds((const __attribute__((address_space(1))) void*)gb,
                                             (__attribute__((address_space(3))) void*)lb, 16, 0, 0);
        }
    };

    stage(0, 0);
    stage(1, 32);                  // 6 loads in flight; KK >= 64 guaranteed
    int cur = 0;
    for (int t = 0; t < nsteps; ++t) {
        // wait for group t (oldest); keep the newer group in flight
        if (t + 1 < nsteps) asm volatile("s_waitcnt vmcnt(3)" ::: "memory");
        else                asm volatile("s_waitcnt vmcnt(0)" ::: "memory");
        __builtin_amdgcn_s_barrier();          // all waves: buf[cur] ready
        asm volatile("" ::: "memory");

        s16x8 af[4], bg[4];
        {
            const int rl = lane & 15;
            const int cw = lane >> 4;
#pragma unroll
            for (int m = 0; m < 4; ++m) {
                int r  = wr * 64 + m * 16 + rl;
                int sl = cw ^ ((r + (r >> 2)) & 3);
                af[m] = *(const s16x8*)(&sA[cur][r * 32 + sl * 8]);
                int c  = wc * 64 + m * 16 + rl;
                int sc = cw ^ ((c + (c >> 2)) & 3);
                bg[m] = *(const s16x8*)(&sB[cur][c * 32 + sc * 8]);
            }
        }
        // MFMAs consume all af/bg (compiler interleaves reads+MFMA with
        // fine-grained lgkmcnt); after them this wave's LDS reads are done.
#pragma unroll
        for (int m = 0; m < 4; ++m)
#pragma unroll
            for (int n = 0; n < 4; ++n)
                acc[m][n] = __builtin_amdgcn_mfma_f32_16x16x32_bf16(af[m], bg[n], acc[m][n], 0, 0, 0);

        __builtin_amdgcn_s_barrier();          // all waves done READING buf[cur]
        asm volatile("" ::: "memory");
        if (t + 2 < nsteps) stage(cur, (t + 2) * 32);   // re-stage 2 ahead
        cur ^= 1;
    }

    // C/D layout: col=lane&15, row=(lane>>4)*4+reg
    const int rbase = row0 + rloc;
    if (mode == 2) {
        float bi[4];
#pragma unroll
        for (int gg2 = 0; gg2 < 4; ++gg2) {
            float bb = bhh ? bhh[gg2 * 256 + ch] : 0.f;
            bi[gg2] = bih[gg2 * 256 + ch] + bb;
        }
#pragma unroll
        for (int m = 0; m < 4; ++m) {
#pragma unroll
            for (int r = 0; r < 4; ++r) {
                int row = rbase + m * 16 + r;
                float gi = acc[m][0][r] + bi[0];
                float gf = acc[m][1][r] + bi[1];
                float gg = acc[m][2][r] + bi[2];
                float go = acc[m][3][r] + bi[3];
                size_t idx = (size_t)row * HID + ch;
                float co = c_in ? co_pre[m][r] : 0.f;
                float c2 = fsigm(gf) * co + fsigm(gi) * ftanh(gg);
                float h2 = fsigm(go) * ftanh(c2);
                c_out[idx] = c2;
                h_out[idx] = f2b(h2);
            }
        }
    } else {
        const int cbase = col0 + wc * 64 + l16;
#pragma unroll
        for (int n = 0; n < 4; ++n) {
            int col = cbase + n * 16;
            float ba = bias ? bias[col] : 0.f;
#pragma unroll
            for (int m = 0; m < 4; ++m) {
#pragma unroll
                for (int r = 0; r < 4; ++r) {
                    int row = rbase + m * 16 + r;
                    float v = acc[m][n][r] + ba;
                    size_t idx = (size_t)row * N + col;
                    if (mode == 1) Cb[idx] = f2b(v);
                    else           Cf[idx] = v;
                }
            }
        }
    }
}

// ---------------- fused GATv2 (softmax + aggregate + bias + LN + ELU) -------
// quarter-wave per head (r21 structure, verified)
__global__ __launch_bounds__(256) void gat_fused(
    const short* __restrict__ xlr, const int* __restrict__ rowptr,
    const int* __restrict__ esrc, const float* __restrict__ att,
    const float* __restrict__ gb, const float* __restrict__ lg,
    const float* __restrict__ lb, short* __restrict__ outb)
{
    int i    = blockIdx.x * 4 + (threadIdx.x >> 6);
    int lane = threadIdx.x & 63;
    if (i >= NN) return;
    const int cb = (lane >> 4) * 64 + (lane & 15) * 4;   // channel base

    float xr4[4], at4[4];
    {
        s16x4 v = *(const s16x4*)(&xlr[(size_t)i * 512 + 256 + cb]);
#pragma unroll
        for (int j = 0; j < 4; ++j) { xr4[j] = b2f(v[j]); at4[j] = att[cb + j]; }
    }
    float mx = -INFINITY, sm = 0.f;
    float ac[4] = {0.f, 0.f, 0.f, 0.f};

    int lo = rowptr[i], hi = rowptr[i + 1];
    for (int e = lo; e < hi; ++e) {
        int s = esrc[e];
        s16x4 xv = *(const s16x4*)(&xlr[(size_t)s * 512 + cb]);
        float xs[4], pl = 0.f;
#pragma unroll
        for (int j = 0; j < 4; ++j) {
            xs[j] = b2f(xv[j]);
            float v = xs[j] + xr4[j];
            v = (v >= 0.f) ? v : 0.2f * v;
            pl += v * at4[j];
        }
#pragma unroll
        for (int o = 1; o < 16; o <<= 1) pl += __shfl_xor(pl, o);   // head logit
        float mn = fmaxf(mx, pl);
        float sc = fexp(mx - mn);            // first iter: exp(-inf)=0
        float a  = fexp(pl - mn);
        sm = sm * sc + a;
#pragma unroll
        for (int j = 0; j < 4; ++j) ac[j] = ac[j] * sc + a * xs[j];
        mx = mn;
    }
    // y = ac/sm (+ gat bias), then LayerNorm(256) + ELU, write bf16
    float val[4], s1 = 0.f, s2 = 0.f;
    float ism = frcp(sm);
#pragma unroll
    for (int j = 0; j < 4; ++j) {
        float v = ac[j] * ism + gb[cb + j];
        val[j] = v; s1 += v; s2 += v * v;
    }
    s1 = wsum64(s1); s2 = wsum64(s2);
    float mean = s1 * (1.f / 256.f);
    float var  = s2 * (1.f / 256.f) - mean * mean;
    float inv  = rsqrtf(var + 1e-5f);
    s16x4 ov;
#pragma unroll
    for (int j = 0; j < 4; ++j) {
        float v = (val[j] - mean) * inv * lg[cb + j] + lb[cb + j];
        v = (v > 0.f) ? v : (fexp(v) - 1.f);
        ov[j] = f2b(v);
    }
    *(s16x4*)(&outb[(size_t)i * HID + cb]) = ov;
}

// ---------------- LayerNorm (+act) for the MLP head -------------------------
__global__ __launch_bounds__(256) void ln_act_kernel(
    const float* __restrict__ in, const float* __restrict__ gamma,
    const float* __restrict__ beta, float* __restrict__ outf,
    short* __restrict__ outb, int width, int act)
{
    int row = blockIdx.x;
    const float* ip = in + (size_t)row * width;
    float vals[3];
    float s = 0.f, ss = 0.f;
    int nw = width >> 8;
    for (int i = 0; i < nw; ++i) {
        int c = threadIdx.x + (i << 8);
        float v = ip[c];
        vals[i] = v; s += v; ss += v * v;
    }
#pragma unroll
    for (int off = 32; off > 0; off >>= 1) {
        s  += __shfl_down(s, off);
        ss += __shfl_down(ss, off);
    }
    __shared__ float sh[8];
    int wv = threadIdx.x >> 6, lane = threadIdx.x & 63;
    if (lane == 0) { sh[wv] = s; sh[4 + wv] = ss; }
    __syncthreads();
    if (threadIdx.x == 0) {
        sh[0] = sh[0] + sh[1] + sh[2] + sh[3];
        sh[4] = sh[4] + sh[5] + sh[6] + sh[7];
    }
    __syncthreads();
    float mean = sh[0] / width;
    float var  = sh[4] / width - mean * mean;
    float inv  = rsqrtf(var + 1e-5f);
    for (int i = 0; i < nw; ++i) {
        int c = threadIdx.x + (i << 8);
        float v = (vals[i] - mean) * inv * gamma[c] + beta[c];
        if (act == 1) v = fmaxf(v, 0.f);
        if (outb) outb[(size_t)row * width + c] = f2b(v);
        else      outf[(size_t)row * width + c] = v;
    }
}

// ---------------- sorted-batch mean pool ------------------------------------
__global__ __launch_bounds__(256) void pool_mean(
    const short* __restrict__ h, const int* __restrict__ batch,
    short* __restrict__ poolb)
{
    int b    = blockIdx.x * 4 + (threadIdx.x >> 6);
    int lane = threadIdx.x & 63;
    if (b >= BG) return;
    auto lbound = [&](int key) {
        int lo = 0, hi = NN;
        while (lo < hi) { int mid = (lo + hi) >> 1; if (batch[mid] < key) lo = mid + 1; else hi = mid; }
        return lo;
    };
    int lo = lbound(b), hi = lbound(b + 1);
    float acc[HEADS] = {0.f, 0.f, 0.f, 0.f};
    for (int r = lo; r < hi; ++r)
#pragma unroll
        for (int hh = 0; hh < HEADS; ++hh)
            acc[hh] += b2f(h[(size_t)r * HID + hh * 64 + lane]);
    float inv = 1.f / fmaxf((float)(hi - lo), 1.f);
#pragma unroll
    for (int hh = 0; hh < HEADS; ++hh)
        poolb[(size_t)b * HID + hh * 64 + lane] = f2b(acc[hh] * inv);
}

// ---------------------------------------------------------------------------
extern "C" void kernel_launch(void* const* d_in, const int* in_sizes, int n_in,
                              void* d_out, int out_size, void* d_ws, size_t ws_size,
                              hipStream_t stream)
{
    (void)in_sizes; (void)n_in; (void)out_size; (void)ws_size;
    const float* x      = (const float*)d_in[0];
    const int*   ei     = (const int*)d_in[1];
    const int*   batch  = (const int*)d_in[2];
    const float* lin0_w = (const float*)d_in[4];
    const float* lin0_b = (const float*)d_in[5];
    const float* r0_wih = (const float*)d_in[6];
    const float* r0_bih = (const float*)d_in[8];
    const float* r0_bhh = (const float*)d_in[9];
    const float* mh1_w  = (const float*)d_in[46];
    const float* mh1_b  = (const float*)d_in[47];
    const float* ln1_g  = (const float*)d_in[48];
    const float* ln1_b  = (const float*)d_in[49];
    const float* mh2_w  = (const float*)d_in[50];
    const float* mh2_b  = (const float*)d_in[51];
    const float* ln2_g  = (const float*)d_in[52];
    const float* ln2_b  = (const float*)d_in[53];
    float* out = (float*)d_out;

    // ---- workspace bump allocation ----
    char* wsb = (char*)d_ws;
    auto alloc = [&](size_t bytes) -> void* {
        void* p = (void*)wsb;
        wsb += (bytes + 255) & ~(size_t)255;
        return p;
    };
    const size_t NH = (size_t)MP * HID;
    float* cb   = (float*)alloc(NH * 4);          // LSTM cell state f32
    short* hA   = (short*)alloc(NH * 2);          // h ping
    short* hB   = (short*)alloc(NH * 2);          // h pong
    short* ybb  = (short*)alloc(NH * 2);          // GAT-out / LSTM-input bf16
    short* xlr  = (short*)alloc((size_t)MP * 512 * 2);  // [xl|xr] bf16
    int*   deg    = (int*)alloc((size_t)NN * 4);
    int*   rowptr = (int*)alloc((size_t)(NN + 1) * 4);
    int*   cursor = (int*)alloc((size_t)NN * 4);
    int*   esrc   = (int*)alloc((size_t)EP * 4);
    int*   bsum   = (int*)alloc((size_t)SCB * 4);
    int*   bpre   = (int*)alloc((size_t)SCB * 4);
    // weights bf16
    short* w_r0f  = (short*)alloc((size_t)G4H * KP0 * 2);  // folded lin0+rnn0
    float* b_r0   = (float*)alloc((size_t)G4H * 4);        // folded bias
    short* w_lr[3]; short* w_ih[3]; short* w_hh[3]; float* blr[3];
    for (int l = 0; l < 3; ++l) {
        int Kp = (l == 0) ? KP0 : 256;
        w_lr[l] = (short*)alloc((size_t)512 * Kp * 2);
        w_ih[l] = (short*)alloc((size_t)G4H * 256 * 2);
        w_hh[l] = (short*)alloc((size_t)G4H * 256 * 2);
        blr[l]  = (float*)alloc(512 * 4);
    }
    short* w_m1 = (short*)alloc((size_t)NH1 * 256 * 2);
    short* w_m2 = (short*)alloc((size_t)NH2 * NH1 * 2);
    // xb (layer-0 padded input) with head temps aliased over it (head runs
    // only after xb is dead)
    short* xb = (short*)alloc((size_t)MP * KP0 * 2);   // 64 MB
    float* z1    = (float*)xb;                          // BG*NH1 f32 (8.4MB)
    short* z1b   = (short*)(z1 + (size_t)BG * NH1);     // BG*NH1 bf16
    short* poolb = z1b + (size_t)BG * NH1;              // BG*HID bf16

    // mode 0/1 GEMM; 1-D grid with XCD swizzle (requires (M/256)%8==0)
    auto G = [&](const short* A, const short* B, int K, const float* bias,
                 float* Cf, short* Cbb, int M, int N, int mode) {
        int nrp = M / 256, nct = N / 128;
        mfma_gemm<<<dim3(nrp * nct), dim3(512), 0, stream>>>(
            A, B, K, nullptr, nullptr, 0, bias,
            nullptr, nullptr, nullptr, nullptr, nullptr, Cf, Cbb, N, mode, nct);
    };
    // mode 2 LSTM GEMM (dual-source)
    auto GL = [&](const short* A1, const short* B1, int K1,
                  const short* A2, const short* B2, int K2,
                  const float* bih, const float* bhh,
                  const float* ci, float* co, short* ho) {
        mfma_gemm<<<dim3((MP / 256) * 8), dim3(512), 0, stream>>>(
            A1, B1, K1, A2, B2, K2, nullptr,
            bih, bhh, ci, co, ho, nullptr, nullptr, G4H, 2, 8);
    };

    // ---- conversions: x pad-convert, batched weights, folds, concat ----
    conv_bf16<<<dim3(512), dim3(256), 0, stream>>>(x, xb, NN, MP, FIN, KP0);

    CPack cp; int nd = 0;
    auto addc = [&](const float* s, short* d, int rsrc, int rdst, int Ks, int Kd) {
        cp.d[nd++] = CDesc{ s, d, rdst * Kd, Ks, Kd, rsrc, 0 };
    };
    auto addg = [&](const float* s, short* d) {
        cp.d[nd++] = CDesc{ s, d, G4H * 256, 256, 256, G4H, 1 };
    };
    for (int l = 0; l < 3; ++l) {
        int base = 10 + 12 * l;
        int K  = (l == 0) ? FIN : 256;
        int Kp = (l == 0) ? KP0 : 256;
        addc((const float*)d_in[base + 0], w_lr[l], 256, 256, K, Kp);
        addc((const float*)d_in[base + 2], w_lr[l] + (size_t)256 * Kp, 256, 256, K, Kp);
        addg((const float*)d_in[base + 8], w_ih[l]);
        addg((const float*)d_in[base + 9], w_hh[l]);
    }
    addc(mh1_w, w_m1, NH1, NH1, 256, 256);
    addc(mh2_w, w_m2, NH2, NH2, NH1, NH1);
    conv_pack<<<dim3(32, nd), dim3(256), 0, stream>>>(cp, nd);

    fold_w<<<dim3(G4H), dim3(320), 0, stream>>>(r0_wih, lin0_w, w_r0f);
    fold_b<<<dim3(4), dim3(256), 0, stream>>>(r0_wih, lin0_b, r0_bih, r0_bhh, b_r0);

    BPack bp;
    for (int l = 0; l < 3; ++l) {
        int base = 10 + 12 * l;
        bp.a[l] = (const float*)d_in[base + 1];
        bp.b[l] = (const float*)d_in[base + 3];
        bp.dst[l] = blr[l];
    }
    concat_pack<<<dim3(6), dim3(256), 0, stream>>>(bp);

    // ---- CSR build ----
    zero_f32<<<dim3(256), dim3(256), 0, stream>>>((float*)deg, NN);
    edge_hist<<<dim3((EP + 255) / 256), dim3(256), 0, stream>>>(ei, deg);
    scan_part<<<dim3(SCB), dim3(256), 0, stream>>>(deg, bsum);
    scan_tops<<<dim3(1), dim3(512), 0, stream>>>(bsum, bpre, rowptr);
    scan_fill<<<dim3(SCB), dim3(256), 0, stream>>>(deg, bpre, rowptr, cursor);
    edge_fill<<<dim3((EP + 255) / 256), dim3(256), 0, stream>>>(ei, rowptr, cursor, esrc);

    // ---- rnn0 LSTM directly from xb (folded weights; h=c=0 start) ----
    GL(xb, w_r0f, KP0, nullptr, nullptr, 0, b_r0, nullptr, nullptr, cb, hA);

    // ---- 3x (GATv2 -> LN+ELU -> LSTM) ----
    short* hprev = hA;
    short* hnext = hB;
    for (int l = 0; l < 3; ++l) {
        int base = 10 + 12 * l;
        const float* att = (const float*)d_in[base + 4];
        const float* gb  = (const float*)d_in[base + 5];
        const float* lg  = (const float*)d_in[base + 6];
        const float* lb  = (const float*)d_in[base + 7];
        const float* bih = (const float*)d_in[base + 10];
        const float* bhh = (const float*)d_in[base + 11];
        const short* Ain = (l == 0) ? xb : hprev;
        int K = (l == 0) ? KP0 : 256;

        G(Ain, w_lr[l], K, blr[l], nullptr, xlr, MP, 512, 1);
        gat_fused<<<dim3((NN + 3) / 4), dim3(256), 0, stream>>>(
            xlr, rowptr, esrc, att, gb, lg, lb, ybb);
        GL(ybb, w_ih[l], 256, hprev, w_hh[l], 256, bih, bhh, cb, cb, hnext);
        short* t = hprev; hprev = hnext; hnext = t;
    }

    // ---- mean pool (sorted batch) + MLP head ----
    pool_mean<<<dim3((BG + 3) / 4), dim3(256), 0, stream>>>(hprev, batch, poolb);
    G(poolb, w_m1, 256, mh1_b, z1, nullptr, BG, NH1, 0);
    ln_act_kernel<<<dim3(BG), dim3(256), 0, stream>>>(z1, ln1_g, ln1_b, nullptr, z1b, NH1, 1);
    G(z1b, w_m2, NH1, mh2_b, out, nullptr, BG, NH2, 0);
    ln_act_kernel<<<dim3(BG), dim3(256), 0, stream>>>(out, ln2_g, ln2_b, out, nullptr, NH2, 0);
}

// Round 23
// 1329.545 us; speedup vs baseline: 1.3651x; 1.0673x over previous
//
#include <hip/hip_runtime.h>
#include <hip/hip_bf16.h>
#include <math.h>

// ---------------------------------------------------------------------------
// GraphEncoder round 23: r22 (best: 1419us) + conv_x polish.
// conv_bf16 for the 32.1M-element x pad-convert did a 64-bit int division
// per element (~50-instr sequence); conv_x uses 8-rows-per-block layout
// with zero divisions. Same f2b math, bit-identical xb.
// Everything else identical to r22: BM=256 depth-2 counted-vmcnt MFMA GEMM
// (plateau ~185us/dispatch, quintuple-verified), quarter-wave gat_fused,
// lin0->rnn0 fold, hierarchical scan, batched conversions.
// Session: 14009us (r3 baseline) -> ~1420us (9.9x).
// ---------------------------------------------------------------------------

constexpr int NN    = 100000;
constexpr int EE    = 400000;
constexpr int EP    = EE + NN;      // 500000 (incl self loops)
constexpr int BG    = 4096;
constexpr int FIN   = 300;
constexpr int HEADS = 4;
constexpr int HID   = 256;
constexpr int G4H   = 1024;
constexpr int NH1   = 512;
constexpr int NH2   = 768;
constexpr int MP    = 100352;       // 392*256, 392 % 8 == 0
constexpr int KP0   = 320;          // FIN padded to mult of 32
constexpr int SCB   = 392;          // scan blocks (392*256 = 100352 >= NN)

typedef __attribute__((ext_vector_type(4))) float f32x4;
typedef __attribute__((ext_vector_type(8))) short s16x8;
typedef __attribute__((ext_vector_type(4))) short s16x4;

#define LOG2E 1.4426950408889634f

// fast HW transcendentals (v_exp_f32 = 2^x, v_rcp_f32)
__device__ inline float fexp(float x)  { return __builtin_amdgcn_exp2f(x * LOG2E); }
__device__ inline float frcp(float x)  { return __builtin_amdgcn_rcpf(x); }
__device__ inline float fsigm(float x) { return frcp(1.f + __builtin_amdgcn_exp2f(-LOG2E * x)); }
__device__ inline float ftanh(float x) { return 1.f - 2.f * frcp(1.f + __builtin_amdgcn_exp2f(2.f * LOG2E * x)); }

__device__ inline float b2f(short s) { return __uint_as_float(((unsigned)(unsigned short)s) << 16); }
__device__ inline short f2b(float f) {
    unsigned u = __float_as_uint(f);
    u += 0x7fff + ((u >> 16) & 1);          // round-to-nearest-even
    return (short)(u >> 16);
}
__device__ inline float wsum64(float v) {
#pragma unroll
    for (int o = 32; o > 0; o >>= 1) v += __shfl_xor(v, o);
    return v;
}

// ---------------- utility kernels -------------------------------------------
__global__ __launch_bounds__(256) void zero_f32(float* __restrict__ p, long long n)
{
    long long i = (long long)blockIdx.x * 256 + threadIdx.x;
    long long stride = (long long)gridDim.x * 256;
    for (; i < n; i += stride) p[i] = 0.f;
}

// x pad-convert without divisions: 8 rows/block, threads stride the 320 cols
__global__ __launch_bounds__(256) void conv_x(
    const float* __restrict__ src, short* __restrict__ dst)
{
    int r0 = blockIdx.x * 8;
#pragma unroll
    for (int rr = 0; rr < 8; ++rr) {
        int r = r0 + rr;
        const float* s = src + (size_t)r * FIN;
        short* d = dst + (size_t)r * KP0;
        bool valid = (r < NN);
        for (int c = threadIdx.x; c < KP0; c += 256) {
            float v = (valid && c < FIN) ? s[c] : 0.f;
            d[c] = f2b(v);
        }
    }
}

// ---- batched weight conversions: one dispatch for all small tensors --------
// gate==0: pad-convert [rsrc x Ks] -> [n/Kd x Kd] bf16
// gate==1: gate-interleaved LSTM pack (Ks = K), n = 1024*K
struct CDesc { const float* src; short* dst; int n, Ks, Kd, rsrc, gate; };
struct CPack { CDesc d[16]; };

__global__ __launch_bounds__(256) void conv_pack(CPack p, int nd)
{
    int di = blockIdx.y;
    if (di >= nd) return;
    CDesc c = p.d[di];
    int stride = gridDim.x * 256;
    for (int i = blockIdx.x * 256 + threadIdx.x; i < c.n; i += stride) {
        float v;
        if (c.gate) {
            int K  = c.Ks;
            int pp = i / K, k = i - pp * K;
            int gate = (pp >> 4) & 3;
            int ch   = (pp >> 7) * 32 + ((pp >> 6) & 1) * 16 + (pp & 15);
            v = c.src[(size_t)(gate * 256 + ch) * K + k];
        } else {
            int r = i / c.Kd, k = i - r * c.Kd;
            v = (r < c.rsrc && k < c.Ks) ? c.src[(size_t)r * c.Ks + k] : 0.f;
        }
        c.dst[i] = f2b(v);
    }
}

// ---- lin0->rnn0 fold: W'[packed p][k] = sum_h r0_wih[orig][h]*lin0_w[h][k] --
// one block per packed row p (gate-interleaved dest); 320 threads = cols.
__global__ __launch_bounds__(320) void fold_w(
    const float* __restrict__ wih, const float* __restrict__ lw,
    short* __restrict__ dst)
{
    __shared__ float row[256];
    int p = blockIdx.x;
    int gate = (p >> 4) & 3;
    int ch   = (p >> 7) * 32 + ((p >> 6) & 1) * 16 + (p & 15);
    int orig = gate * 256 + ch;
    for (int h = threadIdx.x; h < 256; h += 320)
        row[h] = wih[(size_t)orig * 256 + h];
    __syncthreads();
    int j = threadIdx.x;                 // 0..319
    float s = 0.f;
    if (j < FIN) {
        for (int h = 0; h < 256; ++h) s += row[h] * lw[(size_t)h * FIN + j];
    }
    dst[(size_t)p * KP0 + j] = f2b(s);
}

// b'[orig t] = r0_bih[t] + r0_bhh[t] + sum_h r0_wih[t][h]*lin0_b[h]
__global__ __launch_bounds__(256) void fold_b(
    const float* __restrict__ wih, const float* __restrict__ lb,
    const float* __restrict__ bih, const float* __restrict__ bhh,
    float* __restrict__ dst)
{
    int t = blockIdx.x * 256 + threadIdx.x;
    if (t >= G4H) return;
    float s = bih[t] + bhh[t];
    for (int h = 0; h < 256; ++h) s += wih[(size_t)t * 256 + h] * lb[h];
    dst[t] = s;
}

// ---- batched bias concat (3 layers x [bl|br] -> blr f32[512]) --------------
struct BPack { const float* a[3]; const float* b[3]; float* dst[3]; };
__global__ __launch_bounds__(256) void concat_pack(BPack p)
{
    int l = blockIdx.x >> 1;
    int half = blockIdx.x & 1;
    const float* s = half ? p.b[l] : p.a[l];
    p.dst[l][half * 256 + threadIdx.x] = s[threadIdx.x];
}

// ---------------- CSR build -------------------------------------------------
__global__ __launch_bounds__(256) void edge_hist(const int* __restrict__ ei,
                                                 int* __restrict__ deg)
{
    int e = blockIdx.x * 256 + threadIdx.x;
    if (e >= EP) return;
    int d = (e < EE) ? ei[EE + e] : e - EE;
    atomicAdd(&deg[d], 1);
}

// pass 1: per-block chunk sums (coalesced)
__global__ __launch_bounds__(256) void scan_part(const int* __restrict__ deg,
                                                 int* __restrict__ bsum)
{
    int b = blockIdx.x, t = threadIdx.x;
    int i = b * 256 + t;
    int v = (i < NN) ? deg[i] : 0;
#pragma unroll
    for (int o = 32; o > 0; o >>= 1) v += __shfl_down(v, o);
    __shared__ int sh[4];
    if ((t & 63) == 0) sh[t >> 6] = v;
    __syncthreads();
    if (t == 0) bsum[b] = sh[0] + sh[1] + sh[2] + sh[3];
}

// pass 2: scan the 392 block sums (single small block)
__global__ __launch_bounds__(512) void scan_tops(const int* __restrict__ bsum,
                                                 int* __restrict__ bpre,
                                                 int* __restrict__ rowptr)
{
    __shared__ int sh[512];
    int t = threadIdx.x;
    int v = (t < SCB) ? bsum[t] : 0;
    sh[t] = v;
    __syncthreads();
    for (int off = 1; off < 512; off <<= 1) {
        int u = (t >= off) ? sh[t - off] : 0;
        __syncthreads();
        sh[t] += u;
        __syncthreads();
    }
    if (t < SCB) bpre[t] = sh[t] - v;          // exclusive prefix
    if (t == SCB - 1) rowptr[NN] = sh[t];      // total == EP
}

// pass 3: intra-block exclusive scan + write rowptr/cursor (coalesced)
__global__ __launch_bounds__(256) void scan_fill(const int* __restrict__ deg,
                                                 const int* __restrict__ bpre,
                                                 int* __restrict__ rowptr,
                                                 int* __restrict__ cursor)
{
    __shared__ int sh[256];
    int b = blockIdx.x, t = threadIdx.x;
    int i = b * 256 + t;
    int v = (i < NN) ? deg[i] : 0;
    sh[t] = v;
    __syncthreads();
    for (int off = 1; off < 256; off <<= 1) {
        int u = (t >= off) ? sh[t - off] : 0;
        __syncthreads();
        sh[t] += u;
        __syncthreads();
    }
    if (i < NN) {
        rowptr[i] = bpre[b] + sh[t] - v;       // exclusive
        cursor[i] = 0;
    }
}

__global__ __launch_bounds__(256) void edge_fill(const int* __restrict__ ei,
                                                 const int* __restrict__ rowptr,
                                                 int* __restrict__ cursor,
                                                 int* __restrict__ esrc)
{
    int e = blockIdx.x * 256 + threadIdx.x;
    if (e >= EP) return;
    int s, d;
    if (e < EE) { s = ei[e]; d = ei[EE + e]; }
    else        { s = d = e - EE; }
    int slot = rowptr[d] + atomicAdd(&cursor[d], 1);
    esrc[slot] = s;
}

// ---------------- MFMA GEMM with fused epilogues ----------------------------
// (identical schedule to r17/r19/r20/r21/r22)
__global__ __launch_bounds__(512) void mfma_gemm(
    const short* __restrict__ A1, const short* __restrict__ B1, int K1,
    const short* __restrict__ A2, const short* __restrict__ B2, int K2,
    const float* __restrict__ bias,
    const float* __restrict__ bih, const float* __restrict__ bhh,
    const float* __restrict__ c_in, float* __restrict__ c_out,
    short* __restrict__ h_out,
    float* __restrict__ Cf, short* __restrict__ Cb, int N, int mode, int nct)
{
    __shared__ __align__(16) short sA[2][256 * 32];   // 16KB each
    __shared__ __align__(16) short sB[2][128 * 32];   // 8KB each
    const int tid  = threadIdx.x;
    const int w    = tid >> 6, lane = tid & 63;
    const int wr   = w >> 1,  wc   = w & 1;      // 4x2 waves of 64x64
    // XCD-aware decode (consecutive bids round-robin across 8 XCDs)
    const int bid  = blockIdx.x;
    const int xcd  = bid & 7;
    const int slot = bid >> 3;
    const int g    = slot / nct;
    const int tcol = slot - g * nct;
    const int row0 = (g * 8 + xcd) * 256;
    const int col0 = tcol * 128;

    f32x4 acc[4][4];
#pragma unroll
    for (int m = 0; m < 4; ++m)
#pragma unroll
        for (int n = 0; n < 4; ++n) acc[m][n] = (f32x4){0.f, 0.f, 0.f, 0.f};

    const int rs = lane >> 2;
    const int cs = lane & 3;
    const int KK = K1 + K2;
    const int nsteps = KK >> 5;
    const int l16 = lane & 15;
    const int rloc = wr * 64 + ((lane >> 4) << 2);   // block-local base row

    // mode-2: prefetch c_in into regs; latency hides under the K-loop
    float co_pre[4][4] = {};
    const int ch = tcol * 32 + wc * 16 + l16;        // mode-2 channel
    if (mode == 2 && c_in) {
#pragma unroll
        for (int m = 0; m < 4; ++m)
#pragma unroll
            for (int r = 0; r < 4; ++r)
                co_pre[m][r] = c_in[(size_t)(row0 + rloc + m * 16 + r) * HID + ch];
    }

    // 3 global_load_lds per wave per stage call (2x A-seg, 1x B-seg)
    auto stage = [&](int buf, int k0) {
        const short* Ak; const short* Bk; int kk, ld;
        if (k0 < K1) { Ak = A1; Bk = B1; kk = k0;      ld = K1; }
        else         { Ak = A2; Bk = B2; kk = k0 - K1; ld = K2; }
#pragma unroll
        for (int i = 0; i < 2; ++i) {
            int seg = w * 2 + i;                     // 16 A-segs of 16 rows
            int row = seg * 16 + rs;
            int c8  = cs ^ ((row + (row >> 2)) & 3);
            const short* ga = Ak + (size_t)(row0 + row) * ld + kk + c8 * 8;
            short* la = &sA[buf][seg * 512 + lane * 8];
            __builtin_amdgcn_global_load_lds((const __attribute__((address_space(1))) void*)ga,
                                             (__attribute__((address_space(3))) void*)la, 16, 0, 0);
        }
        {
            int row = w * 16 + rs;                   // 8 B-segs of 16 rows
            int c8  = cs ^ ((row + (row >> 2)) & 3);
            const short* gb = Bk + (size_t)(col0 + row) * ld + kk + c8 * 8;
            short* lb = &sB[buf][w * 512 + lane * 8];
            __builtin_amdgcn_global_load_lds((const __attribute__((address_space(1))) void*)gb,
                                             (__attribute__((address_space(3))) void*)lb, 16, 0, 0);
        }
    };

    stage(0, 0);
    stage(1, 32);                  // 6 loads in flight; KK >= 64 guaranteed
    int cur = 0;
    for (int t = 0; t < nsteps; ++t) {
        // wait for group t (oldest); keep the newer group in flight
        if (t + 1 < nsteps) asm volatile("s_waitcnt vmcnt(3)" ::: "memory");
        else                asm volatile("s_waitcnt vmcnt(0)" ::: "memory");
        __builtin_amdgcn_s_barrier();          // all waves: buf[cur] ready
        asm volatile("" ::: "memory");

        s16x8 af[4], bg[4];
        {
            const int rl = lane & 15;
            const int cw = lane >> 4;
#pragma unroll
            for (int m = 0; m < 4; ++m) {
                int r  = wr * 64 + m * 16 + rl;
                int sl = cw ^ ((r + (r >> 2)) & 3);
                af[m] = *(const s16x8*)(&sA[cur][r * 32 + sl * 8]);
                int c  = wc * 64 + m * 16 + rl;
                int sc = cw ^ ((c + (c >> 2)) & 3);
                bg[m] = *(const s16x8*)(&sB[cur][c * 32 + sc * 8]);
            }
        }
        // MFMAs consume all af/bg (compiler interleaves reads+MFMA with
        // fine-grained lgkmcnt); after them this wave's LDS reads are done.
#pragma unroll
        for (int m = 0; m < 4; ++m)
#pragma unroll
            for (int n = 0; n < 4; ++n)
                acc[m][n] = __builtin_amdgcn_mfma_f32_16x16x32_bf16(af[m], bg[n], acc[m][n], 0, 0, 0);

        __builtin_amdgcn_s_barrier();          // all waves done READING buf[cur]
        asm volatile("" ::: "memory");
        if (t + 2 < nsteps) stage(cur, (t + 2) * 32);   // re-stage 2 ahead
        cur ^= 1;
    }

    // C/D layout: col=lane&15, row=(lane>>4)*4+reg
    const int rbase = row0 + rloc;
    if (mode == 2) {
        float bi[4];
#pragma unroll
        for (int gg2 = 0; gg2 < 4; ++gg2) {
            float bb = bhh ? bhh[gg2 * 256 + ch] : 0.f;
            bi[gg2] = bih[gg2 * 256 + ch] + bb;
        }
#pragma unroll
        for (int m = 0; m < 4; ++m) {
#pragma unroll
            for (int r = 0; r < 4; ++r) {
                int row = rbase + m * 16 + r;
                float gi = acc[m][0][r] + bi[0];
                float gf = acc[m][1][r] + bi[1];
                float gg = acc[m][2][r] + bi[2];
                float go = acc[m][3][r] + bi[3];
                size_t idx = (size_t)row * HID + ch;
                float co = c_in ? co_pre[m][r] : 0.f;
                float c2 = fsigm(gf) * co + fsigm(gi) * ftanh(gg);
                float h2 = fsigm(go) * ftanh(c2);
                c_out[idx] = c2;
                h_out[idx] = f2b(h2);
            }
        }
    } else {
        const int cbase = col0 + wc * 64 + l16;
#pragma unroll
        for (int n = 0; n < 4; ++n) {
            int col = cbase + n * 16;
            float ba = bias ? bias[col] : 0.f;
#pragma unroll
            for (int m = 0; m < 4; ++m) {
#pragma unroll
                for (int r = 0; r < 4; ++r) {
                    int row = rbase + m * 16 + r;
                    float v = acc[m][n][r] + ba;
                    size_t idx = (size_t)row * N + col;
                    if (mode == 1) Cb[idx] = f2b(v);
                    else           Cf[idx] = v;
                }
            }
        }
    }
}

// ---------------- fused GATv2 (softmax + aggregate + bias + LN + ELU) -------
// quarter-wave per head (r21 structure, verified)
__global__ __launch_bounds__(256) void gat_fused(
    const short* __restrict__ xlr, const int* __restrict__ rowptr,
    const int* __restrict__ esrc, const float* __restrict__ att,
    const float* __restrict__ gb, const float* __restrict__ lg,
    const float* __restrict__ lb, short* __restrict__ outb)
{
    int i    = blockIdx.x * 4 + (threadIdx.x >> 6);
    int lane = threadIdx.x & 63;
    if (i >= NN) return;
    const int cb = (lane >> 4) * 64 + (lane & 15) * 4;   // channel base

    float xr4[4], at4[4];
    {
        s16x4 v = *(const s16x4*)(&xlr[(size_t)i * 512 + 256 + cb]);
#pragma unroll
        for (int j = 0; j < 4; ++j) { xr4[j] = b2f(v[j]); at4[j] = att[cb + j]; }
    }
    float mx = -INFINITY, sm = 0.f;
    float ac[4] = {0.f, 0.f, 0.f, 0.f};

    int lo = rowptr[i], hi = rowptr[i + 1];
    for (int e = lo; e < hi; ++e) {
        int s = esrc[e];
        s16x4 xv = *(const s16x4*)(&xlr[(size_t)s * 512 + cb]);
        float xs[4], pl = 0.f;
#pragma unroll
        for (int j = 0; j < 4; ++j) {
            xs[j] = b2f(xv[j]);
            float v = xs[j] + xr4[j];
            v = (v >= 0.f) ? v : 0.2f * v;
            pl += v * at4[j];
        }
#pragma unroll
        for (int o = 1; o < 16; o <<= 1) pl += __shfl_xor(pl, o);   // head logit
        float mn = fmaxf(mx, pl);
        float sc = fexp(mx - mn);            // first iter: exp(-inf)=0
        float a  = fexp(pl - mn);
        sm = sm * sc + a;
#pragma unroll
        for (int j = 0; j < 4; ++j) ac[j] = ac[j] * sc + a * xs[j];
        mx = mn;
    }
    // y = ac/sm (+ gat bias), then LayerNorm(256) + ELU, write bf16
    float val[4], s1 = 0.f, s2 = 0.f;
    float ism = frcp(sm);
#pragma unroll
    for (int j = 0; j < 4; ++j) {
        float v = ac[j] * ism + gb[cb + j];
        val[j] = v; s1 += v; s2 += v * v;
    }
    s1 = wsum64(s1); s2 = wsum64(s2);
    float mean = s1 * (1.f / 256.f);
    float var  = s2 * (1.f / 256.f) - mean * mean;
    float inv  = rsqrtf(var + 1e-5f);
    s16x4 ov;
#pragma unroll
    for (int j = 0; j < 4; ++j) {
        float v = (val[j] - mean) * inv * lg[cb + j] + lb[cb + j];
        v = (v > 0.f) ? v : (fexp(v) - 1.f);
        ov[j] = f2b(v);
    }
    *(s16x4*)(&outb[(size_t)i * HID + cb]) = ov;
}

// ---------------- LayerNorm (+act) for the MLP head -------------------------
__global__ __launch_bounds__(256) void ln_act_kernel(
    const float* __restrict__ in, const float* __restrict__ gamma,
    const float* __restrict__ beta, float* __restrict__ outf,
    short* __restrict__ outb, int width, int act)
{
    int row = blockIdx.x;
    const float* ip = in + (size_t)row * width;
    float vals[3];
    float s = 0.f, ss = 0.f;
    int nw = width >> 8;
    for (int i = 0; i < nw; ++i) {
        int c = threadIdx.x + (i << 8);
        float v = ip[c];
        vals[i] = v; s += v; ss += v * v;
    }
#pragma unroll
    for (int off = 32; off > 0; off >>= 1) {
        s  += __shfl_down(s, off);
        ss += __shfl_down(ss, off);
    }
    __shared__ float sh[8];
    int wv = threadIdx.x >> 6, lane = threadIdx.x & 63;
    if (lane == 0) { sh[wv] = s; sh[4 + wv] = ss; }
    __syncthreads();
    if (threadIdx.x == 0) {
        sh[0] = sh[0] + sh[1] + sh[2] + sh[3];
        sh[4] = sh[4] + sh[5] + sh[6] + sh[7];
    }
    __syncthreads();
    float mean = sh[0] / width;
    float var  = sh[4] / width - mean * mean;
    float inv  = rsqrtf(var + 1e-5f);
    for (int i = 0; i < nw; ++i) {
        int c = threadIdx.x + (i << 8);
        float v = (vals[i] - mean) * inv * gamma[c] + beta[c];
        if (act == 1) v = fmaxf(v, 0.f);
        if (outb) outb[(size_t)row * width + c] = f2b(v);
        else      outf[(size_t)row * width + c] = v;
    }
}

// ---------------- sorted-batch mean pool ------------------------------------
__global__ __launch_bounds__(256) void pool_mean(
    const short* __restrict__ h, const int* __restrict__ batch,
    short* __restrict__ poolb)
{
    int b    = blockIdx.x * 4 + (threadIdx.x >> 6);
    int lane = threadIdx.x & 63;
    if (b >= BG) return;
    auto lbound = [&](int key) {
        int lo = 0, hi = NN;
        while (lo < hi) { int mid = (lo + hi) >> 1; if (batch[mid] < key) lo = mid + 1; else hi = mid; }
        return lo;
    };
    int lo = lbound(b), hi = lbound(b + 1);
    float acc[HEADS] = {0.f, 0.f, 0.f, 0.f};
    for (int r = lo; r < hi; ++r)
#pragma unroll
        for (int hh = 0; hh < HEADS; ++hh)
            acc[hh] += b2f(h[(size_t)r * HID + hh * 64 + lane]);
    float inv = 1.f / fmaxf((float)(hi - lo), 1.f);
#pragma unroll
    for (int hh = 0; hh < HEADS; ++hh)
        poolb[(size_t)b * HID + hh * 64 + lane] = f2b(acc[hh] * inv);
}

// ---------------------------------------------------------------------------
extern "C" void kernel_launch(void* const* d_in, const int* in_sizes, int n_in,
                              void* d_out, int out_size, void* d_ws, size_t ws_size,
                              hipStream_t stream)
{
    (void)in_sizes; (void)n_in; (void)out_size; (void)ws_size;
    const float* x      = (const float*)d_in[0];
    const int*   ei     = (const int*)d_in[1];
    const int*   batch  = (const int*)d_in[2];
    const float* lin0_w = (const float*)d_in[4];
    const float* lin0_b = (const float*)d_in[5];
    const float* r0_wih = (const float*)d_in[6];
    const float* r0_bih = (const float*)d_in[8];
    const float* r0_bhh = (const float*)d_in[9];
    const float* mh1_w  = (const float*)d_in[46];
    const float* mh1_b  = (const float*)d_in[47];
    const float* ln1_g  = (const float*)d_in[48];
    const float* ln1_b  = (const float*)d_in[49];
    const float* mh2_w  = (const float*)d_in[50];
    const float* mh2_b  = (const float*)d_in[51];
    const float* ln2_g  = (const float*)d_in[52];
    const float* ln2_b  = (const float*)d_in[53];
    float* out = (float*)d_out;

    // ---- workspace bump allocation ----
    char* wsb = (char*)d_ws;
    auto alloc = [&](size_t bytes) -> void* {
        void* p = (void*)wsb;
        wsb += (bytes + 255) & ~(size_t)255;
        return p;
    };
    const size_t NH = (size_t)MP * HID;
    float* cb   = (float*)alloc(NH * 4);          // LSTM cell state f32
    short* hA   = (short*)alloc(NH * 2);          // h ping
    short* hB   = (short*)alloc(NH * 2);          // h pong
    short* ybb  = (short*)alloc(NH * 2);          // GAT-out / LSTM-input bf16
    short* xlr  = (short*)alloc((size_t)MP * 512 * 2);  // [xl|xr] bf16
    int*   deg    = (int*)alloc((size_t)NN * 4);
    int*   rowptr = (int*)alloc((size_t)(NN + 1) * 4);
    int*   cursor = (int*)alloc((size_t)NN * 4);
    int*   esrc   = (int*)alloc((size_t)EP * 4);
    int*   bsum   = (int*)alloc((size_t)SCB * 4);
    int*   bpre   = (int*)alloc((size_t)SCB * 4);
    // weights bf16
    short* w_r0f  = (short*)alloc((size_t)G4H * KP0 * 2);  // folded lin0+rnn0
    float* b_r0   = (float*)alloc((size_t)G4H * 4);        // folded bias
    short* w_lr[3]; short* w_ih[3]; short* w_hh[3]; float* blr[3];
    for (int l = 0; l < 3; ++l) {
        int Kp = (l == 0) ? KP0 : 256;
        w_lr[l] = (short*)alloc((size_t)512 * Kp * 2);
        w_ih[l] = (short*)alloc((size_t)G4H * 256 * 2);
        w_hh[l] = (short*)alloc((size_t)G4H * 256 * 2);
        blr[l]  = (float*)alloc(512 * 4);
    }
    short* w_m1 = (short*)alloc((size_t)NH1 * 256 * 2);
    short* w_m2 = (short*)alloc((size_t)NH2 * NH1 * 2);
    // xb (layer-0 padded input) with head temps aliased over it (head runs
    // only after xb is dead)
    short* xb = (short*)alloc((size_t)MP * KP0 * 2);   // 64 MB
    float* z1    = (float*)xb;                          // BG*NH1 f32 (8.4MB)
    short* z1b   = (short*)(z1 + (size_t)BG * NH1);     // BG*NH1 bf16
    short* poolb = z1b + (size_t)BG * NH1;              // BG*HID bf16

    // mode 0/1 GEMM; 1-D grid with XCD swizzle (requires (M/256)%8==0)
    auto G = [&](const short* A, const short* B, int K, const float* bias,
                 float* Cf, short* Cbb, int M, int N, int mode) {
        int nrp = M / 256, nct = N / 128;
        mfma_gemm<<<dim3(nrp * nct), dim3(512), 0, stream>>>(
            A, B, K, nullptr, nullptr, 0, bias,
            nullptr, nullptr, nullptr, nullptr, nullptr, Cf, Cbb, N, mode, nct);
    };
    // mode 2 LSTM GEMM (dual-source)
    auto GL = [&](const short* A1, const short* B1, int K1,
                  const short* A2, const short* B2, int K2,
                  const float* bih, const float* bhh,
                  const float* ci, float* co, short* ho) {
        mfma_gemm<<<dim3((MP / 256) * 8), dim3(512), 0, stream>>>(
            A1, B1, K1, A2, B2, K2, nullptr,
            bih, bhh, ci, co, ho, nullptr, nullptr, G4H, 2, 8);
    };

    // ---- conversions: x pad-convert (div-free), batched weights, folds ----
    conv_x<<<dim3(MP / 8), dim3(256), 0, stream>>>(x, xb);

    CPack cp; int nd = 0;
    auto addc = [&](const float* s, short* d, int rsrc, int rdst, int Ks, int Kd) {
        cp.d[nd++] = CDesc{ s, d, rdst * Kd, Ks, Kd, rsrc, 0 };
    };
    auto addg = [&](const float* s, short* d) {
        cp.d[nd++] = CDesc{ s, d, G4H * 256, 256, 256, G4H, 1 };
    };
    for (int l = 0; l < 3; ++l) {
        int base = 10 + 12 * l;
        int K  = (l == 0) ? FIN : 256;
        int Kp = (l == 0) ? KP0 : 256;
        addc((const float*)d_in[base + 0], w_lr[l], 256, 256, K, Kp);
        addc((const float*)d_in[base + 2], w_lr[l] + (size_t)256 * Kp, 256, 256, K, Kp);
        addg((const float*)d_in[base + 8], w_ih[l]);
        addg((const float*)d_in[base + 9], w_hh[l]);
    }
    addc(mh1_w, w_m1, NH1, NH1, 256, 256);
    addc(mh2_w, w_m2, NH2, NH2, NH1, NH1);
    conv_pack<<<dim3(32, nd), dim3(256), 0, stream>>>(cp, nd);

    fold_w<<<dim3(G4H), dim3(320), 0, stream>>>(r0_wih, lin0_w, w_r0f);
    fold_b<<<dim3(4), dim3(256), 0, stream>>>(r0_wih, lin0_b, r0_bih, r0_bhh, b_r0);

    BPack bp;
    for (int l = 0; l < 3; ++l) {
        int base = 10 + 12 * l;
        bp.a[l] = (const float*)d_in[base + 1];
        bp.b[l] = (const float*)d_in[base + 3];
        bp.dst[l] = blr[l];
    }
    concat_pack<<<dim3(6), dim3(256), 0, stream>>>(bp);

    // ---- CSR build ----
    zero_f32<<<dim3(256), dim3(256), 0, stream>>>((float*)deg, NN);
    edge_hist<<<dim3((EP + 255) / 256), dim3(256), 0, stream>>>(ei, deg);
    scan_part<<<dim3(SCB), dim3(256), 0, stream>>>(deg, bsum);
    scan_tops<<<dim3(1), dim3(512), 0, stream>>>(bsum, bpre, rowptr);
    scan_fill<<<dim3(SCB), dim3(256), 0, stream>>>(deg, bpre, rowptr, cursor);
    edge_fill<<<dim3((EP + 255) / 256), dim3(256), 0, stream>>>(ei, rowptr, cursor, esrc);

    // ---- rnn0 LSTM directly from xb (folded weights; h=c=0 start) ----
    GL(xb, w_r0f, KP0, nullptr, nullptr, 0, b_r0, nullptr, nullptr, cb, hA);

    // ---- 3x (GATv2 -> LN+ELU -> LSTM) ----
    short* hprev = hA;
    short* hnext = hB;
    for (int l = 0; l < 3; ++l) {
        int base = 10 + 12 * l;
        const float* att = (const float*)d_in[base + 4];
        const float* gb  = (const float*)d_in[base + 5];
        const float* lg  = (const float*)d_in[base + 6];
        const float* lb  = (const float*)d_in[base + 7];
        const float* bih = (const float*)d_in[base + 10];
        const float* bhh = (const float*)d_in[base + 11];
        const short* Ain = (l == 0) ? xb : hprev;
        int K = (l == 0) ? KP0 : 256;

        G(Ain, w_lr[l], K, blr[l], nullptr, xlr, MP, 512, 1);
        gat_fused<<<dim3((NN + 3) / 4), dim3(256), 0, stream>>>(
            xlr, rowptr, esrc, att, gb, lg, lb, ybb);
        GL(ybb, w_ih[l], 256, hprev, w_hh[l], 256, bih, bhh, cb, cb, hnext);
        short* t = hprev; hprev = hnext; hnext = t;
    }

    // ---- mean pool (sorted batch) + MLP head ----
    pool_mean<<<dim3((BG + 3) / 4), dim3(256), 0, stream>>>(hprev, batch, poolb);
    G(poolb, w_m1, 256, mh1_b, z1, nullptr, BG, NH1, 0);
    ln_act_kernel<<<dim3(BG), dim3(256), 0, stream>>>(z1, ln1_g, ln1_b, nullptr, z1b, NH1, 1);
    G(z1b, w_m2, NH1, mh2_b, out, nullptr, BG, NH2, 0);
    ln_act_kernel<<<dim3(BG), dim3(256), 0, stream>>>(out, ln2_g, ln2_b, out, nullptr, NH2, 0);
}

// Round 24
// 1281.772 us; speedup vs baseline: 1.4160x; 1.0373x over previous
//
#include <hip/hip_runtime.h>
#include <hip/hip_bf16.h>
#include <math.h>

// ---------------------------------------------------------------------------
// GraphEncoder round 24: r23 (best: 1330us) + 4-wide gather batching in
// gat_fused. The per-edge loop was a serial dependent-gather chain
// (~500cyc L3 latency x avg-degree-5 per node); now each 4-edge chunk
// issues all 4 esrc loads + all 4 xlr gathers back-to-back (named regs,
// no runtime-indexed arrays), then processes them in the SAME edge order
// (wave-uniform guards; rowptr is per-wave uniform) -> 4-deep latency
// overlap, bit-identical math.
// Everything else identical to r23: BM=256 depth-2 counted-vmcnt MFMA GEMM
// (~185us plateau), lin0->rnn0 fold, div-free conv_x, hierarchical scan,
// batched conversions. Session: 14009us (r3) -> 1330us (r23), 10.5x.
// ---------------------------------------------------------------------------

constexpr int NN    = 100000;
constexpr int EE    = 400000;
constexpr int EP    = EE + NN;      // 500000 (incl self loops)
constexpr int BG    = 4096;
constexpr int FIN   = 300;
constexpr int HEADS = 4;
constexpr int HID   = 256;
constexpr int G4H   = 1024;
constexpr int NH1   = 512;
constexpr int NH2   = 768;
constexpr int MP    = 100352;       // 392*256, 392 % 8 == 0
constexpr int KP0   = 320;          // FIN padded to mult of 32
constexpr int SCB   = 392;          // scan blocks (392*256 = 100352 >= NN)

typedef __attribute__((ext_vector_type(4))) float f32x4;
typedef __attribute__((ext_vector_type(8))) short s16x8;
typedef __attribute__((ext_vector_type(4))) short s16x4;

#define LOG2E 1.4426950408889634f

// fast HW transcendentals (v_exp_f32 = 2^x, v_rcp_f32)
__device__ inline float fexp(float x)  { return __builtin_amdgcn_exp2f(x * LOG2E); }
__device__ inline float frcp(float x)  { return __builtin_amdgcn_rcpf(x); }
__device__ inline float fsigm(float x) { return frcp(1.f + __builtin_amdgcn_exp2f(-LOG2E * x)); }
__device__ inline float ftanh(float x) { return 1.f - 2.f * frcp(1.f + __builtin_amdgcn_exp2f(2.f * LOG2E * x)); }

__device__ inline float b2f(short s) { return __uint_as_float(((unsigned)(unsigned short)s) << 16); }
__device__ inline short f2b(float f) {
    unsigned u = __float_as_uint(f);
    u += 0x7fff + ((u >> 16) & 1);          // round-to-nearest-even
    return (short)(u >> 16);
}
__device__ inline float wsum64(float v) {
#pragma unroll
    for (int o = 32; o > 0; o >>= 1) v += __shfl_xor(v, o);
    return v;
}

// ---------------- utility kernels -------------------------------------------
__global__ __launch_bounds__(256) void zero_f32(float* __restrict__ p, long long n)
{
    long long i = (long long)blockIdx.x * 256 + threadIdx.x;
    long long stride = (long long)gridDim.x * 256;
    for (; i < n; i += stride) p[i] = 0.f;
}

// x pad-convert without divisions: 8 rows/block, threads stride the 320 cols
__global__ __launch_bounds__(256) void conv_x(
    const float* __restrict__ src, short* __restrict__ dst)
{
    int r0 = blockIdx.x * 8;
#pragma unroll
    for (int rr = 0; rr < 8; ++rr) {
        int r = r0 + rr;
        const float* s = src + (size_t)r * FIN;
        short* d = dst + (size_t)r * KP0;
        bool valid = (r < NN);
        for (int c = threadIdx.x; c < KP0; c += 256) {
            float v = (valid && c < FIN) ? s[c] : 0.f;
            d[c] = f2b(v);
        }
    }
}

// ---- batched weight conversions: one dispatch for all small tensors --------
// gate==0: pad-convert [rsrc x Ks] -> [n/Kd x Kd] bf16
// gate==1: gate-interleaved LSTM pack (Ks = K), n = 1024*K
struct CDesc { const float* src; short* dst; int n, Ks, Kd, rsrc, gate; };
struct CPack { CDesc d[16]; };

__global__ __launch_bounds__(256) void conv_pack(CPack p, int nd)
{
    int di = blockIdx.y;
    if (di >= nd) return;
    CDesc c = p.d[di];
    int stride = gridDim.x * 256;
    for (int i = blockIdx.x * 256 + threadIdx.x; i < c.n; i += stride) {
        float v;
        if (c.gate) {
            int K  = c.Ks;
            int pp = i / K, k = i - pp * K;
            int gate = (pp >> 4) & 3;
            int ch   = (pp >> 7) * 32 + ((pp >> 6) & 1) * 16 + (pp & 15);
            v = c.src[(size_t)(gate * 256 + ch) * K + k];
        } else {
            int r = i / c.Kd, k = i - r * c.Kd;
            v = (r < c.rsrc && k < c.Ks) ? c.src[(size_t)r * c.Ks + k] : 0.f;
        }
        c.dst[i] = f2b(v);
    }
}

// ---- lin0->rnn0 fold: W'[packed p][k] = sum_h r0_wih[orig][h]*lin0_w[h][k] --
// one block per packed row p (gate-interleaved dest); 320 threads = cols.
__global__ __launch_bounds__(320) void fold_w(
    const float* __restrict__ wih, const float* __restrict__ lw,
    short* __restrict__ dst)
{
    __shared__ float row[256];
    int p = blockIdx.x;
    int gate = (p >> 4) & 3;
    int ch   = (p >> 7) * 32 + ((p >> 6) & 1) * 16 + (p & 15);
    int orig = gate * 256 + ch;
    for (int h = threadIdx.x; h < 256; h += 320)
        row[h] = wih[(size_t)orig * 256 + h];
    __syncthreads();
    int j = threadIdx.x;                 // 0..319
    float s = 0.f;
    if (j < FIN) {
        for (int h = 0; h < 256; ++h) s += row[h] * lw[(size_t)h * FIN + j];
    }
    dst[(size_t)p * KP0 + j] = f2b(s);
}

// b'[orig t] = r0_bih[t] + r0_bhh[t] + sum_h r0_wih[t][h]*lin0_b[h]
__global__ __launch_bounds__(256) void fold_b(
    const float* __restrict__ wih, const float* __restrict__ lb,
    const float* __restrict__ bih, const float* __restrict__ bhh,
    float* __restrict__ dst)
{
    int t = blockIdx.x * 256 + threadIdx.x;
    if (t >= G4H) return;
    float s = bih[t] + bhh[t];
    for (int h = 0; h < 256; ++h) s += wih[(size_t)t * 256 + h] * lb[h];
    dst[t] = s;
}

// ---- batched bias concat (3 layers x [bl|br] -> blr f32[512]) --------------
struct BPack { const float* a[3]; const float* b[3]; float* dst[3]; };
__global__ __launch_bounds__(256) void concat_pack(BPack p)
{
    int l = blockIdx.x >> 1;
    int half = blockIdx.x & 1;
    const float* s = half ? p.b[l] : p.a[l];
    p.dst[l][half * 256 + threadIdx.x] = s[threadIdx.x];
}

// ---------------- CSR build -------------------------------------------------
__global__ __launch_bounds__(256) void edge_hist(const int* __restrict__ ei,
                                                 int* __restrict__ deg)
{
    int e = blockIdx.x * 256 + threadIdx.x;
    if (e >= EP) return;
    int d = (e < EE) ? ei[EE + e] : e - EE;
    atomicAdd(&deg[d], 1);
}

// pass 1: per-block chunk sums (coalesced)
__global__ __launch_bounds__(256) void scan_part(const int* __restrict__ deg,
                                                 int* __restrict__ bsum)
{
    int b = blockIdx.x, t = threadIdx.x;
    int i = b * 256 + t;
    int v = (i < NN) ? deg[i] : 0;
#pragma unroll
    for (int o = 32; o > 0; o >>= 1) v += __shfl_down(v, o);
    __shared__ int sh[4];
    if ((t & 63) == 0) sh[t >> 6] = v;
    __syncthreads();
    if (t == 0) bsum[b] = sh[0] + sh[1] + sh[2] + sh[3];
}

// pass 2: scan the 392 block sums (single small block)
__global__ __launch_bounds__(512) void scan_tops(const int* __restrict__ bsum,
                                                 int* __restrict__ bpre,
                                                 int* __restrict__ rowptr)
{
    __shared__ int sh[512];
    int t = threadIdx.x;
    int v = (t < SCB) ? bsum[t] : 0;
    sh[t] = v;
    __syncthreads();
    for (int off = 1; off < 512; off <<= 1) {
        int u = (t >= off) ? sh[t - off] : 0;
        __syncthreads();
        sh[t] += u;
        __syncthreads();
    }
    if (t < SCB) bpre[t] = sh[t] - v;          // exclusive prefix
    if (t == SCB - 1) rowptr[NN] = sh[t];      // total == EP
}

// pass 3: intra-block exclusive scan + write rowptr/cursor (coalesced)
__global__ __launch_bounds__(256) void scan_fill(const int* __restrict__ deg,
                                                 const int* __restrict__ bpre,
                                                 int* __restrict__ rowptr,
                                                 int* __restrict__ cursor)
{
    __shared__ int sh[256];
    int b = blockIdx.x, t = threadIdx.x;
    int i = b * 256 + t;
    int v = (i < NN) ? deg[i] : 0;
    sh[t] = v;
    __syncthreads();
    for (int off = 1; off < 256; off <<= 1) {
        int u = (t >= off) ? sh[t - off] : 0;
        __syncthreads();
        sh[t] += u;
        __syncthreads();
    }
    if (i < NN) {
        rowptr[i] = bpre[b] + sh[t] - v;       // exclusive
        cursor[i] = 0;
    }
}

__global__ __launch_bounds__(256) void edge_fill(const int* __restrict__ ei,
                                                 const int* __restrict__ rowptr,
                                                 int* __restrict__ cursor,
                                                 int* __restrict__ esrc)
{
    int e = blockIdx.x * 256 + threadIdx.x;
    if (e >= EP) return;
    int s, d;
    if (e < EE) { s = ei[e]; d = ei[EE + e]; }
    else        { s = d = e - EE; }
    int slot = rowptr[d] + atomicAdd(&cursor[d], 1);
    esrc[slot] = s;
}

// ---------------- MFMA GEMM with fused epilogues ----------------------------
// (identical schedule to r17/r19/r20/r21/r22/r23)
__global__ __launch_bounds__(512) void mfma_gemm(
    const short* __restrict__ A1, const short* __restrict__ B1, int K1,
    const short* __restrict__ A2, const short* __restrict__ B2, int K2,
    const float* __restrict__ bias,
    const float* __restrict__ bih, const float* __restrict__ bhh,
    const float* __restrict__ c_in, float* __restrict__ c_out,
    short* __restrict__ h_out,
    float* __restrict__ Cf, short* __restrict__ Cb, int N, int mode, int nct)
{
    __shared__ __align__(16) short sA[2][256 * 32];   // 16KB each
    __shared__ __align__(16) short sB[2][128 * 32];   // 8KB each
    const int tid  = threadIdx.x;
    const int w    = tid >> 6, lane = tid & 63;
    const int wr   = w >> 1,  wc   = w & 1;      // 4x2 waves of 64x64
    // XCD-aware decode (consecutive bids round-robin across 8 XCDs)
    const int bid  = blockIdx.x;
    const int xcd  = bid & 7;
    const int slot = bid >> 3;
    const int g    = slot / nct;
    const int tcol = slot - g * nct;
    const int row0 = (g * 8 + xcd) * 256;
    const int col0 = tcol * 128;

    f32x4 acc[4][4];
#pragma unroll
    for (int m = 0; m < 4; ++m)
#pragma unroll
        for (int n = 0; n < 4; ++n) acc[m][n] = (f32x4){0.f, 0.f, 0.f, 0.f};

    const int rs = lane >> 2;
    const int cs = lane & 3;
    const int KK = K1 + K2;
    const int nsteps = KK >> 5;
    const int l16 = lane & 15;
    const int rloc = wr * 64 + ((lane >> 4) << 2);   // block-local base row

    // mode-2: prefetch c_in into regs; latency hides under the K-loop
    float co_pre[4][4] = {};
    const int ch = tcol * 32 + wc * 16 + l16;        // mode-2 channel
    if (mode == 2 && c_in) {
#pragma unroll
        for (int m = 0; m < 4; ++m)
#pragma unroll
            for (int r = 0; r < 4; ++r)
                co_pre[m][r] = c_in[(size_t)(row0 + rloc + m * 16 + r) * HID + ch];
    }

    // 3 global_load_lds per wave per stage call (2x A-seg, 1x B-seg)
    auto stage = [&](int buf, int k0) {
        const short* Ak; const short* Bk; int kk, ld;
        if (k0 < K1) { Ak = A1; Bk = B1; kk = k0;      ld = K1; }
        else         { Ak = A2; Bk = B2; kk = k0 - K1; ld = K2; }
#pragma unroll
        for (int i = 0; i < 2; ++i) {
            int seg = w * 2 + i;                     // 16 A-segs of 16 rows
            int row = seg * 16 + rs;
            int c8  = cs ^ ((row + (row >> 2)) & 3);
            const short* ga = Ak + (size_t)(row0 + row) * ld + kk + c8 * 8;
            short* la = &sA[buf][seg * 512 + lane * 8];
            __builtin_amdgcn_global_load_lds((const __attribute__((address_space(1))) void*)ga,
                                             (__attribute__((address_space(3))) void*)la, 16, 0, 0);
        }
        {
            int row = w * 16 + rs;                   // 8 B-segs of 16 rows
            int c8  = cs ^ ((row + (row >> 2)) & 3);
            const short* gb = Bk + (size_t)(col0 + row) * ld + kk + c8 * 8;
            short* lb = &sB[buf][w * 512 + lane * 8];
            __builtin_amdgcn_global_load_lds((const __attribute__((address_space(1))) void*)gb,
                                             (__attribute__((address_space(3))) void*)lb, 16, 0, 0);
        }
    };

    stage(0, 0);
    stage(1, 32);                  // 6 loads in flight; KK >= 64 guaranteed
    int cur = 0;
    for (int t = 0; t < nsteps; ++t) {
        // wait for group t (oldest); keep the newer group in flight
        if (t + 1 < nsteps) asm volatile("s_waitcnt vmcnt(3)" ::: "memory");
        else                asm volatile("s_waitcnt vmcnt(0)" ::: "memory");
        __builtin_amdgcn_s_barrier();          // all waves: buf[cur] ready
        asm volatile("" ::: "memory");

        s16x8 af[4], bg[4];
        {
            const int rl = lane & 15;
            const int cw = lane >> 4;
#pragma unroll
            for (int m = 0; m < 4; ++m) {
                int r  = wr * 64 + m * 16 + rl;
                int sl = cw ^ ((r + (r >> 2)) & 3);
                af[m] = *(const s16x8*)(&sA[cur][r * 32 + sl * 8]);
                int c  = wc * 64 + m * 16 + rl;
                int sc = cw ^ ((c + (c >> 2)) & 3);
                bg[m] = *(const s16x8*)(&sB[cur][c * 32 + sc * 8]);
            }
        }
        // MFMAs consume all af/bg (compiler interleaves reads+MFMA with
        // fine-grained lgkmcnt); after them this wave's LDS reads are done.
#pragma unroll
        for (int m = 0; m < 4; ++m)
#pragma unroll
            for (int n = 0; n < 4; ++n)
                acc[m][n] = __builtin_amdgcn_mfma_f32_16x16x32_bf16(af[m], bg[n], acc[m][n], 0, 0, 0);

        __builtin_amdgcn_s_barrier();          // all waves done READING buf[cur]
        asm volatile("" ::: "memory");
        if (t + 2 < nsteps) stage(cur, (t + 2) * 32);   // re-stage 2 ahead
        cur ^= 1;
    }

    // C/D layout: col=lane&15, row=(lane>>4)*4+reg
    const int rbase = row0 + rloc;
    if (mode == 2) {
        float bi[4];
#pragma unroll
        for (int gg2 = 0; gg2 < 4; ++gg2) {
            float bb = bhh ? bhh[gg2 * 256 + ch] : 0.f;
            bi[gg2] = bih[gg2 * 256 + ch] + bb;
        }
#pragma unroll
        for (int m = 0; m < 4; ++m) {
#pragma unroll
            for (int r = 0; r < 4; ++r) {
                int row = rbase + m * 16 + r;
                float gi = acc[m][0][r] + bi[0];
                float gf = acc[m][1][r] + bi[1];
                float gg = acc[m][2][r] + bi[2];
                float go = acc[m][3][r] + bi[3];
                size_t idx = (size_t)row * HID + ch;
                float co = c_in ? co_pre[m][r] : 0.f;
                float c2 = fsigm(gf) * co + fsigm(gi) * ftanh(gg);
                float h2 = fsigm(go) * ftanh(c2);
                c_out[idx] = c2;
                h_out[idx] = f2b(h2);
            }
        }
    } else {
        const int cbase = col0 + wc * 64 + l16;
#pragma unroll
        for (int n = 0; n < 4; ++n) {
            int col = cbase + n * 16;
            float ba = bias ? bias[col] : 0.f;
#pragma unroll
            for (int m = 0; m < 4; ++m) {
#pragma unroll
                for (int r = 0; r < 4; ++r) {
                    int row = rbase + m * 16 + r;
                    float v = acc[m][n][r] + ba;
                    size_t idx = (size_t)row * N + col;
                    if (mode == 1) Cb[idx] = f2b(v);
                    else           Cf[idx] = v;
                }
            }
        }
    }
}

// ---------------- fused GATv2 (softmax + aggregate + bias + LN + ELU) -------
// quarter-wave per head; 4-wide gather batching (latency overlap).
// xlr: [MP][512] bf16, cols 0..255 = lin_l(x), 256..511 = lin_r(x).
__global__ __launch_bounds__(256) void gat_fused(
    const short* __restrict__ xlr, const int* __restrict__ rowptr,
    const int* __restrict__ esrc, const float* __restrict__ att,
    const float* __restrict__ gb, const float* __restrict__ lg,
    const float* __restrict__ lb, short* __restrict__ outb)
{
    int i    = blockIdx.x * 4 + (threadIdx.x >> 6);
    int lane = threadIdx.x & 63;
    if (i >= NN) return;
    const int cb = (lane >> 4) * 64 + (lane & 15) * 4;   // channel base

    float xr4[4], at4[4];
    {
        s16x4 v = *(const s16x4*)(&xlr[(size_t)i * 512 + 256 + cb]);
#pragma unroll
        for (int j = 0; j < 4; ++j) { xr4[j] = b2f(v[j]); at4[j] = att[cb + j]; }
    }
    float mx = -INFINITY, sm = 0.f;
    float ac[4] = {0.f, 0.f, 0.f, 0.f};

    // process one gathered edge (identical math/order to r23's loop body)
    auto process = [&](s16x4 xv) {
        float xs[4], pl = 0.f;
#pragma unroll
        for (int j = 0; j < 4; ++j) {
            xs[j] = b2f(xv[j]);
            float v = xs[j] + xr4[j];
            v = (v >= 0.f) ? v : 0.2f * v;
            pl += v * at4[j];
        }
#pragma unroll
        for (int o = 1; o < 16; o <<= 1) pl += __shfl_xor(pl, o);   // head logit
        float mn = fmaxf(mx, pl);
        float sc = fexp(mx - mn);            // first iter: exp(-inf)=0
        float a  = fexp(pl - mn);
        sm = sm * sc + a;
#pragma unroll
        for (int j = 0; j < 4; ++j) ac[j] = ac[j] * sc + a * xs[j];
        mx = mn;
    };

    int lo = rowptr[i], hi = rowptr[i + 1];   // wave-uniform; deg >= 1
    for (int e0 = lo; e0 < hi; e0 += 4) {
        int n = hi - e0;                      // wave-uniform chunk size
        // issue all esrc loads, then all 4 gathers back-to-back (4-deep
        // latency overlap); inactive slots re-load edge e0 (safe, unused).
        int s0 = esrc[e0];
        int s1 = (n > 1) ? esrc[e0 + 1] : s0;
        int s2 = (n > 2) ? esrc[e0 + 2] : s0;
        int s3 = (n > 3) ? esrc[e0 + 3] : s0;
        s16x4 x0 = *(const s16x4*)(&xlr[(size_t)s0 * 512 + cb]);
        s16x4 x1 = *(const s16x4*)(&xlr[(size_t)s1 * 512 + cb]);
        s16x4 x2 = *(const s16x4*)(&xlr[(size_t)s2 * 512 + cb]);
        s16x4 x3 = *(const s16x4*)(&xlr[(size_t)s3 * 512 + cb]);
        process(x0);
        if (n > 1) process(x1);
        if (n > 2) process(x2);
        if (n > 3) process(x3);
    }

    // y = ac/sm (+ gat bias), then LayerNorm(256) + ELU, write bf16
    float val[4], s1v = 0.f, s2v = 0.f;
    float ism = frcp(sm);
#pragma unroll
    for (int j = 0; j < 4; ++j) {
        float v = ac[j] * ism + gb[cb + j];
        val[j] = v; s1v += v; s2v += v * v;
    }
    s1v = wsum64(s1v); s2v = wsum64(s2v);
    float mean = s1v * (1.f / 256.f);
    float var  = s2v * (1.f / 256.f) - mean * mean;
    float inv  = rsqrtf(var + 1e-5f);
    s16x4 ov;
#pragma unroll
    for (int j = 0; j < 4; ++j) {
        float v = (val[j] - mean) * inv * lg[cb + j] + lb[cb + j];
        v = (v > 0.f) ? v : (fexp(v) - 1.f);
        ov[j] = f2b(v);
    }
    *(s16x4*)(&outb[(size_t)i * HID + cb]) = ov;
}

// ---------------- LayerNorm (+act) for the MLP head -------------------------
__global__ __launch_bounds__(256) void ln_act_kernel(
    const float* __restrict__ in, const float* __restrict__ gamma,
    const float* __restrict__ beta, float* __restrict__ outf,
    short* __restrict__ outb, int width, int act)
{
    int row = blockIdx.x;
    const float* ip = in + (size_t)row * width;
    float vals[3];
    float s = 0.f, ss = 0.f;
    int nw = width >> 8;
    for (int i = 0; i < nw; ++i) {
        int c = threadIdx.x + (i << 8);
        float v = ip[c];
        vals[i] = v; s += v; ss += v * v;
    }
#pragma unroll
    for (int off = 32; off > 0; off >>= 1) {
        s  += __shfl_down(s, off);
        ss += __shfl_down(ss, off);
    }
    __shared__ float sh[8];
    int wv = threadIdx.x >> 6, lane = threadIdx.x & 63;
    if (lane == 0) { sh[wv] = s; sh[4 + wv] = ss; }
    __syncthreads();
    if (threadIdx.x == 0) {
        sh[0] = sh[0] + sh[1] + sh[2] + sh[3];
        sh[4] = sh[4] + sh[5] + sh[6] + sh[7];
    }
    __syncthreads();
    float mean = sh[0] / width;
    float var  = sh[4] / width - mean * mean;
    float inv  = rsqrtf(var + 1e-5f);
    for (int i = 0; i < nw; ++i) {
        int c = threadIdx.x + (i << 8);
        float v = (vals[i] - mean) * inv * gamma[c] + beta[c];
        if (act == 1) v = fmaxf(v, 0.f);
        if (outb) outb[(size_t)row * width + c] = f2b(v);
        else      outf[(size_t)row * width + c] = v;
    }
}

// ---------------- sorted-batch mean pool ------------------------------------
__global__ __launch_bounds__(256) void pool_mean(
    const short* __restrict__ h, const int* __restrict__ batch,
    short* __restrict__ poolb)
{
    int b    = blockIdx.x * 4 + (threadIdx.x >> 6);
    int lane = threadIdx.x & 63;
    if (b >= BG) return;
    auto lbound = [&](int key) {
        int lo = 0, hi = NN;
        while (lo < hi) { int mid = (lo + hi) >> 1; if (batch[mid] < key) lo = mid + 1; else hi = mid; }
        return lo;
    };
    int lo = lbound(b), hi = lbound(b + 1);
    float acc[HEADS] = {0.f, 0.f, 0.f, 0.f};
    for (int r = lo; r < hi; ++r)
#pragma unroll
        for (int hh = 0; hh < HEADS; ++hh)
            acc[hh] += b2f(h[(size_t)r * HID + hh * 64 + lane]);
    float inv = 1.f / fmaxf((float)(hi - lo), 1.f);
#pragma unroll
    for (int hh = 0; hh < HEADS; ++hh)
        poolb[(size_t)b * HID + hh * 64 + lane] = f2b(acc[hh] * inv);
}

// ---------------------------------------------------------------------------
extern "C" void kernel_launch(void* const* d_in, const int* in_sizes, int n_in,
                              void* d_out, int out_size, void* d_ws, size_t ws_size,
                              hipStream_t stream)
{
    (void)in_sizes; (void)n_in; (void)out_size; (void)ws_size;
    const float* x      = (const float*)d_in[0];
    const int*   ei     = (const int*)d_in[1];
    const int*   batch  = (const int*)d_in[2];
    const float* lin0_w = (const float*)d_in[4];
    const float* lin0_b = (const float*)d_in[5];
    const float* r0_wih = (const float*)d_in[6];
    const float* r0_bih = (const float*)d_in[8];
    const float* r0_bhh = (const float*)d_in[9];
    const float* mh1_w  = (const float*)d_in[46];
    const float* mh1_b  = (const float*)d_in[47];
    const float* ln1_g  = (const float*)d_in[48];
    const float* ln1_b  = (const float*)d_in[49];
    const float* mh2_w  = (const float*)d_in[50];
    const float* mh2_b  = (const float*)d_in[51];
    const float* ln2_g  = (const float*)d_in[52];
    const float* ln2_b  = (const float*)d_in[53];
    float* out = (float*)d_out;

    // ---- workspace bump allocation ----
    char* wsb = (char*)d_ws;
    auto alloc = [&](size_t bytes) -> void* {
        void* p = (void*)wsb;
        wsb += (bytes + 255) & ~(size_t)255;
        return p;
    };
    const size_t NH = (size_t)MP * HID;
    float* cb   = (float*)alloc(NH * 4);          // LSTM cell state f32
    short* hA   = (short*)alloc(NH * 2);          // h ping
    short* hB   = (short*)alloc(NH * 2);          // h pong
    short* ybb  = (short*)alloc(NH * 2);          // GAT-out / LSTM-input bf16
    short* xlr  = (short*)alloc((size_t)MP * 512 * 2);  // [xl|xr] bf16
    int*   deg    = (int*)alloc((size_t)NN * 4);
    int*   rowptr = (int*)alloc((size_t)(NN + 1) * 4);
    int*   cursor = (int*)alloc((size_t)NN * 4);
    int*   esrc   = (int*)alloc((size_t)EP * 4);
    int*   bsum   = (int*)alloc((size_t)SCB * 4);
    int*   bpre   = (int*)alloc((size_t)SCB * 4);
    // weights bf16
    short* w_r0f  = (short*)alloc((size_t)G4H * KP0 * 2);  // folded lin0+rnn0
    float* b_r0   = (float*)alloc((size_t)G4H * 4);        // folded bias
    short* w_lr[3]; short* w_ih[3]; short* w_hh[3]; float* blr[3];
    for (int l = 0; l < 3; ++l) {
        int Kp = (l == 0) ? KP0 : 256;
        w_lr[l] = (short*)alloc((size_t)512 * Kp * 2);
        w_ih[l] = (short*)alloc((size_t)G4H * 256 * 2);
        w_hh[l] = (short*)alloc((size_t)G4H * 256 * 2);
        blr[l]  = (float*)alloc(512 * 4);
    }
    short* w_m1 = (short*)alloc((size_t)NH1 * 256 * 2);
    short* w_m2 = (short*)alloc((size_t)NH2 * NH1 * 2);
    // xb (layer-0 padded input) with head temps aliased over it (head runs
    // only after xb is dead)
    short* xb = (short*)alloc((size_t)MP * KP0 * 2);   // 64 MB
    float* z1    = (float*)xb;                          // BG*NH1 f32 (8.4MB)
    short* z1b   = (short*)(z1 + (size_t)BG * NH1);     // BG*NH1 bf16
    short* poolb = z1b + (size_t)BG * NH1;              // BG*HID bf16

    // mode 0/1 GEMM; 1-D grid with XCD swizzle (requires (M/256)%8==0)
    auto G = [&](const short* A, const short* B, int K, const float* bias,
                 float* Cf, short* Cbb, int M, int N, int mode) {
        int nrp = M / 256, nct = N / 128;
        mfma_gemm<<<dim3(nrp * nct), dim3(512), 0, stream>>>(
            A, B, K, nullptr, nullptr, 0, bias,
            nullptr, nullptr, nullptr, nullptr, nullptr, Cf, Cbb, N, mode, nct);
    };
    // mode 2 LSTM GEMM (dual-source)
    auto GL = [&](const short* A1, const short* B1, int K1,
                  const short* A2, const short* B2, int K2,
                  const float* bih, const float* bhh,
                  const float* ci, float* co, short* ho) {
        mfma_gemm<<<dim3((MP / 256) * 8), dim3(512), 0, stream>>>(
            A1, B1, K1, A2, B2, K2, nullptr,
            bih, bhh, ci, co, ho, nullptr, nullptr, G4H, 2, 8);
    };

    // ---- conversions: x pad-convert (div-free), batched weights, folds ----
    conv_x<<<dim3(MP / 8), dim3(256), 0, stream>>>(x, xb);

    CPack cp; int nd = 0;
    auto addc = [&](const float* s, short* d, int rsrc, int rdst, int Ks, int Kd) {
        cp.d[nd++] = CDesc{ s, d, rdst * Kd, Ks, Kd, rsrc, 0 };
    };
    auto addg = [&](const float* s, short* d) {
        cp.d[nd++] = CDesc{ s, d, G4H * 256, 256, 256, G4H, 1 };
    };
    for (int l = 0; l < 3; ++l) {
        int base = 10 + 12 * l;
        int K  = (l == 0) ? FIN : 256;
        int Kp = (l == 0) ? KP0 : 256;
        addc((const float*)d_in[base + 0], w_lr[l], 256, 256, K, Kp);
        addc((const float*)d_in[base + 2], w_lr[l] + (size_t)256 * Kp, 256, 256, K, Kp);
        addg((const float*)d_in[base + 8], w_ih[l]);
        addg((const float*)d_in[base + 9], w_hh[l]);
    }
    addc(mh1_w, w_m1, NH1, NH1, 256, 256);
    addc(mh2_w, w_m2, NH2, NH2, NH1, NH1);
    conv_pack<<<dim3(32, nd), dim3(256), 0, stream>>>(cp, nd);

    fold_w<<<dim3(G4H), dim3(320), 0, stream>>>(r0_wih, lin0_w, w_r0f);
    fold_b<<<dim3(4), dim3(256), 0, stream>>>(r0_wih, lin0_b, r0_bih, r0_bhh, b_r0);

    BPack bp;
    for (int l = 0; l < 3; ++l) {
        int base = 10 + 12 * l;
        bp.a[l] = (const float*)d_in[base + 1];
        bp.b[l] = (const float*)d_in[base + 3];
        bp.dst[l] = blr[l];
    }
    concat_pack<<<dim3(6), dim3(256), 0, stream>>>(bp);

    // ---- CSR build ----
    zero_f32<<<dim3(256), dim3(256), 0, stream>>>((float*)deg, NN);
    edge_hist<<<dim3((EP + 255) / 256), dim3(256), 0, stream>>>(ei, deg);
    scan_part<<<dim3(SCB), dim3(256), 0, stream>>>(deg, bsum);
    scan_tops<<<dim3(1), dim3(512), 0, stream>>>(bsum, bpre, rowptr);
    scan_fill<<<dim3(SCB), dim3(256), 0, stream>>>(deg, bpre, rowptr, cursor);
    edge_fill<<<dim3((EP + 255) / 256), dim3(256), 0, stream>>>(ei, rowptr, cursor, esrc);

    // ---- rnn0 LSTM directly from xb (folded weights; h=c=0 start) ----
    GL(xb, w_r0f, KP0, nullptr, nullptr, 0, b_r0, nullptr, nullptr, cb, hA);

    // ---- 3x (GATv2 -> LN+ELU -> LSTM) ----
    short* hprev = hA;
    short* hnext = hB;
    for (int l = 0; l < 3; ++l) {
        int base = 10 + 12 * l;
        const float* att = (const float*)d_in[base + 4];
        const float* gb  = (const float*)d_in[base + 5];
        const float* lg  = (const float*)d_in[base + 6];
        const float* lb  = (const float*)d_in[base + 7];
        const float* bih = (const float*)d_in[base + 10];
        const float* bhh = (const float*)d_in[base + 11];
        const short* Ain = (l == 0) ? xb : hprev;
        int K = (l == 0) ? KP0 : 256;

        G(Ain, w_lr[l], K, blr[l], nullptr, xlr, MP, 512, 1);
        gat_fused<<<dim3((NN + 3) / 4), dim3(256), 0, stream>>>(
            xlr, rowptr, esrc, att, gb, lg, lb, ybb);
        GL(ybb, w_ih[l], 256, hprev, w_hh[l], 256, bih, bhh, cb, cb, hnext);
        short* t = hprev; hprev = hnext; hnext = t;
    }

    // ---- mean pool (sorted batch) + MLP head ----
    pool_mean<<<dim3((BG + 3) / 4), dim3(256), 0, stream>>>(hprev, batch, poolb);
    G(poolb, w_m1, 256, mh1_b, z1, nullptr, BG, NH1, 0);
    ln_act_kernel<<<dim3(BG), dim3(256), 0, stream>>>(z1, ln1_g, ln1_b, nullptr, z1b, NH1, 1);
    G(z1b, w_m2, NH1, mh2_b, out, nullptr, BG, NH2, 0);
    ln_act_kernel<<<dim3(BG), dim3(256), 0, stream>>>(out, ln2_g, ln2_b, out, nullptr, NH2, 0);
}

// Round 25
// 1256.528 us; speedup vs baseline: 1.4445x; 1.0201x over previous
//
#include <hip/hip_runtime.h>
#include <hip/hip_bf16.h>
#include <math.h>

// ---------------------------------------------------------------------------
// GraphEncoder round 25: r24 (best: 1282us) + two residual polish items:
//  (1) gat_fused gather batching 4 -> 8 wide: avg degree 5 meant the 4-wide
//      loop still ran two chunks (two exposed ~500cyc gather windows); 8-wide
//      collapses deg<=8 nodes to ONE window. Same process() order.
//  (2) conv_pack restructured to row-per-block loops (like conv_x): the
//      per-element runtime division (14M times) is gone; gate-interleave
//      bit-decode hoisted to once per row. Same element values.
// Everything else identical to r24: BM=256 depth-2 counted-vmcnt MFMA GEMM
// (~187us plateau, 6x-verified), lin0->rnn0 fold, div-free conv_x,
// hierarchical scan. Session: 14009us (r3) -> 1282us (r24), 10.9x.
// ---------------------------------------------------------------------------

constexpr int NN    = 100000;
constexpr int EE    = 400000;
constexpr int EP    = EE + NN;      // 500000 (incl self loops)
constexpr int BG    = 4096;
constexpr int FIN   = 300;
constexpr int HEADS = 4;
constexpr int HID   = 256;
constexpr int G4H   = 1024;
constexpr int NH1   = 512;
constexpr int NH2   = 768;
constexpr int MP    = 100352;       // 392*256, 392 % 8 == 0
constexpr int KP0   = 320;          // FIN padded to mult of 32
constexpr int SCB   = 392;          // scan blocks (392*256 = 100352 >= NN)

typedef __attribute__((ext_vector_type(4))) float f32x4;
typedef __attribute__((ext_vector_type(8))) short s16x8;
typedef __attribute__((ext_vector_type(4))) short s16x4;

#define LOG2E 1.4426950408889634f

// fast HW transcendentals (v_exp_f32 = 2^x, v_rcp_f32)
__device__ inline float fexp(float x)  { return __builtin_amdgcn_exp2f(x * LOG2E); }
__device__ inline float frcp(float x)  { return __builtin_amdgcn_rcpf(x); }
__device__ inline float fsigm(float x) { return frcp(1.f + __builtin_amdgcn_exp2f(-LOG2E * x)); }
__device__ inline float ftanh(float x) { return 1.f - 2.f * frcp(1.f + __builtin_amdgcn_exp2f(2.f * LOG2E * x)); }

__device__ inline float b2f(short s) { return __uint_as_float(((unsigned)(unsigned short)s) << 16); }
__device__ inline short f2b(float f) {
    unsigned u = __float_as_uint(f);
    u += 0x7fff + ((u >> 16) & 1);          // round-to-nearest-even
    return (short)(u >> 16);
}
__device__ inline float wsum64(float v) {
#pragma unroll
    for (int o = 32; o > 0; o >>= 1) v += __shfl_xor(v, o);
    return v;
}

// ---------------- utility kernels -------------------------------------------
__global__ __launch_bounds__(256) void zero_f32(float* __restrict__ p, long long n)
{
    long long i = (long long)blockIdx.x * 256 + threadIdx.x;
    long long stride = (long long)gridDim.x * 256;
    for (; i < n; i += stride) p[i] = 0.f;
}

// x pad-convert without divisions: 8 rows/block, threads stride the 320 cols
__global__ __launch_bounds__(256) void conv_x(
    const float* __restrict__ src, short* __restrict__ dst)
{
    int r0 = blockIdx.x * 8;
#pragma unroll
    for (int rr = 0; rr < 8; ++rr) {
        int r = r0 + rr;
        const float* s = src + (size_t)r * FIN;
        short* d = dst + (size_t)r * KP0;
        bool valid = (r < NN);
        for (int c = threadIdx.x; c < KP0; c += 256) {
            float v = (valid && c < FIN) ? s[c] : 0.f;
            d[c] = f2b(v);
        }
    }
}

// ---- batched weight conversions: one dispatch for all small tensors --------
// Row-per-block loops (no per-element division).
// gate==0: pad-convert [rsrc x Ks] -> [rows x Kd] bf16
// gate==1: gate-interleaved LSTM pack, rows=1024, Ks=Kd=256
struct CDesc { const float* src; short* dst; int rows, Ks, Kd, rsrc, gate; };
struct CPack { CDesc d[16]; };

__global__ __launch_bounds__(256) void conv_pack(CPack p, int nd)
{
    int di = blockIdx.y;
    if (di >= nd) return;
    CDesc c = p.d[di];
    for (int r = blockIdx.x; r < c.rows; r += gridDim.x) {
        short* d = c.dst + (size_t)r * c.Kd;
        if (c.gate) {
            int gate = (r >> 4) & 3;
            int ch   = (r >> 7) * 32 + ((r >> 6) & 1) * 16 + (r & 15);
            const float* s = c.src + (size_t)(gate * 256 + ch) * c.Ks;
            for (int k = threadIdx.x; k < c.Kd; k += 256)
                d[k] = f2b(s[k]);
        } else {
            const float* s = c.src + (size_t)r * c.Ks;
            bool valid = (r < c.rsrc);
            for (int k = threadIdx.x; k < c.Kd; k += 256) {
                float v = (valid && k < c.Ks) ? s[k] : 0.f;
                d[k] = f2b(v);
            }
        }
    }
}

// ---- lin0->rnn0 fold: W'[packed p][k] = sum_h r0_wih[orig][h]*lin0_w[h][k] --
// one block per packed row p (gate-interleaved dest); 320 threads = cols.
__global__ __launch_bounds__(320) void fold_w(
    const float* __restrict__ wih, const float* __restrict__ lw,
    short* __restrict__ dst)
{
    __shared__ float row[256];
    int p = blockIdx.x;
    int gate = (p >> 4) & 3;
    int ch   = (p >> 7) * 32 + ((p >> 6) & 1) * 16 + (p & 15);
    int orig = gate * 256 + ch;
    for (int h = threadIdx.x; h < 256; h += 320)
        row[h] = wih[(size_t)orig * 256 + h];
    __syncthreads();
    int j = threadIdx.x;                 // 0..319
    float s = 0.f;
    if (j < FIN) {
        for (int h = 0; h < 256; ++h) s += row[h] * lw[(size_t)h * FIN + j];
    }
    dst[(size_t)p * KP0 + j] = f2b(s);
}

// b'[orig t] = r0_bih[t] + r0_bhh[t] + sum_h r0_wih[t][h]*lin0_b[h]
__global__ __launch_bounds__(256) void fold_b(
    const float* __restrict__ wih, const float* __restrict__ lb,
    const float* __restrict__ bih, const float* __restrict__ bhh,
    float* __restrict__ dst)
{
    int t = blockIdx.x * 256 + threadIdx.x;
    if (t >= G4H) return;
    float s = bih[t] + bhh[t];
    for (int h = 0; h < 256; ++h) s += wih[(size_t)t * 256 + h] * lb[h];
    dst[t] = s;
}

// ---- batched bias concat (3 layers x [bl|br] -> blr f32[512]) --------------
struct BPack { const float* a[3]; const float* b[3]; float* dst[3]; };
__global__ __launch_bounds__(256) void concat_pack(BPack p)
{
    int l = blockIdx.x >> 1;
    int half = blockIdx.x & 1;
    const float* s = half ? p.b[l] : p.a[l];
    p.dst[l][half * 256 + threadIdx.x] = s[threadIdx.x];
}

// ---------------- CSR build -------------------------------------------------
__global__ __launch_bounds__(256) void edge_hist(const int* __restrict__ ei,
                                                 int* __restrict__ deg)
{
    int e = blockIdx.x * 256 + threadIdx.x;
    if (e >= EP) return;
    int d = (e < EE) ? ei[EE + e] : e - EE;
    atomicAdd(&deg[d], 1);
}

// pass 1: per-block chunk sums (coalesced)
__global__ __launch_bounds__(256) void scan_part(const int* __restrict__ deg,
                                                 int* __restrict__ bsum)
{
    int b = blockIdx.x, t = threadIdx.x;
    int i = b * 256 + t;
    int v = (i < NN) ? deg[i] : 0;
#pragma unroll
    for (int o = 32; o > 0; o >>= 1) v += __shfl_down(v, o);
    __shared__ int sh[4];
    if ((t & 63) == 0) sh[t >> 6] = v;
    __syncthreads();
    if (t == 0) bsum[b] = sh[0] + sh[1] + sh[2] + sh[3];
}

// pass 2: scan the 392 block sums (single small block)
__global__ __launch_bounds__(512) void scan_tops(const int* __restrict__ bsum,
                                                 int* __restrict__ bpre,
                                                 int* __restrict__ rowptr)
{
    __shared__ int sh[512];
    int t = threadIdx.x;
    int v = (t < SCB) ? bsum[t] : 0;
    sh[t] = v;
    __syncthreads();
    for (int off = 1; off < 512; off <<= 1) {
        int u = (t >= off) ? sh[t - off] : 0;
        __syncthreads();
        sh[t] += u;
        __syncthreads();
    }
    if (t < SCB) bpre[t] = sh[t] - v;          // exclusive prefix
    if (t == SCB - 1) rowptr[NN] = sh[t];      // total == EP
}

// pass 3: intra-block exclusive scan + write rowptr/cursor (coalesced)
__global__ __launch_bounds__(256) void scan_fill(const int* __restrict__ deg,
                                                 const int* __restrict__ bpre,
                                                 int* __restrict__ rowptr,
                                                 int* __restrict__ cursor)
{
    __shared__ int sh[256];
    int b = blockIdx.x, t = threadIdx.x;
    int i = b * 256 + t;
    int v = (i < NN) ? deg[i] : 0;
    sh[t] = v;
    __syncthreads();
    for (int off = 1; off < 256; off <<= 1) {
        int u = (t >= off) ? sh[t - off] : 0;
        __syncthreads();
        sh[t] += u;
        __syncthreads();
    }
    if (i < NN) {
        rowptr[i] = bpre[b] + sh[t] - v;       // exclusive
        cursor[i] = 0;
    }
}

__global__ __launch_bounds__(256) void edge_fill(const int* __restrict__ ei,
                                                 const int* __restrict__ rowptr,
                                                 int* __restrict__ cursor,
                                                 int* __restrict__ esrc)
{
    int e = blockIdx.x * 256 + threadIdx.x;
    if (e >= EP) return;
    int s, d;
    if (e < EE) { s = ei[e]; d = ei[EE + e]; }
    else        { s = d = e - EE; }
    int slot = rowptr[d] + atomicAdd(&cursor[d], 1);
    esrc[slot] = s;
}

// ---------------- MFMA GEMM with fused epilogues ----------------------------
// (identical schedule to r17/r19-r24)
__global__ __launch_bounds__(512) void mfma_gemm(
    const short* __restrict__ A1, const short* __restrict__ B1, int K1,
    const short* __restrict__ A2, const short* __restrict__ B2, int K2,
    const float* __restrict__ bias,
    const float* __restrict__ bih, const float* __restrict__ bhh,
    const float* __restrict__ c_in, float* __restrict__ c_out,
    short* __restrict__ h_out,
    float* __restrict__ Cf, short* __restrict__ Cb, int N, int mode, int nct)
{
    __shared__ __align__(16) short sA[2][256 * 32];   // 16KB each
    __shared__ __align__(16) short sB[2][128 * 32];   // 8KB each
    const int tid  = threadIdx.x;
    const int w    = tid >> 6, lane = tid & 63;
    const int wr   = w >> 1,  wc   = w & 1;      // 4x2 waves of 64x64
    // XCD-aware decode (consecutive bids round-robin across 8 XCDs)
    const int bid  = blockIdx.x;
    const int xcd  = bid & 7;
    const int slot = bid >> 3;
    const int g    = slot / nct;
    const int tcol = slot - g * nct;
    const int row0 = (g * 8 + xcd) * 256;
    const int col0 = tcol * 128;

    f32x4 acc[4][4];
#pragma unroll
    for (int m = 0; m < 4; ++m)
#pragma unroll
        for (int n = 0; n < 4; ++n) acc[m][n] = (f32x4){0.f, 0.f, 0.f, 0.f};

    const int rs = lane >> 2;
    const int cs = lane & 3;
    const int KK = K1 + K2;
    const int nsteps = KK >> 5;
    const int l16 = lane & 15;
    const int rloc = wr * 64 + ((lane >> 4) << 2);   // block-local base row

    // mode-2: prefetch c_in into regs; latency hides under the K-loop
    float co_pre[4][4] = {};
    const int ch = tcol * 32 + wc * 16 + l16;        // mode-2 channel
    if (mode == 2 && c_in) {
#pragma unroll
        for (int m = 0; m < 4; ++m)
#pragma unroll
            for (int r = 0; r < 4; ++r)
                co_pre[m][r] = c_in[(size_t)(row0 + rloc + m * 16 + r) * HID + ch];
    }

    // 3 global_load_lds per wave per stage call (2x A-seg, 1x B-seg)
    auto stage = [&](int buf, int k0) {
        const short* Ak; const short* Bk; int kk, ld;
        if (k0 < K1) { Ak = A1; Bk = B1; kk = k0;      ld = K1; }
        else         { Ak = A2; Bk = B2; kk = k0 - K1; ld = K2; }
#pragma unroll
        for (int i = 0; i < 2; ++i) {
            int seg = w * 2 + i;                     // 16 A-segs of 16 rows
            int row = seg * 16 + rs;
            int c8  = cs ^ ((row + (row >> 2)) & 3);
            const short* ga = Ak + (size_t)(row0 + row) * ld + kk + c8 * 8;
            short* la = &sA[buf][seg * 512 + lane * 8];
            __builtin_amdgcn_global_load_lds((const __attribute__((address_space(1))) void*)ga,
                                             (__attribute__((address_space(3))) void*)la, 16, 0, 0);
        }
        {
            int row = w * 16 + rs;                   // 8 B-segs of 16 rows
            int c8  = cs ^ ((row + (row >> 2)) & 3);
            const short* gb = Bk + (size_t)(col0 + row) * ld + kk + c8 * 8;
            short* lb = &sB[buf][w * 512 + lane * 8];
            __builtin_amdgcn_global_load_lds((const __attribute__((address_space(1))) void*)gb,
                                             (__attribute__((address_space(3))) void*)lb, 16, 0, 0);
        }
    };

    stage(0, 0);
    stage(1, 32);                  // 6 loads in flight; KK >= 64 guaranteed
    int cur = 0;
    for (int t = 0; t < nsteps; ++t) {
        // wait for group t (oldest); keep the newer group in flight
        if (t + 1 < nsteps) asm volatile("s_waitcnt vmcnt(3)" ::: "memory");
        else                asm volatile("s_waitcnt vmcnt(0)" ::: "memory");
        __builtin_amdgcn_s_barrier();          // all waves: buf[cur] ready
        asm volatile("" ::: "memory");

        s16x8 af[4], bg[4];
        {
            const int rl = lane & 15;
            const int cw = lane >> 4;
#pragma unroll
            for (int m = 0; m < 4; ++m) {
                int r  = wr * 64 + m * 16 + rl;
                int sl = cw ^ ((r + (r >> 2)) & 3);
                af[m] = *(const s16x8*)(&sA[cur][r * 32 + sl * 8]);
                int c  = wc * 64 + m * 16 + rl;
                int sc = cw ^ ((c + (c >> 2)) & 3);
                bg[m] = *(const s16x8*)(&sB[cur][c * 32 + sc * 8]);
            }
        }
        // MFMAs consume all af/bg (compiler interleaves reads+MFMA with
        // fine-grained lgkmcnt); after them this wave's LDS reads are done.
#pragma unroll
        for (int m = 0; m < 4; ++m)
#pragma unroll
            for (int n = 0; n < 4; ++n)
                acc[m][n] = __builtin_amdgcn_mfma_f32_16x16x32_bf16(af[m], bg[n], acc[m][n], 0, 0, 0);

        __builtin_amdgcn_s_barrier();          // all waves done READING buf[cur]
        asm volatile("" ::: "memory");
        if (t + 2 < nsteps) stage(cur, (t + 2) * 32);   // re-stage 2 ahead
        cur ^= 1;
    }

    // C/D layout: col=lane&15, row=(lane>>4)*4+reg
    const int rbase = row0 + rloc;
    if (mode == 2) {
        float bi[4];
#pragma unroll
        for (int gg2 = 0; gg2 < 4; ++gg2) {
            float bb = bhh ? bhh[gg2 * 256 + ch] : 0.f;
            bi[gg2] = bih[gg2 * 256 + ch] + bb;
        }
#pragma unroll
        for (int m = 0; m < 4; ++m) {
#pragma unroll
            for (int r = 0; r < 4; ++r) {
                int row = rbase + m * 16 + r;
                float gi = acc[m][0][r] + bi[0];
                float gf = acc[m][1][r] + bi[1];
                float gg = acc[m][2][r] + bi[2];
                float go = acc[m][3][r] + bi[3];
                size_t idx = (size_t)row * HID + ch;
                float co = c_in ? co_pre[m][r] : 0.f;
                float c2 = fsigm(gf) * co + fsigm(gi) * ftanh(gg);
                float h2 = fsigm(go) * ftanh(c2);
                c_out[idx] = c2;
                h_out[idx] = f2b(h2);
            }
        }
    } else {
        const int cbase = col0 + wc * 64 + l16;
#pragma unroll
        for (int n = 0; n < 4; ++n) {
            int col = cbase + n * 16;
            float ba = bias ? bias[col] : 0.f;
#pragma unroll
            for (int m = 0; m < 4; ++m) {
#pragma unroll
                for (int r = 0; r < 4; ++r) {
                    int row = rbase + m * 16 + r;
                    float v = acc[m][n][r] + ba;
                    size_t idx = (size_t)row * N + col;
                    if (mode == 1) Cb[idx] = f2b(v);
                    else           Cf[idx] = v;
                }
            }
        }
    }
}

// ---------------- fused GATv2 (softmax + aggregate + bias + LN + ELU) -------
// quarter-wave per head; 8-wide gather batching (one exposed latency window
// for deg <= 8, which covers most nodes at avg degree 5).
// xlr: [MP][512] bf16, cols 0..255 = lin_l(x), 256..511 = lin_r(x).
__global__ __launch_bounds__(256) void gat_fused(
    const short* __restrict__ xlr, const int* __restrict__ rowptr,
    const int* __restrict__ esrc, const float* __restrict__ att,
    const float* __restrict__ gb, const float* __restrict__ lg,
    const float* __restrict__ lb, short* __restrict__ outb)
{
    int i    = blockIdx.x * 4 + (threadIdx.x >> 6);
    int lane = threadIdx.x & 63;
    if (i >= NN) return;
    const int cb = (lane >> 4) * 64 + (lane & 15) * 4;   // channel base

    float xr4[4], at4[4];
    {
        s16x4 v = *(const s16x4*)(&xlr[(size_t)i * 512 + 256 + cb]);
#pragma unroll
        for (int j = 0; j < 4; ++j) { xr4[j] = b2f(v[j]); at4[j] = att[cb + j]; }
    }
    float mx = -INFINITY, sm = 0.f;
    float ac[4] = {0.f, 0.f, 0.f, 0.f};

    // process one gathered edge (identical math/order to r23/r24 loop body)
    auto process = [&](s16x4 xv) {
        float xs[4], pl = 0.f;
#pragma unroll
        for (int j = 0; j < 4; ++j) {
            xs[j] = b2f(xv[j]);
            float v = xs[j] + xr4[j];
            v = (v >= 0.f) ? v : 0.2f * v;
            pl += v * at4[j];
        }
#pragma unroll
        for (int o = 1; o < 16; o <<= 1) pl += __shfl_xor(pl, o);   // head logit
        float mn = fmaxf(mx, pl);
        float sc = fexp(mx - mn);            // first iter: exp(-inf)=0
        float a  = fexp(pl - mn);
        sm = sm * sc + a;
#pragma unroll
        for (int j = 0; j < 4; ++j) ac[j] = ac[j] * sc + a * xs[j];
        mx = mn;
    };

    int lo = rowptr[i], hi = rowptr[i + 1];   // wave-uniform; deg >= 1
    for (int e0 = lo; e0 < hi; e0 += 8) {
        int n = hi - e0;                      // wave-uniform chunk size
        // issue all esrc loads, then all 8 gathers back-to-back (8-deep
        // latency overlap); inactive slots re-load edge e0 (safe, unused).
        int s0 = esrc[e0];
        int s1 = (n > 1) ? esrc[e0 + 1] : s0;
        int s2 = (n > 2) ? esrc[e0 + 2] : s0;
        int s3 = (n > 3) ? esrc[e0 + 3] : s0;
        int s4 = (n > 4) ? esrc[e0 + 4] : s0;
        int s5 = (n > 5) ? esrc[e0 + 5] : s0;
        int s6 = (n > 6) ? esrc[e0 + 6] : s0;
        int s7 = (n > 7) ? esrc[e0 + 7] : s0;
        s16x4 x0 = *(const s16x4*)(&xlr[(size_t)s0 * 512 + cb]);
        s16x4 x1 = *(const s16x4*)(&xlr[(size_t)s1 * 512 + cb]);
        s16x4 x2 = *(const s16x4*)(&xlr[(size_t)s2 * 512 + cb]);
        s16x4 x3 = *(const s16x4*)(&xlr[(size_t)s3 * 512 + cb]);
        s16x4 x4 = *(const s16x4*)(&xlr[(size_t)s4 * 512 + cb]);
        s16x4 x5 = *(const s16x4*)(&xlr[(size_t)s5 * 512 + cb]);
        s16x4 x6 = *(const s16x4*)(&xlr[(size_t)s6 * 512 + cb]);
        s16x4 x7 = *(const s16x4*)(&xlr[(size_t)s7 * 512 + cb]);
        process(x0);
        if (n > 1) process(x1);
        if (n > 2) process(x2);
        if (n > 3) process(x3);
        if (n > 4) process(x4);
        if (n > 5) process(x5);
        if (n > 6) process(x6);
        if (n > 7) process(x7);
    }

    // y = ac/sm (+ gat bias), then LayerNorm(256) + ELU, write bf16
    float val[4], s1v = 0.f, s2v = 0.f;
    float ism = frcp(sm);
#pragma unroll
    for (int j = 0; j < 4; ++j) {
        float v = ac[j] * ism + gb[cb + j];
        val[j] = v; s1v += v; s2v += v * v;
    }
    s1v = wsum64(s1v); s2v = wsum64(s2v);
    float mean = s1v * (1.f / 256.f);
    float var  = s2v * (1.f / 256.f) - mean * mean;
    float inv  = rsqrtf(var + 1e-5f);
    s16x4 ov;
#pragma unroll
    for (int j = 0; j < 4; ++j) {
        float v = (val[j] - mean) * inv * lg[cb + j] + lb[cb + j];
        v = (v > 0.f) ? v : (fexp(v) - 1.f);
        ov[j] = f2b(v);
    }
    *(s16x4*)(&outb[(size_t)i * HID + cb]) = ov;
}

// ---------------- LayerNorm (+act) for the MLP head -------------------------
__global__ __launch_bounds__(256) void ln_act_kernel(
    const float* __restrict__ in, const float* __restrict__ gamma,
    const float* __restrict__ beta, float* __restrict__ outf,
    short* __restrict__ outb, int width, int act)
{
    int row = blockIdx.x;
    const float* ip = in + (size_t)row * width;
    float vals[3];
    float s = 0.f, ss = 0.f;
    int nw = width >> 8;
    for (int i = 0; i < nw; ++i) {
        int c = threadIdx.x + (i << 8);
        float v = ip[c];
        vals[i] = v; s += v; ss += v * v;
    }
#pragma unroll
    for (int off = 32; off > 0; off >>= 1) {
        s  += __shfl_down(s, off);
        ss += __shfl_down(ss, off);
    }
    __shared__ float sh[8];
    int wv = threadIdx.x >> 6, lane = threadIdx.x & 63;
    if (lane == 0) { sh[wv] = s; sh[4 + wv] = ss; }
    __syncthreads();
    if (threadIdx.x == 0) {
        sh[0] = sh[0] + sh[1] + sh[2] + sh[3];
        sh[4] = sh[4] + sh[5] + sh[6] + sh[7];
    }
    __syncthreads();
    float mean = sh[0] / width;
    float var  = sh[4] / width - mean * mean;
    float inv  = rsqrtf(var + 1e-5f);
    for (int i = 0; i < nw; ++i) {
        int c = threadIdx.x + (i << 8);
        float v = (vals[i] - mean) * inv * gamma[c] + beta[c];
        if (act == 1) v = fmaxf(v, 0.f);
        if (outb) outb[(size_t)row * width + c] = f2b(v);
        else      outf[(size_t)row * width + c] = v;
    }
}

// ---------------- sorted-batch mean pool ------------------------------------
__global__ __launch_bounds__(256) void pool_mean(
    const short* __restrict__ h, const int* __restrict__ batch,
    short* __restrict__ poolb)
{
    int b    = blockIdx.x * 4 + (threadIdx.x >> 6);
    int lane = threadIdx.x & 63;
    if (b >= BG) return;
    auto lbound = [&](int key) {
        int lo = 0, hi = NN;
        while (lo < hi) { int mid = (lo + hi) >> 1; if (batch[mid] < key) lo = mid + 1; else hi = mid; }
        return lo;
    };
    int lo = lbound(b), hi = lbound(b + 1);
    float acc[HEADS] = {0.f, 0.f, 0.f, 0.f};
    for (int r = lo; r < hi; ++r)
#pragma unroll
        for (int hh = 0; hh < HEADS; ++hh)
            acc[hh] += b2f(h[(size_t)r * HID + hh * 64 + lane]);
    float inv = 1.f / fmaxf((float)(hi - lo), 1.f);
#pragma unroll
    for (int hh = 0; hh < HEADS; ++hh)
        poolb[(size_t)b * HID + hh * 64 + lane] = f2b(acc[hh] * inv);
}

// ---------------------------------------------------------------------------
extern "C" void kernel_launch(void* const* d_in, const int* in_sizes, int n_in,
                              void* d_out, int out_size, void* d_ws, size_t ws_size,
                              hipStream_t stream)
{
    (void)in_sizes; (void)n_in; (void)out_size; (void)ws_size;
    const float* x      = (const float*)d_in[0];
    const int*   ei     = (const int*)d_in[1];
    const int*   batch  = (const int*)d_in[2];
    const float* lin0_w = (const float*)d_in[4];
    const float* lin0_b = (const float*)d_in[5];
    const float* r0_wih = (const float*)d_in[6];
    const float* r0_bih = (const float*)d_in[8];
    const float* r0_bhh = (const float*)d_in[9];
    const float* mh1_w  = (const float*)d_in[46];
    const float* mh1_b  = (const float*)d_in[47];
    const float* ln1_g  = (const float*)d_in[48];
    const float* ln1_b  = (const float*)d_in[49];
    const float* mh2_w  = (const float*)d_in[50];
    const float* mh2_b  = (const float*)d_in[51];
    const float* ln2_g  = (const float*)d_in[52];
    const float* ln2_b  = (const float*)d_in[53];
    float* out = (float*)d_out;

    // ---- workspace bump allocation ----
    char* wsb = (char*)d_ws;
    auto alloc = [&](size_t bytes) -> void* {
        void* p = (void*)wsb;
        wsb += (bytes + 255) & ~(size_t)255;
        return p;
    };
    const size_t NH = (size_t)MP * HID;
    float* cb   = (float*)alloc(NH * 4);          // LSTM cell state f32
    short* hA   = (short*)alloc(NH * 2);          // h ping
    short* hB   = (short*)alloc(NH * 2);          // h pong
    short* ybb  = (short*)alloc(NH * 2);          // GAT-out / LSTM-input bf16
    short* xlr  = (short*)alloc((size_t)MP * 512 * 2);  // [xl|xr] bf16
    int*   deg    = (int*)alloc((size_t)NN * 4);
    int*   rowptr = (int*)alloc((size_t)(NN + 1) * 4);
    int*   cursor = (int*)alloc((size_t)NN * 4);
    int*   esrc   = (int*)alloc((size_t)EP * 4);
    int*   bsum   = (int*)alloc((size_t)SCB * 4);
    int*   bpre   = (int*)alloc((size_t)SCB * 4);
    // weights bf16
    short* w_r0f  = (short*)alloc((size_t)G4H * KP0 * 2);  // folded lin0+rnn0
    float* b_r0   = (float*)alloc((size_t)G4H * 4);        // folded bias
    short* w_lr[3]; short* w_ih[3]; short* w_hh[3]; float* blr[3];
    for (int l = 0; l < 3; ++l) {
        int Kp = (l == 0) ? KP0 : 256;
        w_lr[l] = (short*)alloc((size_t)512 * Kp * 2);
        w_ih[l] = (short*)alloc((size_t)G4H * 256 * 2);
        w_hh[l] = (short*)alloc((size_t)G4H * 256 * 2);
        blr[l]  = (float*)alloc(512 * 4);
    }
    short* w_m1 = (short*)alloc((size_t)NH1 * 256 * 2);
    short* w_m2 = (short*)alloc((size_t)NH2 * NH1 * 2);
    // xb (layer-0 padded input) with head temps aliased over it (head runs
    // only after xb is dead)
    short* xb = (short*)alloc((size_t)MP * KP0 * 2);   // 64 MB
    float* z1    = (float*)xb;                          // BG*NH1 f32 (8.4MB)
    short* z1b   = (short*)(z1 + (size_t)BG * NH1);     // BG*NH1 bf16
    short* poolb = z1b + (size_t)BG * NH1;              // BG*HID bf16

    // mode 0/1 GEMM; 1-D grid with XCD swizzle (requires (M/256)%8==0)
    auto G = [&](const short* A, const short* B, int K, const float* bias,
                 float* Cf, short* Cbb, int M, int N, int mode) {
        int nrp = M / 256, nct = N / 128;
        mfma_gemm<<<dim3(nrp * nct), dim3(512), 0, stream>>>(
            A, B, K, nullptr, nullptr, 0, bias,
            nullptr, nullptr, nullptr, nullptr, nullptr, Cf, Cbb, N, mode, nct);
    };
    // mode 2 LSTM GEMM (dual-source)
    auto GL = [&](const short* A1, const short* B1, int K1,
                  const short* A2, const short* B2, int K2,
                  const float* bih, const float* bhh,
                  const float* ci, float* co, short* ho) {
        mfma_gemm<<<dim3((MP / 256) * 8), dim3(512), 0, stream>>>(
            A1, B1, K1, A2, B2, K2, nullptr,
            bih, bhh, ci, co, ho, nullptr, nullptr, G4H, 2, 8);
    };

    // ---- conversions: x pad-convert (div-free), batched weights, folds ----
    conv_x<<<dim3(MP / 8), dim3(256), 0, stream>>>(x, xb);

    CPack cp; int nd = 0;
    auto addc = [&](const float* s, short* d, int rsrc, int rdst, int Ks, int Kd) {
        cp.d[nd++] = CDesc{ s, d, rdst, Ks, Kd, rsrc, 0 };
    };
    auto addg = [&](const float* s, short* d) {
        cp.d[nd++] = CDesc{ s, d, G4H, 256, 256, G4H, 1 };
    };
    for (int l = 0; l < 3; ++l) {
        int base = 10 + 12 * l;
        int K  = (l == 0) ? FIN : 256;
        int Kp = (l == 0) ? KP0 : 256;
        addc((const float*)d_in[base + 0], w_lr[l], 256, 256, K, Kp);
        addc((const float*)d_in[base + 2], w_lr[l] + (size_t)256 * Kp, 256, 256, K, Kp);
        addg((const float*)d_in[base + 8], w_ih[l]);
        addg((const float*)d_in[base + 9], w_hh[l]);
    }
    addc(mh1_w, w_m1, NH1, NH1, 256, 256);
    addc(mh2_w, w_m2, NH2, NH2, NH1, NH1);
    conv_pack<<<dim3(64, nd), dim3(256), 0, stream>>>(cp, nd);

    fold_w<<<dim3(G4H), dim3(320), 0, stream>>>(r0_wih, lin0_w, w_r0f);
    fold_b<<<dim3(4), dim3(256), 0, stream>>>(r0_wih, lin0_b, r0_bih, r0_bhh, b_r0);

    BPack bp;
    for (int l = 0; l < 3; ++l) {
        int base = 10 + 12 * l;
        bp.a[l] = (const float*)d_in[base + 1];
        bp.b[l] = (const float*)d_in[base + 3];
        bp.dst[l] = blr[l];
    }
    concat_pack<<<dim3(6), dim3(256), 0, stream>>>(bp);

    // ---- CSR build ----
    zero_f32<<<dim3(256), dim3(256), 0, stream>>>((float*)deg, NN);
    edge_hist<<<dim3((EP + 255) / 256), dim3(256), 0, stream>>>(ei, deg);
    scan_part<<<dim3(SCB), dim3(256), 0, stream>>>(deg, bsum);
    scan_tops<<<dim3(1), dim3(512), 0, stream>>>(bsum, bpre, rowptr);
    scan_fill<<<dim3(SCB), dim3(256), 0, stream>>>(deg, bpre, rowptr, cursor);
    edge_fill<<<dim3((EP + 255) / 256), dim3(256), 0, stream>>>(ei, rowptr, cursor, esrc);

    // ---- rnn0 LSTM directly from xb (folded weights; h=c=0 start) ----
    GL(xb, w_r0f, KP0, nullptr, nullptr, 0, b_r0, nullptr, nullptr, cb, hA);

    // ---- 3x (GATv2 -> LN+ELU -> LSTM) ----
    short* hprev = hA;
    short* hnext = hB;
    for (int l = 0; l < 3; ++l) {
        int base = 10 + 12 * l;
        const float* att = (const float*)d_in[base + 4];
        const float* gb  = (const float*)d_in[base + 5];
        const float* lg  = (const float*)d_in[base + 6];
        const float* lb  = (const float*)d_in[base + 7];
        const float* bih = (const float*)d_in[base + 10];
        const float* bhh = (const float*)d_in[base + 11];
        const short* Ain = (l == 0) ? xb : hprev;
        int K = (l == 0) ? KP0 : 256;

        G(Ain, w_lr[l], K, blr[l], nullptr, xlr, MP, 512, 1);
        gat_fused<<<dim3((NN + 3) / 4), dim3(256), 0, stream>>>(
            xlr, rowptr, esrc, att, gb, lg, lb, ybb);
        GL(ybb, w_ih[l], 256, hprev, w_hh[l], 256, bih, bhh, cb, cb, hnext);
        short* t = hprev; hprev = hnext; hnext = t;
    }

    // ---- mean pool (sorted batch) + MLP head ----
    pool_mean<<<dim3((BG + 3) / 4), dim3(256), 0, stream>>>(hprev, batch, poolb);
    G(poolb, w_m1, 256, mh1_b, z1, nullptr, BG, NH1, 0);
    ln_act_kernel<<<dim3(BG), dim3(256), 0, stream>>>(z1, ln1_g, ln1_b, nullptr, z1b, NH1, 1);
    G(z1b, w_m2, NH1, mh2_b, out, nullptr, BG, NH2, 0);
    ln_act_kernel<<<dim3(BG), dim3(256), 0, stream>>>(out, ln2_g, ln2_b, out, nullptr, NH2, 0);
}